// Round 4
// baseline (558.415 us; speedup 1.0000x reference)
//
#include <hip/hip_runtime.h>

#define B_ 2
#define L_ 2048
#define D_ 2048
#define H_ 8
#define HD_ 256
#define FD_ 64
#define F_ 128          // 2*FD
#define NC_ 32          // L/CHUNK
#define M_ (B_*L_)      // 4096
#define SCALE_Q 0.08838834764831845f   // 128^-0.5

typedef unsigned short u16;
typedef __attribute__((ext_vector_type(8))) short bf16x8;
typedef __attribute__((ext_vector_type(8))) unsigned short u16x8;
typedef __attribute__((ext_vector_type(16))) float f32x16;
typedef __attribute__((ext_vector_type(4))) unsigned int u32x4;

#define FMA4(a_, s_, v_) { (a_).x += (s_)*(v_).x; (a_).y += (s_)*(v_).y; \
                           (a_).z += (s_)*(v_).z; (a_).w += (s_)*(v_).w; }

// ---------------------------------------------------------------------------
// Tiled operand layouts (read-major: memory order == MFMA fragment order).
// 512-u16 chunk (one 32xK16 fragment set): addr = ((k>>3)&1)*256 + (x&31)*8
// + (k&7), where x is the row (A) or col (B) index. Lane l reads u16x8 at
// chunk + l*8 -> (x = l&31, k = ks*16 + (l>>5)*8 + elem). Symmetric between
// A-frags and B-frags (verified by the existing GEMM bodies).
// ---------------------------------------------------------------------------

__device__ __forceinline__ u16 bf16_rne(float x) {
  unsigned u = __float_as_uint(x);
  return (u16)((u + 0x7fffu + ((u >> 16) & 1u)) >> 16);
}
__device__ __forceinline__ void bf16_split(float x, u16& h, u16& l) {
  unsigned u = __float_as_uint(x);
  unsigned hb = (u + 0x7fffu + ((u >> 16) & 1u)) >> 16;
  h = (u16)hb;
  float hf = __uint_as_float(hb << 16);
  l = bf16_rne(x - hf);
}

__device__ __forceinline__ void gl_lds16(const u16* g, u16* l) {
  __builtin_amdgcn_global_load_lds(
      (const __attribute__((address_space(1))) unsigned int*)g,
      (__attribute__((address_space(3))) unsigned int*)l, 16, 0, 0);
}

// kvb / v-frag tiled offset: per-chunk [2 d-panel][4 f-kt][4096] layout,
// identical algebra to the B-tiled weights. f0 must be 8-aligned for u16x8.
__device__ __forceinline__ size_t kvb_off(int d, int f) {
  return (size_t)(((d >> 7) & 1) * 16384 + ((f >> 5) & 3) * 4096 +
                  ((d >> 6) & 1) * 2048 + ((f >> 4) & 1) * 1024 +
                  ((d >> 5) & 1) * 512 + ((f >> 3) & 1) * 256 +
                  (d & 31) * 8 + (f & 7));
}

// ---------------------------------------------------------------------------
// W[K=2048][Nsrc] fp32 -> B-tiled bf16 (panel P, ktile kt).
// ---------------------------------------------------------------------------
__device__ __forceinline__ void wtrans_body(const float* __restrict__ W, int Nsrc,
                                            int n0, u16* __restrict__ dst,
                                            int P, int kt) {
  int t = threadIdx.x;
  int nn = t & 127, kh = t >> 7;
  const float* src = W + (size_t)(kt * 32 + kh * 16) * Nsrc + n0 + nn;
  u16x8 u0, u1;
  #pragma unroll
  for (int kk = 0; kk < 8; ++kk) u0[kk] = bf16_rne(src[(size_t)kk * Nsrc]);
  #pragma unroll
  for (int kk = 0; kk < 8; ++kk) u1[kk] = bf16_rne(src[(size_t)(kk + 8) * Nsrc]);
  size_t base = ((size_t)P * 64 + kt) * 4096 + (size_t)((nn >> 6) & 1) * 2048
              + (size_t)kh * 1024 + (size_t)((nn >> 5) & 1) * 512
              + (size_t)(nn & 31) * 8;
  *(u16x8*)(dst + base) = u0;
  *(u16x8*)(dst + base + 256) = u1;
}

__global__ __launch_bounds__(256)
void prep_kernel(const float* __restrict__ hs,
                 const float* __restrict__ Wq, const float* __restrict__ Wk,
                 const float* __restrict__ Wv,
                 u16* __restrict__ hsHt, u16* __restrict__ hsLt,
                 u16* __restrict__ WTh) {
  int bid = blockIdx.x;
  if (bid < 4096) {
    int gid = bid * 256 + threadIdx.x;
    int r = gid >> 8, u = gid & 255;
    const float* src = hs + (size_t)r * 2048 + u * 8;
    float4 v0 = *(const float4*)src, v1 = *(const float4*)(src + 4);
    float vals[8] = {v0.x, v0.y, v0.z, v0.w, v1.x, v1.y, v1.z, v1.w};
    u16x8 hv, lv;
    #pragma unroll
    for (int j = 0; j < 8; ++j) { u16 hh, ll; bf16_split(vals[j], hh, ll); hv[j] = hh; lv[j] = ll; }
    size_t off = ((size_t)(r >> 6) * 64 + (u >> 2)) * 2048
               + (size_t)((u >> 1) & 1) * 1024 + (size_t)((r >> 5) & 1) * 512
               + (size_t)(u & 1) * 256 + (size_t)(r & 31) * 8;
    *(u16x8*)(hsHt + off) = hv;
    *(u16x8*)(hsLt + off) = lv;
  } else {
    int idx = bid - 4096;
    int P = idx >> 6, kt = idx & 63;
    const float* W; int Nsrc, n0;
    if (P < 16)      { W = Wq; Nsrc = 2048; n0 = P * 128; }
    else if (P < 18) { W = Wk; Nsrc = 256;  n0 = (P - 16) * 128; }
    else             { W = Wv; Nsrc = 256;  n0 = (P - 18) * 128; }
    wtrans_body(W, Nsrc, n0, WTh, P, kt);
  }
}

// o fp32 [4096][2048] -> A-tiled split bf16 (same as prep's hs branch).
__global__ __launch_bounds__(256)
void prep_o(const float* __restrict__ o, u16* __restrict__ oHt,
            u16* __restrict__ oLt) {
  int gid = blockIdx.x * 256 + threadIdx.x;
  int r = gid >> 8, u = gid & 255;
  const float* src = o + (size_t)r * 2048 + u * 8;
  float4 v0 = *(const float4*)src, v1 = *(const float4*)(src + 4);
  float vals[8] = {v0.x, v0.y, v0.z, v0.w, v1.x, v1.y, v1.z, v1.w};
  u16x8 hv, lv;
  #pragma unroll
  for (int j = 0; j < 8; ++j) { u16 hh, ll; bf16_split(vals[j], hh, ll); hv[j] = hh; lv[j] = ll; }
  size_t off = ((size_t)(r >> 6) * 64 + (u >> 2)) * 2048
             + (size_t)((u >> 1) & 1) * 1024 + (size_t)((r >> 5) & 1) * 512
             + (size_t)(u & 1) * 256 + (size_t)(r & 31) * 8;
  *(u16x8*)(oHt + off) = hv;
  *(u16x8*)(oLt + off) = lv;
}

__global__ __launch_bounds__(256)
void wtrans_wo(const float* __restrict__ Wo, u16* __restrict__ WoTh) {
  wtrans_body(Wo, 2048, blockIdx.x * 128, WoTh, blockIdx.x, blockIdx.y);
}

// ---------------------------------------------------------------------------
// OLD 2-pass split-bf16 MFMA GEMM (64x128 tile, BK=32, 128 threads).
// ---------------------------------------------------------------------------
__device__ __forceinline__ void mfma_body(
    const u16* __restrict__ AtH, const u16* __restrict__ AtL,
    const u16* __restrict__ Bt, float* __restrict__ C, int cstride,
    int bm, int bn) {
  __shared__ __align__(16) u16 AsH[2048];
  __shared__ __align__(16) u16 AsL[2048];
  __shared__ __align__(16) u16 Bs[4096];
  const int t = threadIdx.x, lane = t & 63, wv = t >> 6;
  const u16* aSrc = (wv ? AtL : AtH) + (size_t)bm * 131072 + lane * 8;
  const u16* bSrc = Bt + (size_t)bn * 262144 + wv * 2048 + lane * 8;
  u16* aDst = wv ? AsL : AsH;
  u16* bDst = Bs + wv * 2048;

  f32x16 acc[2][2];
  #pragma unroll
  for (int a = 0; a < 2; ++a)
    #pragma unroll
    for (int b2 = 0; b2 < 2; ++b2)
      #pragma unroll
      for (int r = 0; r < 16; ++r) acc[a][b2][r] = 0.f;

  for (int kt = 0; kt < 64; ++kt) {
    const u16* ak = aSrc + (size_t)kt * 2048;
    const u16* bk = bSrc + (size_t)kt * 4096;
    __syncthreads();
    #pragma unroll
    for (int c = 0; c < 4; ++c) {
      gl_lds16(ak + c * 512, aDst + c * 512);
      gl_lds16(bk + c * 512, bDst + c * 512);
    }
    __syncthreads();

    #pragma unroll
    for (int ks = 0; ks < 2; ++ks) {
      const u16* ph = AsH + ks * 1024 + lane * 8;
      const u16* pl = AsL + ks * 1024 + lane * 8;
      const u16* pb = Bs + wv * 2048 + ks * 1024 + lane * 8;
      bf16x8 a0 = *(const bf16x8*)ph;
      bf16x8 a1 = *(const bf16x8*)(ph + 512);
      bf16x8 b0 = *(const bf16x8*)pb;
      bf16x8 b1 = *(const bf16x8*)(pb + 512);
      acc[0][0] = __builtin_amdgcn_mfma_f32_32x32x16_bf16(a0, b0, acc[0][0], 0, 0, 0);
      acc[0][1] = __builtin_amdgcn_mfma_f32_32x32x16_bf16(a0, b1, acc[0][1], 0, 0, 0);
      acc[1][0] = __builtin_amdgcn_mfma_f32_32x32x16_bf16(a1, b0, acc[1][0], 0, 0, 0);
      acc[1][1] = __builtin_amdgcn_mfma_f32_32x32x16_bf16(a1, b1, acc[1][1], 0, 0, 0);
      bf16x8 l0 = *(const bf16x8*)pl;
      bf16x8 l1 = *(const bf16x8*)(pl + 512);
      acc[0][0] = __builtin_amdgcn_mfma_f32_32x32x16_bf16(l0, b0, acc[0][0], 0, 0, 0);
      acc[0][1] = __builtin_amdgcn_mfma_f32_32x32x16_bf16(l0, b1, acc[0][1], 0, 0, 0);
      acc[1][0] = __builtin_amdgcn_mfma_f32_32x32x16_bf16(l1, b0, acc[1][0], 0, 0, 0);
      acc[1][1] = __builtin_amdgcn_mfma_f32_32x32x16_bf16(l1, b1, acc[1][1], 0, 0, 0);
    }
  }

  const int fr = lane & 31, g = lane >> 5;
  float* Cp = C + (size_t)(bm * 64) * cstride + wv * 64;
  #pragma unroll
  for (int mt = 0; mt < 2; ++mt)
    #pragma unroll
    for (int nt = 0; nt < 2; ++nt) {
      #pragma unroll
      for (int r = 0; r < 16; ++r) {
        int row = mt * 32 + (r & 3) + 8 * (r >> 2) + 4 * g;
        Cp[(size_t)row * cstride + nt * 32 + fr] = acc[mt][nt][r];
      }
    }
}

// ---------------------------------------------------------------------------
// Pipelined body: 256x128 tile, 8 waves, BK=32, triple-buffered LDS ring,
// counted vmcnt(5) across raw s_barrier, setprio around MFMA clusters.
// ---------------------------------------------------------------------------
#define SUB_ 20480

__device__ __forceinline__ void mfma_big_body(
    const u16* __restrict__ AtH, const u16* __restrict__ AtL,
    const u16* __restrict__ Bt, float* __restrict__ C, int cstride,
    int bm, int bn) {
  __shared__ __align__(16) u16 lds[3 * SUB_];
  const int t = threadIdx.x, lane = t & 63, wv = t >> 6;
  const int wm = wv >> 1, wn = wv & 1;

  const u16* gs[5];
  unsigned lo[5], gst[5];
  #pragma unroll
  for (int j = 0; j < 5; ++j) {
    int line = wv * 5 + j;
    if (line < 16) {
      gs[j] = AtH + ((size_t)(4 * bm + (line >> 2)) * 64) * 2048
                  + (size_t)(line & 3) * 512 + lane * 8;
      lo[j] = line * 512; gst[j] = 2048;
    } else if (line < 32) {
      int l2 = line - 16;
      gs[j] = AtL + ((size_t)(4 * bm + (l2 >> 2)) * 64) * 2048
                  + (size_t)(l2 & 3) * 512 + lane * 8;
      lo[j] = 8192 + l2 * 512; gst[j] = 2048;
    } else {
      int l3 = line - 32;
      gs[j] = Bt + (size_t)bn * 262144 + (size_t)l3 * 512 + lane * 8;
      lo[j] = 16384 + l3 * 512; gst[j] = 4096;
    }
  }

  f32x16 acc[2][2];
  #pragma unroll
  for (int a = 0; a < 2; ++a)
    #pragma unroll
    for (int b2 = 0; b2 < 2; ++b2)
      #pragma unroll
      for (int r = 0; r < 16; ++r) acc[a][b2][r] = 0.f;

  auto stage = [&](int kt_, int boff_) {
    #pragma unroll
    for (int j = 0; j < 5; ++j)
      gl_lds16(gs[j] + (size_t)kt_ * gst[j], lds + boff_ + lo[j]);
  };

  stage(0, 0);
  stage(1, SUB_);
  asm volatile("s_waitcnt vmcnt(5)" ::: "memory");
  __builtin_amdgcn_s_barrier();
  __builtin_amdgcn_sched_barrier(0);

  int cb = 0;
  for (int kt = 0; kt < 64; ++kt) {
    int sb = cb + 2 * SUB_; if (sb >= 3 * SUB_) sb -= 3 * SUB_;
    if (kt < 62) stage(kt + 2, sb);
    const u16* base = lds + cb;
    #pragma unroll
    for (int ks = 0; ks < 2; ++ks) {
      const u16* ph = base + wm * 2048 + ks * 1024 + lane * 8;
      const u16* pb = base + 16384 + wn * 2048 + ks * 1024 + lane * 8;
      bf16x8 a0 = *(const bf16x8*)ph;
      bf16x8 a1 = *(const bf16x8*)(ph + 512);
      bf16x8 l0 = *(const bf16x8*)(ph + 8192);
      bf16x8 l1 = *(const bf16x8*)(ph + 8704);
      bf16x8 b0 = *(const bf16x8*)pb;
      bf16x8 b1 = *(const bf16x8*)(pb + 512);
      __builtin_amdgcn_s_setprio(1);
      acc[0][0] = __builtin_amdgcn_mfma_f32_32x32x16_bf16(a0, b0, acc[0][0], 0, 0, 0);
      acc[0][1] = __builtin_amdgcn_mfma_f32_32x32x16_bf16(a0, b1, acc[0][1], 0, 0, 0);
      acc[1][0] = __builtin_amdgcn_mfma_f32_32x32x16_bf16(a1, b0, acc[1][0], 0, 0, 0);
      acc[1][1] = __builtin_amdgcn_mfma_f32_32x32x16_bf16(a1, b1, acc[1][1], 0, 0, 0);
      acc[0][0] = __builtin_amdgcn_mfma_f32_32x32x16_bf16(l0, b0, acc[0][0], 0, 0, 0);
      acc[0][1] = __builtin_amdgcn_mfma_f32_32x32x16_bf16(l0, b1, acc[0][1], 0, 0, 0);
      acc[1][0] = __builtin_amdgcn_mfma_f32_32x32x16_bf16(l1, b0, acc[1][0], 0, 0, 0);
      acc[1][1] = __builtin_amdgcn_mfma_f32_32x32x16_bf16(l1, b1, acc[1][1], 0, 0, 0);
      __builtin_amdgcn_s_setprio(0);
    }
    asm volatile("s_waitcnt lgkmcnt(0)" ::: "memory");
    if (kt < 62) asm volatile("s_waitcnt vmcnt(5)" ::: "memory");
    else         asm volatile("s_waitcnt vmcnt(0)" ::: "memory");
    __builtin_amdgcn_s_barrier();
    __builtin_amdgcn_sched_barrier(0);
    cb += SUB_; if (cb == 3 * SUB_) cb = 0;
  }

  const int fr = lane & 31, g = lane >> 5;
  float* Cp = C + (size_t)(bm * 256 + wm * 64) * cstride + wn * 64;
  #pragma unroll
  for (int mt = 0; mt < 2; ++mt)
    #pragma unroll
    for (int nt = 0; nt < 2; ++nt) {
      #pragma unroll
      for (int r = 0; r < 16; ++r) {
        int row = mt * 32 + (r & 3) + 8 * (r >> 2) + 4 * g;
        Cp[(size_t)row * cstride + nt * 32 + fr] = acc[mt][nt][r];
      }
    }
}

__global__ __launch_bounds__(512, 2)
void mfma_q(const u16* __restrict__ hsHt, const u16* __restrict__ hsLt,
            const u16* __restrict__ WTh, float* __restrict__ q) {
  mfma_big_body(hsHt, hsLt, WTh, q + blockIdx.x * 128, 2048,
                blockIdx.y, blockIdx.x);
}

__global__ __launch_bounds__(128, 4)
void mfma_kv(const u16* __restrict__ hsHt, const u16* __restrict__ hsLt,
             const u16* __restrict__ WTh,
             float* __restrict__ k, float* __restrict__ v) {
  int bn = blockIdx.x;
  float* Cb; int co;
  if (bn < 2) { Cb = k; co = bn * 128; }
  else        { Cb = v; co = (bn - 2) * 128; }
  mfma_body(hsHt, hsLt, WTh, Cb + co, 256, blockIdx.y, 16 + bn);
}

__global__ __launch_bounds__(512, 2)
void mfma_wo(const u16* __restrict__ oHt, const u16* __restrict__ oLt,
             const u16* __restrict__ WoTh, float* __restrict__ out) {
  mfma_big_body(oHt, oLt, WoTh, out + blockIdx.x * 128, 2048,
                blockIdx.y, blockIdx.x);
}

__device__ __forceinline__ float wave_max64(float v) {
  #pragma unroll
  for (int off = 32; off > 0; off >>= 1) v = fmaxf(v, __shfl_xor(v, off, 64));
  return v;
}
__device__ __forceinline__ float wave_sum64(float v) {
  #pragma unroll
  for (int off = 32; off > 0; off >>= 1) v += __shfl_xor(v, off, 64);
  return v;
}

// ---------------------------------------------------------------------------
// Fused RoPE + hedgehog (unchanged).
// ---------------------------------------------------------------------------
__global__ __launch_bounds__(256)
void hedgehog_kernel(const float* __restrict__ q, const float* __restrict__ kx,
                     const float* __restrict__ fmq, const float* __restrict__ fmk,
                     const float* __restrict__ cosb, const float* __restrict__ sinb,
                     float* __restrict__ qf, float* __restrict__ kf) {
  __shared__ __align__(16) float rows[4][4][256];
  int bid = blockIdx.x;
  const float* x; const float* fm; float* out; int nh_in, gb;
  if (bid < 2048) { x = q;  fm = fmq; out = qf; nh_in = 8; gb = bid * 4; }
  else            { x = kx; fm = fmk; out = kf; nh_in = 1; gb = (bid - 2048) * 4; }
  int wave = threadIdx.x >> 6, lane = threadIdx.x & 63;
  int g = gb + wave;
  int l4 = g & (L_/4 - 1);
  int bh = g / (L_/4);
  int h = bh & 7, b = bh >> 3;
  int l0 = l4 * 4;
  size_t rstride = (nh_in == 1) ? (size_t)HD_ : (size_t)H_ * HD_;
  const float* xrow = (nh_in == 1)
      ? x + (size_t)(b * L_ + l0) * HD_
      : x + ((size_t)(b * L_ + l0) * H_ + h) * HD_;
  int dd = (lane & 31) * 4;
  #pragma unroll
  for (int r = 0; r < 4; ++r) {
    float4 v = *(const float4*)(xrow + r * rstride + lane * 4);
    float4 u;
    u.x = __shfl_xor(v.x, 32, 64); u.y = __shfl_xor(v.y, 32, 64);
    u.z = __shfl_xor(v.z, 32, 64); u.w = __shfl_xor(v.w, 32, 64);
    int l = l0 + r;
    float4 c = *(const float4*)(cosb + (size_t)l * 128 + dd);
    float4 s = *(const float4*)(sinb + (size_t)l * 128 + dd);
    float4 ro;
    if (lane < 32) {
      ro.x = v.x * c.x - u.x * s.x; ro.y = v.y * c.y - u.y * s.y;
      ro.z = v.z * c.z - u.z * s.z; ro.w = v.w * c.w - u.w * s.w;
    } else {
      ro.x = u.x * s.x + v.x * c.x; ro.y = u.y * s.y + v.y * c.y;
      ro.z = u.z * s.z + v.z * c.z; ro.w = u.w * s.w + v.w * c.w;
    }
    *(float4*)&rows[wave][r][lane * 4] = ro;
  }
  __syncthreads();

  const float* fmh = fm + (size_t)h * HD_ * FD_;
  float p0 = 0.f, p1 = 0.f, p2 = 0.f, p3 = 0.f;
  for (int d2 = 0; d2 < HD_; d2 += 4) {
    float w0 = fmh[(d2 + 0) * FD_ + lane];
    float w1 = fmh[(d2 + 1) * FD_ + lane];
    float w2 = fmh[(d2 + 2) * FD_ + lane];
    float w3 = fmh[(d2 + 3) * FD_ + lane];
    float4 r0 = *(const float4*)&rows[wave][0][d2];
    float4 r1 = *(const float4*)&rows[wave][1][d2];
    float4 r2 = *(const float4*)&rows[wave][2][d2];
    float4 r3 = *(const float4*)&rows[wave][3][d2];
    p0 += r0.x * w0 + r0.y * w1 + r0.z * w2 + r0.w * w3;
    p1 += r1.x * w0 + r1.y * w1 + r1.z * w2 + r1.w * w3;
    p2 += r2.x * w0 + r2.y * w1 + r2.z * w2 + r2.w * w3;
    p3 += r3.x * w0 + r3.y * w1 + r3.z * w2 + r3.w * w3;
  }
  float p[4] = {p0, p1, p2, p3};
  #pragma unroll
  for (int r = 0; r < 4; ++r) {
    float m = wave_max64(fabsf(p[r]));
    float e1 = __expf(p[r] - m);
    float e2 = __expf(-p[r] - m);
    float z = wave_sum64(e1 + e2);
    float inv = 1.0f / z;
    size_t base = ((size_t)bh * L_ + l0 + r) * F_;
    out[base + lane]      = e1 * inv;
    out[base + 64 + lane] = e2 * inv;
  }
}

// ---------------------------------------------------------------------------
// Phase A: per-chunk kv_n[f][d] = sum_j kf[j][f] v[j][d]; epilogue now emits
// frag-tiled SPLIT bf16 (kvbH/kvbL) instead of fp32 (zero extra workspace).
// ---------------------------------------------------------------------------
__global__ __launch_bounds__(256)
void chunk_kv_kernel(const float* __restrict__ kf, const float* __restrict__ v,
                     u16* __restrict__ kvbH, u16* __restrict__ kvbL) {
  __shared__ __align__(16) float kfs[64][128];
  int n = blockIdx.x & (NC_ - 1), bh = blockIdx.x >> 5;
  int b = bh >> 3;
  const float* kfp = kf + ((size_t)bh * L_ + (size_t)n * 64) * F_;
  int t = threadIdx.x;
  #pragma unroll
  for (int it = 0; it < 8; ++it) {
    int flat = t * 4 + it * 1024;
    *(float4*)&kfs[flat >> 7][flat & 127] = *(const float4*)(kfp + flat);
  }
  __syncthreads();
  int dg = t & 63;
  int fg = t >> 6;
  const float* vp = v + (size_t)(b * L_ + n * 64) * HD_ + dg * 4;
  size_t cb = (size_t)blockIdx.x * 32768;
  #pragma unroll
  for (int pass = 0; pass < 4; ++pass) {
    int f0 = fg * 8 + pass * 32;
    float4 acc[8];
    #pragma unroll
    for (int i = 0; i < 8; ++i) acc[i] = make_float4(0.f, 0.f, 0.f, 0.f);
    for (int j = 0; j < 64; ++j) {
      float4 vv = *(const float4*)(vp + (size_t)j * HD_);
      float4 ka = *(const float4*)&kfs[j][f0];
      float4 kb = *(const float4*)&kfs[j][f0 + 4];
      FMA4(acc[0], ka.x, vv); FMA4(acc[1], ka.y, vv);
      FMA4(acc[2], ka.z, vv); FMA4(acc[3], ka.w, vv);
      FMA4(acc[4], kb.x, vv); FMA4(acc[5], kb.y, vv);
      FMA4(acc[6], kb.z, vv); FMA4(acc[7], kb.w, vv);
    }
    #pragma unroll
    for (int c = 0; c < 4; ++c) {
      u16x8 hv, lv;
      #pragma unroll
      for (int ff = 0; ff < 8; ++ff) {
        float xs = (c == 0) ? acc[ff].x : (c == 1) ? acc[ff].y
                 : (c == 2) ? acc[ff].z : acc[ff].w;
        u16 hh, ll; bf16_split(xs, hh, ll); hv[ff] = hh; lv[ff] = ll;
      }
      int d = dg * 4 + c;
      size_t off = cb + kvb_off(d, f0);
      *(u16x8*)(kvbH + off) = hv;
      *(u16x8*)(kvbL + off) = lv;
    }
  }
}

// Phase B: in-place exclusive prefix over the 32 chunks, on split bf16.
// block = (bh, g): thread d owns f = g*8..g*8+7 at one d.
__global__ __launch_bounds__(256)
void chunk_scan_kernel(u16* __restrict__ kvbH, u16* __restrict__ kvbL) {
  int bh = blockIdx.x >> 4, g = blockIdx.x & 15;
  int d = threadIdx.x;
  size_t off = kvb_off(d, g * 8);
  float run[8] = {0.f, 0.f, 0.f, 0.f, 0.f, 0.f, 0.f, 0.f};
  for (int n = 0; n < NC_; ++n) {
    size_t a = ((size_t)(bh * 32 + n)) * 32768 + off;
    u16x8 hv = *(u16x8*)(kvbH + a);
    u16x8 lv = *(u16x8*)(kvbL + a);
    u16x8 oh, ol;
    #pragma unroll
    for (int c = 0; c < 8; ++c) {
      float val = __uint_as_float((unsigned)hv[c] << 16)
                + __uint_as_float((unsigned)lv[c] << 16);
      u16 hh, ll; bf16_split(run[c], hh, ll); oh[c] = hh; ol[c] = ll;
      run[c] += val;
    }
    *(u16x8*)(kvbH + a) = oh;
    *(u16x8*)(kvbL + a) = ol;
  }
}

// ---------------------------------------------------------------------------
// Phase C (MFMA rewrite): out[i][d] = qs[i]·kv_cum[:,d] + sum_{j<=i} s[i][j] v[j][d]
// 256 thr / 4 waves; wave w owns cols w*64..+63 (nt 0..1), all 64 rows.
// All operands split-bf16 3-pass (H·H + L·H + H·L) -> fp32-class accuracy.
// LDS 64KB: qsH|qsL|kfH|kfL as [2 tile][8 ks][512] chunks -> 2 blocks/CU.
// Scores computed TRANSPOSED (sT = kf·qs^T) so C-regs convert to intra
// A-frags with 4 shfl_xor(32) per fragment. Output: plain fp32 'o'.
// ---------------------------------------------------------------------------
#define MFB(a_, b_, c_) (c_) = __builtin_amdgcn_mfma_f32_32x32x16_bf16((a_), (b_), (c_), 0, 0, 0)

__global__ __launch_bounds__(256, 2)
void chunk_attn_kernel(const float* __restrict__ qf, const float* __restrict__ kf,
                       const float* __restrict__ v,
                       const u16* __restrict__ kvbH, const u16* __restrict__ kvbL,
                       float* __restrict__ o) {
  __shared__ __align__(16) u16 lds[32768];   // qsH|qsL|kfH|kfL, 8192 u16 each
  const int n = blockIdx.x & (NC_ - 1), bh = blockIdx.x >> 5;
  const int h = bh & 7, b = bh >> 3;
  const int t = threadIdx.x;
  const int w = t >> 6, i31 = t & 31, G = (t >> 5) & 1;
  const int l8 = (t & 63) * 8;

  // ---- stage qs (scaled, split) and kf (split) into frag chunks ----
  {
    const float* qp = qf + ((size_t)bh * L_ + (size_t)n * 64) * F_;
    const float* kp = kf + ((size_t)bh * L_ + (size_t)n * 64) * F_;
    int o8 = t & 15, ib = t >> 4;
    #pragma unroll
    for (int iter = 0; iter < 4; ++iter) {
      int i = ib + iter * 16;
      int it = i >> 5, ks = o8 >> 1;
      int sub = (it * 8 + ks) * 512 + (o8 & 1) * 256 + (i & 31) * 8;
      {
        const float* src = qp + (size_t)i * 128 + o8 * 8;
        float4 a = *(const float4*)src, c = *(const float4*)(src + 4);
        float vals[8] = {a.x, a.y, a.z, a.w, c.x, c.y, c.z, c.w};
        u16x8 hv, lv;
        #pragma unroll
        for (int j = 0; j < 8; ++j) {
          u16 hh, ll; bf16_split(vals[j] * SCALE_Q, hh, ll);
          hv[j] = hh; lv[j] = ll;
        }
        *(u16x8*)(lds + sub) = hv;
        *(u16x8*)(lds + 8192 + sub) = lv;
      }
      {
        const float* src = kp + (size_t)i * 128 + o8 * 8;
        float4 a = *(const float4*)src, c = *(const float4*)(src + 4);
        float vals[8] = {a.x, a.y, a.z, a.w, c.x, c.y, c.z, c.w};
        u16x8 hv, lv;
        #pragma unroll
        for (int j = 0; j < 8; ++j) {
          u16 hh, ll; bf16_split(vals[j], hh, ll);
          hv[j] = hh; lv[j] = ll;
        }
        *(u16x8*)(lds + 16384 + sub) = hv;
        *(u16x8*)(lds + 24576 + sub) = lv;
      }
    }
  }
  __syncthreads();

  const u16* Lq  = lds;           // qsH
  const u16* Lql = lds + 8192;    // qsL
  const u16* Lk  = lds + 16384;   // kfH
  const u16* Lkl = lds + 24576;   // kfL

  // ---- phase S: sT[jt][it] = kf · qs^T (3-pass split) ----
  f32x16 st[2][2];
  #pragma unroll
  for (int a = 0; a < 2; ++a)
    #pragma unroll
    for (int c = 0; c < 2; ++c)
      #pragma unroll
      for (int r = 0; r < 16; ++r) st[a][c][r] = 0.f;

  #pragma unroll
  for (int ks = 0; ks < 8; ++ks) {
    bf16x8 kh0 = *(const bf16x8*)(Lk  + ks * 512 + l8);
    bf16x8 kh1 = *(const bf16x8*)(Lk  + (8 + ks) * 512 + l8);
    bf16x8 kl0 = *(const bf16x8*)(Lkl + ks * 512 + l8);
    bf16x8 kl1 = *(const bf16x8*)(Lkl + (8 + ks) * 512 + l8);
    bf16x8 qh0 = *(const bf16x8*)(Lq  + ks * 512 + l8);
    bf16x8 qh1 = *(const bf16x8*)(Lq  + (8 + ks) * 512 + l8);
    bf16x8 ql0 = *(const bf16x8*)(Lql + ks * 512 + l8);
    bf16x8 ql1 = *(const bf16x8*)(Lql + (8 + ks) * 512 + l8);
    MFB(kh0, qh0, st[0][0]); MFB(kh0, ql0, st[0][0]); MFB(kl0, qh0, st[0][0]);
    MFB(kh0, qh1, st[0][1]); MFB(kh0, ql1, st[0][1]); MFB(kl0, qh1, st[0][1]);
    MFB(kh1, qh0, st[1][0]); MFB(kh1, ql0, st[1][0]); MFB(kl1, qh0, st[1][0]);
    MFB(kh1, qh1, st[1][1]); MFB(kh1, ql1, st[1][1]); MFB(kl1, qh1, st[1][1]);
  }

  // ---- mask + split + cross-lane transpose: sT C-regs -> s A-frags ----
  // target frag (mt, ksj) elem jj: s[i = mt*32 + i31][j = ksj*16 + 8G + jj]
  // source: tile st[ksj>>1][mt], reg r = (jj&3) + 4G + 8(ksj&1), half (jj>>2).
  bf16x8 sfH[2][4], sfL[2][4];
  #pragma unroll
  for (int mt = 0; mt < 2; ++mt) {
    int iv = mt * 32 + i31;
    #pragma unroll
    for (int ksj = 0; ksj < 4; ++ksj) {
      const int jt = ksj >> 1, kb = ksj & 1;
      unsigned ph[4], pl[4];
      #pragma unroll
      for (int half = 0; half < 2; ++half) {
        u16 hh[4], ll[4];
        #pragma unroll
        for (int c = 0; c < 4; ++c) {
          int r = 8 * kb + 4 * half + c;
          int jv = jt * 32 + (r & 3) + 8 * (r >> 2) + 4 * G;
          float mv = (jv <= iv) ? st[jt][mt][r] : 0.f;
          u16 h_, l_; bf16_split(mv, h_, l_);
          hh[c] = h_; ll[c] = l_;
        }
        ph[half * 2 + 0] = (unsigned)hh[0] | ((unsigned)hh[1] << 16);
        ph[half * 2 + 1] = (unsigned)hh[2] | ((unsigned)hh[3] << 16);
        pl[half * 2 + 0] = (unsigned)ll[0] | ((unsigned)ll[1] << 16);
        pl[half * 2 + 1] = (unsigned)ll[2] | ((unsigned)ll[3] << 16);
      }
      unsigned rH1 = (unsigned)__shfl_xor((int)(G ? ph[0] : ph[2]), 32, 64);
      unsigned rH2 = (unsigned)__shfl_xor((int)(G ? ph[1] : ph[3]), 32, 64);
      unsigned rL1 = (unsigned)__shfl_xor((int)(G ? pl[0] : pl[2]), 32, 64);
      unsigned rL2 = (unsigned)__shfl_xor((int)(G ? pl[1] : pl[3]), 32, 64);
      u32x4 wH, wL;
      wH[0] = G ? rH1 : ph[0]; wH[1] = G ? rH2 : ph[1];
      wH[2] = G ? ph[2] : rH1; wH[3] = G ? ph[3] : rH2;
      wL[0] = G ? rL1 : pl[0]; wL[1] = G ? rL2 : pl[1];
      wL[2] = G ? pl[2] : rL1; wL[3] = G ? pl[3] : rL2;
      sfH[mt][ksj] = __builtin_bit_cast(bf16x8, wH);
      sfL[mt][ksj] = __builtin_bit_cast(bf16x8, wL);
    }
  }

  f32x16 acc[2][2];
  #pragma unroll
  for (int a = 0; a < 2; ++a)
    #pragma unroll
    for (int c = 0; c < 2; ++c)
      #pragma unroll
      for (int r = 0; r < 16; ++r) acc[a][c][r] = 0.f;

  // ---- phase A (intra): acc += s · v, v frags built in-register (split) ----
  {
    const float* vp = v + (size_t)(b * L_ + n * 64) * HD_;
    #pragma unroll
    for (int nt = 0; nt < 2; ++nt) {
      #pragma unroll
      for (int ksj = 0; ksj < 4; ++ksj) {
        const float* vsrc = vp + (size_t)(ksj * 16 + G * 8) * HD_
                          + w * 64 + nt * 32 + i31;
        u16x8 vh, vl;
        #pragma unroll
        for (int c = 0; c < 8; ++c) {
          u16 hh, ll; bf16_split(vsrc[(size_t)c * HD_], hh, ll);
          vh[c] = hh; vl[c] = ll;
        }
        bf16x8 vH = __builtin_bit_cast(bf16x8, vh);
        bf16x8 vL = __builtin_bit_cast(bf16x8, vl);
        MFB(sfH[0][ksj], vH, acc[0][nt]); MFB(sfL[0][ksj], vH, acc[0][nt]);
        MFB(sfH[0][ksj], vL, acc[0][nt]);
        MFB(sfH[1][ksj], vH, acc[1][nt]); MFB(sfL[1][ksj], vH, acc[1][nt]);
        MFB(sfH[1][ksj], vL, acc[1][nt]);
      }
    }
  }

  // ---- phase I (inter): acc += qs · kv_cum (kv frags streamed, pre-tiled) ----
  {
    size_t cb = (size_t)blockIdx.x * 32768;
    #pragma unroll
    for (int ks = 0; ks < 8; ++ks) {
      bf16x8 qa_h0 = *(const bf16x8*)(Lq  + ks * 512 + l8);
      bf16x8 qa_h1 = *(const bf16x8*)(Lq  + (8 + ks) * 512 + l8);
      bf16x8 qa_l0 = *(const bf16x8*)(Lql + ks * 512 + l8);
      bf16x8 qa_l1 = *(const bf16x8*)(Lql + (8 + ks) * 512 + l8);
      #pragma unroll
      for (int nt = 0; nt < 2; ++nt) {
        size_t base = cb + kvb_off(w * 64 + nt * 32, ks * 16) + l8;
        bf16x8 kvH = *(const bf16x8*)((const short*)(kvbH + base));
        bf16x8 kvL = *(const bf16x8*)((const short*)(kvbL + base));
        MFB(qa_h0, kvH, acc[0][nt]); MFB(qa_l0, kvH, acc[0][nt]);
        MFB(qa_h0, kvL, acc[0][nt]);
        MFB(qa_h1, kvH, acc[1][nt]); MFB(qa_l1, kvH, acc[1][nt]);
        MFB(qa_h1, kvL, acc[1][nt]);
      }
    }
  }

  // ---- epilogue: plain fp32 o[b*L + n*64 + row][h*256 + w*64 + nt*32 + i31] ----
  float* op = o + ((size_t)(b * L_ + n * 64)) * 2048 + h * 256 + w * 64;
  #pragma unroll
  for (int mt = 0; mt < 2; ++mt)
    #pragma unroll
    for (int nt = 0; nt < 2; ++nt)
      #pragma unroll
      for (int r = 0; r < 16; ++r) {
        int row = mt * 32 + (r & 3) + 8 * (r >> 2) + 4 * G;
        op[(size_t)row * 2048 + nt * 32 + i31] = acc[mt][nt][r];
      }
}

// ---------------------------------------------------------------------------
extern "C" void kernel_launch(void* const* d_in, const int* in_sizes, int n_in,
                              void* d_out, int out_size, void* d_ws, size_t ws_size,
                              hipStream_t stream) {
  const float* hs   = (const float*)d_in[0];
  const float* fcos = (const float*)d_in[1];
  const float* fsin = (const float*)d_in[2];
  // d_in[3] = mask (all ones, unused)
  const float* Wq  = (const float*)d_in[4];
  const float* Wk  = (const float*)d_in[5];
  const float* Wv  = (const float*)d_in[6];
  const float* Wo  = (const float*)d_in[7];
  const float* fmq = (const float*)d_in[8];
  const float* fmk = (const float*)d_in[9];
  float* out = (float*)d_out;

  float* ws = (float*)d_ws;
  float* q  = ws;                                   // 32MB (later o fp32)
  float* k  = q  + (size_t)M_ * 2048;               // 4MB
  float* v  = k  + (size_t)M_ * 256;                // 4MB
  float* qf = v  + (size_t)M_ * 256;                // 16MB (later oHt)
  float* kf = qf + (size_t)B_ * H_ * L_ * F_;       // 16MB (later oLt)
  float* kvr = kf + (size_t)B_ * H_ * L_ * F_;      // 64MB region

  // tiled bf16 scratch aliased into kv region (dead before chunk_kv writes)
  u16* hsHt = (u16*)kvr;                      // 16 MB
  u16* hsLt = hsHt + (size_t)M_ * 2048;       // 16 MB
  u16* WTh  = hsLt + (size_t)M_ * 2048;       // 10 MB
  // split frag-tiled kv prefix (replaces fp32 kvc; same 64MB region)
  u16* kvbH = (u16*)kvr;                      // 32 MB
  u16* kvbL = kvbH + (size_t)512 * 32768;     // 32 MB
  // after chunk_attn: kvb dead -> WoTh reuses kv region
  u16* WoTh = (u16*)kvr;                      // 8 MB
  // o fp32 in q region (q dead after hedgehog); tiled o in qf/kf regions
  float* o  = q;
  u16* oHt  = (u16*)qf;
  u16* oLt  = (u16*)kf;

  // 1) Fused prep: hs split + Wq/Wk/Wv tiling
  prep_kernel<<<4096 + 1280, 256, 0, stream>>>(hs, Wq, Wk, Wv, hsHt, hsLt, WTh);
  // 2a) q projection: pipelined 8-wave body, 256 blocks
  mfma_q<<<dim3(16, 16), 512, 0, stream>>>(hsHt, hsLt, WTh, q);
  // 2b) k/v projections: old body, 256 blocks
  mfma_kv<<<dim3(4, 64), 128, 0, stream>>>(hsHt, hsLt, WTh, k, v);
  // 3) Fused RoPE + hedgehog
  hedgehog_kernel<<<2048 + 2048, 256, 0, stream>>>(q, k, fmq, fmk, fcos, fsin, qf, kf);
  // 4) Per-chunk k^T v outer products -> split frag-tiled bf16; in-place scan
  chunk_kv_kernel<<<B_ * H_ * NC_, 256, 0, stream>>>(kf, v, kvbH, kvbL);
  chunk_scan_kernel<<<256, 256, 0, stream>>>(kvbH, kvbL);
  // 5) MFMA inter+intra chunk attention -> fp32 o
  chunk_attn_kernel<<<B_ * H_ * NC_, 256, 0, stream>>>(qf, kf, v, kvbH, kvbL, o);
  // 5b) o -> A-tiled split bf16
  prep_o<<<4096, 256, 0, stream>>>(o, oHt, oLt);
  // 6) Output projection
  wtrans_wo<<<dim3(16, 64), 256, 0, stream>>>(Wo, WoTh);
  mfma_wo<<<dim3(16, 16), 512, 0, stream>>>(oHt, oLt, WoTh, out);
}

// Round 5
// 537.882 us; speedup vs baseline: 1.0382x; 1.0382x over previous
//
#include <hip/hip_runtime.h>

#define B_ 2
#define L_ 2048
#define D_ 2048
#define H_ 8
#define HD_ 256
#define FD_ 64
#define F_ 128          // 2*FD
#define NC_ 32          // L/CHUNK
#define M_ (B_*L_)      // 4096
#define SCALE_Q 0.08838834764831845f   // 128^-0.5

typedef unsigned short u16;
typedef __attribute__((ext_vector_type(8))) short bf16x8;
typedef __attribute__((ext_vector_type(8))) unsigned short u16x8;
typedef __attribute__((ext_vector_type(16))) float f32x16;
typedef __attribute__((ext_vector_type(4))) unsigned int u32x4;

#define FMA4(a_, s_, v_) { (a_).x += (s_)*(v_).x; (a_).y += (s_)*(v_).y; \
                           (a_).z += (s_)*(v_).z; (a_).w += (s_)*(v_).w; }

// ---------------------------------------------------------------------------
// Tiled operand layouts (read-major: memory order == MFMA fragment order).
// 512-u16 chunk (one 32xK16 fragment set): addr = ((k>>3)&1)*256 + (x&31)*8
// + (k&7). Lane l reads u16x8 at chunk + l*8 -> (x = l&31, k = ks*16 +
// (l>>5)*8 + elem). Symmetric between A-frags and B-frags.
// ---------------------------------------------------------------------------

__device__ __forceinline__ u16 bf16_rne(float x) {
  unsigned u = __float_as_uint(x);
  return (u16)((u + 0x7fffu + ((u >> 16) & 1u)) >> 16);
}
__device__ __forceinline__ void bf16_split(float x, u16& h, u16& l) {
  unsigned u = __float_as_uint(x);
  unsigned hb = (u + 0x7fffu + ((u >> 16) & 1u)) >> 16;
  h = (u16)hb;
  float hf = __uint_as_float(hb << 16);
  l = bf16_rne(x - hf);
}

__device__ __forceinline__ void gl_lds16(const u16* g, u16* l) {
  __builtin_amdgcn_global_load_lds(
      (const __attribute__((address_space(1))) unsigned int*)g,
      (__attribute__((address_space(3))) unsigned int*)l, 16, 0, 0);
}

// kvb frag-tiled offset: per-chunk [2 d-panel][4 f-kt][4096] (F=128,HD=256).
__device__ __forceinline__ size_t kvb_off(int d, int f) {
  return (size_t)(((d >> 7) & 1) * 16384 + ((f >> 5) & 3) * 4096 +
                  ((d >> 6) & 1) * 2048 + ((f >> 4) & 1) * 1024 +
                  ((d >> 5) & 1) * 512 + ((f >> 3) & 1) * 256 +
                  (d & 31) * 8 + (f & 7));
}
// vb frag-tiled offset: per-chunk (J=64,HD=256) -> 16384 u16.
__device__ __forceinline__ size_t vb_off(int d, int j) {
  return (size_t)(((d >> 7) & 1) * 8192 + ((j >> 5) & 1) * 4096 +
                  ((d >> 6) & 1) * 2048 + ((j >> 4) & 1) * 1024 +
                  ((d >> 5) & 1) * 512 + ((j >> 3) & 1) * 256 +
                  (d & 31) * 8 + (j & 7));
}

// ---------------------------------------------------------------------------
// W[K=2048][Nsrc] fp32 -> B-tiled bf16 (panel P, ktile kt).
// ---------------------------------------------------------------------------
__device__ __forceinline__ void wtrans_body(const float* __restrict__ W, int Nsrc,
                                            int n0, u16* __restrict__ dst,
                                            int P, int kt) {
  int t = threadIdx.x;
  int nn = t & 127, kh = t >> 7;
  const float* src = W + (size_t)(kt * 32 + kh * 16) * Nsrc + n0 + nn;
  u16x8 u0, u1;
  #pragma unroll
  for (int kk = 0; kk < 8; ++kk) u0[kk] = bf16_rne(src[(size_t)kk * Nsrc]);
  #pragma unroll
  for (int kk = 0; kk < 8; ++kk) u1[kk] = bf16_rne(src[(size_t)(kk + 8) * Nsrc]);
  size_t base = ((size_t)P * 64 + kt) * 4096 + (size_t)((nn >> 6) & 1) * 2048
              + (size_t)kh * 1024 + (size_t)((nn >> 5) & 1) * 512
              + (size_t)(nn & 31) * 8;
  *(u16x8*)(dst + base) = u0;
  *(u16x8*)(dst + base + 256) = u1;
}

__global__ __launch_bounds__(256)
void prep_kernel(const float* __restrict__ hs,
                 const float* __restrict__ Wq, const float* __restrict__ Wk,
                 const float* __restrict__ Wv,
                 u16* __restrict__ hsHt, u16* __restrict__ hsLt,
                 u16* __restrict__ WTh) {
  int bid = blockIdx.x;
  if (bid < 4096) {
    int gid = bid * 256 + threadIdx.x;
    int r = gid >> 8, u = gid & 255;
    const float* src = hs + (size_t)r * 2048 + u * 8;
    float4 v0 = *(const float4*)src, v1 = *(const float4*)(src + 4);
    float vals[8] = {v0.x, v0.y, v0.z, v0.w, v1.x, v1.y, v1.z, v1.w};
    u16x8 hv, lv;
    #pragma unroll
    for (int j = 0; j < 8; ++j) { u16 hh, ll; bf16_split(vals[j], hh, ll); hv[j] = hh; lv[j] = ll; }
    size_t off = ((size_t)(r >> 6) * 64 + (u >> 2)) * 2048
               + (size_t)((u >> 1) & 1) * 1024 + (size_t)((r >> 5) & 1) * 512
               + (size_t)(u & 1) * 256 + (size_t)(r & 31) * 8;
    *(u16x8*)(hsHt + off) = hv;
    *(u16x8*)(hsLt + off) = lv;
  } else {
    int idx = bid - 4096;
    int P = idx >> 6, kt = idx & 63;
    const float* W; int Nsrc, n0;
    if (P < 16)      { W = Wq; Nsrc = 2048; n0 = P * 128; }
    else if (P < 18) { W = Wk; Nsrc = 256;  n0 = (P - 16) * 128; }
    else             { W = Wv; Nsrc = 256;  n0 = (P - 18) * 128; }
    wtrans_body(W, Nsrc, n0, WTh, P, kt);
  }
}

// o fp32 [4096][2048] -> A-tiled split bf16.
__global__ __launch_bounds__(256)
void prep_o(const float* __restrict__ o, u16* __restrict__ oHt,
            u16* __restrict__ oLt) {
  int gid = blockIdx.x * 256 + threadIdx.x;
  int r = gid >> 8, u = gid & 255;
  const float* src = o + (size_t)r * 2048 + u * 8;
  float4 v0 = *(const float4*)src, v1 = *(const float4*)(src + 4);
  float vals[8] = {v0.x, v0.y, v0.z, v0.w, v1.x, v1.y, v1.z, v1.w};
  u16x8 hv, lv;
  #pragma unroll
  for (int j = 0; j < 8; ++j) { u16 hh, ll; bf16_split(vals[j], hh, ll); hv[j] = hh; lv[j] = ll; }
  size_t off = ((size_t)(r >> 6) * 64 + (u >> 2)) * 2048
             + (size_t)((u >> 1) & 1) * 1024 + (size_t)((r >> 5) & 1) * 512
             + (size_t)(u & 1) * 256 + (size_t)(r & 31) * 8;
  *(u16x8*)(oHt + off) = hv;
  *(u16x8*)(oLt + off) = lv;
}

// v fp32 chunk [64 j][256 d] -> frag-tiled split bf16 (shared by 8 heads).
__global__ __launch_bounds__(256)
void prep_v(const float* __restrict__ v, u16* __restrict__ vbH,
            u16* __restrict__ vbL) {
  int bn = blockIdx.x;                       // b*NC + n
  const float* vp = v + (size_t)bn * 64 * HD_;
  size_t cbout = (size_t)bn * 16384;
  int d = threadIdx.x;
  #pragma unroll
  for (int it = 0; it < 8; ++it) {
    int j0 = it * 8;
    u16x8 hv, lv;
    #pragma unroll
    for (int c = 0; c < 8; ++c) {
      u16 hh, ll; bf16_split(vp[(size_t)(j0 + c) * HD_ + d], hh, ll);
      hv[c] = hh; lv[c] = ll;
    }
    size_t off = cbout + vb_off(d, j0);
    *(u16x8*)(vbH + off) = hv;
    *(u16x8*)(vbL + off) = lv;
  }
}

__global__ __launch_bounds__(256)
void wtrans_wo(const float* __restrict__ Wo, u16* __restrict__ WoTh) {
  wtrans_body(Wo, 2048, blockIdx.x * 128, WoTh, blockIdx.x, blockIdx.y);
}

// ---------------------------------------------------------------------------
// OLD 2-pass split-bf16 MFMA GEMM (64x128 tile, BK=32, 128 threads).
// Kept for the small k/v projection.
// ---------------------------------------------------------------------------
__device__ __forceinline__ void mfma_body(
    const u16* __restrict__ AtH, const u16* __restrict__ AtL,
    const u16* __restrict__ Bt, float* __restrict__ C, int cstride,
    int bm, int bn) {
  __shared__ __align__(16) u16 AsH[2048];
  __shared__ __align__(16) u16 AsL[2048];
  __shared__ __align__(16) u16 Bs[4096];
  const int t = threadIdx.x, lane = t & 63, wv = t >> 6;
  const u16* aSrc = (wv ? AtL : AtH) + (size_t)bm * 131072 + lane * 8;
  const u16* bSrc = Bt + (size_t)bn * 262144 + wv * 2048 + lane * 8;
  u16* aDst = wv ? AsL : AsH;
  u16* bDst = Bs + wv * 2048;

  f32x16 acc[2][2];
  #pragma unroll
  for (int a = 0; a < 2; ++a)
    #pragma unroll
    for (int b2 = 0; b2 < 2; ++b2)
      #pragma unroll
      for (int r = 0; r < 16; ++r) acc[a][b2][r] = 0.f;

  for (int kt = 0; kt < 64; ++kt) {
    const u16* ak = aSrc + (size_t)kt * 2048;
    const u16* bk = bSrc + (size_t)kt * 4096;
    __syncthreads();
    #pragma unroll
    for (int c = 0; c < 4; ++c) {
      gl_lds16(ak + c * 512, aDst + c * 512);
      gl_lds16(bk + c * 512, bDst + c * 512);
    }
    __syncthreads();

    #pragma unroll
    for (int ks = 0; ks < 2; ++ks) {
      const u16* ph = AsH + ks * 1024 + lane * 8;
      const u16* pl = AsL + ks * 1024 + lane * 8;
      const u16* pb = Bs + wv * 2048 + ks * 1024 + lane * 8;
      bf16x8 a0 = *(const bf16x8*)ph;
      bf16x8 a1 = *(const bf16x8*)(ph + 512);
      bf16x8 b0 = *(const bf16x8*)pb;
      bf16x8 b1 = *(const bf16x8*)(pb + 512);
      acc[0][0] = __builtin_amdgcn_mfma_f32_32x32x16_bf16(a0, b0, acc[0][0], 0, 0, 0);
      acc[0][1] = __builtin_amdgcn_mfma_f32_32x32x16_bf16(a0, b1, acc[0][1], 0, 0, 0);
      acc[1][0] = __builtin_amdgcn_mfma_f32_32x32x16_bf16(a1, b0, acc[1][0], 0, 0, 0);
      acc[1][1] = __builtin_amdgcn_mfma_f32_32x32x16_bf16(a1, b1, acc[1][1], 0, 0, 0);
      bf16x8 l0 = *(const bf16x8*)pl;
      bf16x8 l1 = *(const bf16x8*)(pl + 512);
      acc[0][0] = __builtin_amdgcn_mfma_f32_32x32x16_bf16(l0, b0, acc[0][0], 0, 0, 0);
      acc[0][1] = __builtin_amdgcn_mfma_f32_32x32x16_bf16(l0, b1, acc[0][1], 0, 0, 0);
      acc[1][0] = __builtin_amdgcn_mfma_f32_32x32x16_bf16(l1, b0, acc[1][0], 0, 0, 0);
      acc[1][1] = __builtin_amdgcn_mfma_f32_32x32x16_bf16(l1, b1, acc[1][1], 0, 0, 0);
    }
  }

  const int fr = lane & 31, g = lane >> 5;
  float* Cp = C + (size_t)(bm * 64) * cstride + wv * 64;
  #pragma unroll
  for (int mt = 0; mt < 2; ++mt)
    #pragma unroll
    for (int nt = 0; nt < 2; ++nt) {
      #pragma unroll
      for (int r = 0; r < 16; ++r) {
        int row = mt * 32 + (r & 3) + 8 * (r >> 2) + 4 * g;
        Cp[(size_t)row * cstride + nt * 32 + fr] = acc[mt][nt][r];
      }
    }
}

// ---------------------------------------------------------------------------
// Pipelined body, now PHASE-SPLIT (T3): each BK=32 step = two phases of
// {6 ds_read + partial stage -> s_barrier -> lgkmcnt(0) -> setprio(1) ->
//  8 MFMA -> setprio(0) -> s_barrier}; counted vmcnt(5) once per K-step.
// Triple-buffered ring (3 x 40 KB), 8 waves, 256x128 tile.
// ---------------------------------------------------------------------------
#define SUB_ 20480
#define MFB(a_, b_, c_) (c_) = __builtin_amdgcn_mfma_f32_32x32x16_bf16((a_), (b_), (c_), 0, 0, 0)

__device__ __forceinline__ void mfma_big_body(
    const u16* __restrict__ AtH, const u16* __restrict__ AtL,
    const u16* __restrict__ Bt, float* __restrict__ C, int cstride,
    int bm, int bn) {
  __shared__ __align__(16) u16 lds[3 * SUB_];
  const int t = threadIdx.x, lane = t & 63, wv = t >> 6;
  const int wm = wv >> 1, wn = wv & 1;

  // 40 staging lines of 1 KB per K-step; 5 per wave (0-15 A_H, 16-31 A_L, 32-39 B)
  const u16* gs[5];
  unsigned lo[5], gst[5];
  #pragma unroll
  for (int j = 0; j < 5; ++j) {
    int line = wv * 5 + j;
    if (line < 16) {
      gs[j] = AtH + ((size_t)(4 * bm + (line >> 2)) * 64) * 2048
                  + (size_t)(line & 3) * 512 + lane * 8;
      lo[j] = line * 512; gst[j] = 2048;
    } else if (line < 32) {
      int l2 = line - 16;
      gs[j] = AtL + ((size_t)(4 * bm + (l2 >> 2)) * 64) * 2048
                  + (size_t)(l2 & 3) * 512 + lane * 8;
      lo[j] = 8192 + l2 * 512; gst[j] = 2048;
    } else {
      int l3 = line - 32;
      gs[j] = Bt + (size_t)bn * 262144 + (size_t)l3 * 512 + lane * 8;
      lo[j] = 16384 + l3 * 512; gst[j] = 4096;
    }
  }

  f32x16 acc[2][2];
  #pragma unroll
  for (int a = 0; a < 2; ++a)
    #pragma unroll
    for (int b2 = 0; b2 < 2; ++b2)
      #pragma unroll
      for (int r = 0; r < 16; ++r) acc[a][b2][r] = 0.f;

  // prologue: fill slots 0,1; wait slot 0 only (5 newest stay in flight)
  #pragma unroll
  for (int j = 0; j < 5; ++j) gl_lds16(gs[j], lds + lo[j]);
  #pragma unroll
  for (int j = 0; j < 5; ++j) gl_lds16(gs[j] + gst[j], lds + SUB_ + lo[j]);
  asm volatile("s_waitcnt vmcnt(5)" ::: "memory");
  __builtin_amdgcn_s_barrier();
  __builtin_amdgcn_sched_barrier(0);

  int cb = 0;
  for (int kt = 0; kt < 64; ++kt) {
    int sb = cb + 2 * SUB_; if (sb >= 3 * SUB_) sb -= 3 * SUB_;
    const u16* base = lds + cb;
    const u16* ph0 = base + wm * 2048 + lane * 8;
    const u16* pb0 = base + 16384 + wn * 2048 + lane * 8;

    // -------- phase A (ks=0): 6 ds_read, stage lines 0-2, 8 MFMA --------
    bf16x8 a0 = *(const bf16x8*)(ph0);
    bf16x8 a1 = *(const bf16x8*)(ph0 + 512);
    bf16x8 l0 = *(const bf16x8*)(ph0 + 8192);
    bf16x8 l1 = *(const bf16x8*)(ph0 + 8704);
    bf16x8 b0 = *(const bf16x8*)(pb0);
    bf16x8 b1 = *(const bf16x8*)(pb0 + 512);
    if (kt < 62) {
      gl_lds16(gs[0] + (size_t)(kt + 2) * gst[0], lds + sb + lo[0]);
      gl_lds16(gs[1] + (size_t)(kt + 2) * gst[1], lds + sb + lo[1]);
      gl_lds16(gs[2] + (size_t)(kt + 2) * gst[2], lds + sb + lo[2]);
    }
    __builtin_amdgcn_s_barrier();
    asm volatile("s_waitcnt lgkmcnt(0)" ::: "memory");
    __builtin_amdgcn_sched_barrier(0);
    __builtin_amdgcn_s_setprio(1);
    MFB(a0, b0, acc[0][0]); MFB(a0, b1, acc[0][1]);
    MFB(a1, b0, acc[1][0]); MFB(a1, b1, acc[1][1]);
    MFB(l0, b0, acc[0][0]); MFB(l0, b1, acc[0][1]);
    MFB(l1, b0, acc[1][0]); MFB(l1, b1, acc[1][1]);
    __builtin_amdgcn_s_setprio(0);
    __builtin_amdgcn_s_barrier();
    __builtin_amdgcn_sched_barrier(0);

    // -------- phase B (ks=1): 6 ds_read, stage lines 3-4, 8 MFMA --------
    bf16x8 c0 = *(const bf16x8*)(ph0 + 1024);
    bf16x8 c1 = *(const bf16x8*)(ph0 + 1536);
    bf16x8 m0 = *(const bf16x8*)(ph0 + 9216);
    bf16x8 m1 = *(const bf16x8*)(ph0 + 9728);
    bf16x8 d0 = *(const bf16x8*)(pb0 + 1024);
    bf16x8 d1 = *(const bf16x8*)(pb0 + 1536);
    if (kt < 62) {
      gl_lds16(gs[3] + (size_t)(kt + 2) * gst[3], lds + sb + lo[3]);
      gl_lds16(gs[4] + (size_t)(kt + 2) * gst[4], lds + sb + lo[4]);
    }
    __builtin_amdgcn_s_barrier();
    asm volatile("s_waitcnt lgkmcnt(0)" ::: "memory");
    __builtin_amdgcn_sched_barrier(0);
    __builtin_amdgcn_s_setprio(1);
    MFB(c0, d0, acc[0][0]); MFB(c0, d1, acc[0][1]);
    MFB(c1, d0, acc[1][0]); MFB(c1, d1, acc[1][1]);
    MFB(m0, d0, acc[0][0]); MFB(m0, d1, acc[0][1]);
    MFB(m1, d0, acc[1][0]); MFB(m1, d1, acc[1][1]);
    __builtin_amdgcn_s_setprio(0);
    if (kt < 62) asm volatile("s_waitcnt vmcnt(5)" ::: "memory");
    else         asm volatile("s_waitcnt vmcnt(0)" ::: "memory");
    __builtin_amdgcn_s_barrier();
    __builtin_amdgcn_sched_barrier(0);
    cb += SUB_; if (cb == 3 * SUB_) cb = 0;
  }

  const int fr = lane & 31, g = lane >> 5;
  float* Cp = C + (size_t)(bm * 256 + wm * 64) * cstride + wn * 64;
  #pragma unroll
  for (int mt = 0; mt < 2; ++mt)
    #pragma unroll
    for (int nt = 0; nt < 2; ++nt) {
      #pragma unroll
      for (int r = 0; r < 16; ++r) {
        int row = mt * 32 + (r & 3) + 8 * (r >> 2) + 4 * g;
        Cp[(size_t)row * cstride + nt * 32 + fr] = acc[mt][nt][r];
      }
    }
}

__global__ __launch_bounds__(512, 2)
void mfma_q(const u16* __restrict__ hsHt, const u16* __restrict__ hsLt,
            const u16* __restrict__ WTh, float* __restrict__ q) {
  mfma_big_body(hsHt, hsLt, WTh, q + blockIdx.x * 128, 2048,
                blockIdx.y, blockIdx.x);
}

__global__ __launch_bounds__(128, 4)
void mfma_kv(const u16* __restrict__ hsHt, const u16* __restrict__ hsLt,
             const u16* __restrict__ WTh,
             float* __restrict__ k, float* __restrict__ v) {
  int bn = blockIdx.x;
  float* Cb; int co;
  if (bn < 2) { Cb = k; co = bn * 128; }
  else        { Cb = v; co = (bn - 2) * 128; }
  mfma_body(hsHt, hsLt, WTh, Cb + co, 256, blockIdx.y, 16 + bn);
}

__global__ __launch_bounds__(512, 2)
void mfma_wo(const u16* __restrict__ oHt, const u16* __restrict__ oLt,
             const u16* __restrict__ WoTh, float* __restrict__ out) {
  mfma_big_body(oHt, oLt, WoTh, out + blockIdx.x * 128, 2048,
                blockIdx.y, blockIdx.x);
}

__device__ __forceinline__ float wave_max64(float v) {
  #pragma unroll
  for (int off = 32; off > 0; off >>= 1) v = fmaxf(v, __shfl_xor(v, off, 64));
  return v;
}
__device__ __forceinline__ float wave_sum64(float v) {
  #pragma unroll
  for (int off = 32; off > 0; off >>= 1) v += __shfl_xor(v, off, 64);
  return v;
}

// ---------------------------------------------------------------------------
// Fused RoPE + hedgehog (unchanged).
// ---------------------------------------------------------------------------
__global__ __launch_bounds__(256)
void hedgehog_kernel(const float* __restrict__ q, const float* __restrict__ kx,
                     const float* __restrict__ fmq, const float* __restrict__ fmk,
                     const float* __restrict__ cosb, const float* __restrict__ sinb,
                     float* __restrict__ qf, float* __restrict__ kf) {
  __shared__ __align__(16) float rows[4][4][256];
  int bid = blockIdx.x;
  const float* x; const float* fm; float* out; int nh_in, gb;
  if (bid < 2048) { x = q;  fm = fmq; out = qf; nh_in = 8; gb = bid * 4; }
  else            { x = kx; fm = fmk; out = kf; nh_in = 1; gb = (bid - 2048) * 4; }
  int wave = threadIdx.x >> 6, lane = threadIdx.x & 63;
  int g = gb + wave;
  int l4 = g & (L_/4 - 1);
  int bh = g / (L_/4);
  int h = bh & 7, b = bh >> 3;
  int l0 = l4 * 4;
  size_t rstride = (nh_in == 1) ? (size_t)HD_ : (size_t)H_ * HD_;
  const float* xrow = (nh_in == 1)
      ? x + (size_t)(b * L_ + l0) * HD_
      : x + ((size_t)(b * L_ + l0) * H_ + h) * HD_;
  int dd = (lane & 31) * 4;
  #pragma unroll
  for (int r = 0; r < 4; ++r) {
    float4 v = *(const float4*)(xrow + r * rstride + lane * 4);
    float4 u;
    u.x = __shfl_xor(v.x, 32, 64); u.y = __shfl_xor(v.y, 32, 64);
    u.z = __shfl_xor(v.z, 32, 64); u.w = __shfl_xor(v.w, 32, 64);
    int l = l0 + r;
    float4 c = *(const float4*)(cosb + (size_t)l * 128 + dd);
    float4 s = *(const float4*)(sinb + (size_t)l * 128 + dd);
    float4 ro;
    if (lane < 32) {
      ro.x = v.x * c.x - u.x * s.x; ro.y = v.y * c.y - u.y * s.y;
      ro.z = v.z * c.z - u.z * s.z; ro.w = v.w * c.w - u.w * s.w;
    } else {
      ro.x = u.x * s.x + v.x * c.x; ro.y = u.y * s.y + v.y * c.y;
      ro.z = u.z * s.z + v.z * c.z; ro.w = u.w * s.w + v.w * c.w;
    }
    *(float4*)&rows[wave][r][lane * 4] = ro;
  }
  __syncthreads();

  const float* fmh = fm + (size_t)h * HD_ * FD_;
  float p0 = 0.f, p1 = 0.f, p2 = 0.f, p3 = 0.f;
  for (int d2 = 0; d2 < HD_; d2 += 4) {
    float w0 = fmh[(d2 + 0) * FD_ + lane];
    float w1 = fmh[(d2 + 1) * FD_ + lane];
    float w2 = fmh[(d2 + 2) * FD_ + lane];
    float w3 = fmh[(d2 + 3) * FD_ + lane];
    float4 r0 = *(const float4*)&rows[wave][0][d2];
    float4 r1 = *(const float4*)&rows[wave][1][d2];
    float4 r2 = *(const float4*)&rows[wave][2][d2];
    float4 r3 = *(const float4*)&rows[wave][3][d2];
    p0 += r0.x * w0 + r0.y * w1 + r0.z * w2 + r0.w * w3;
    p1 += r1.x * w0 + r1.y * w1 + r1.z * w2 + r1.w * w3;
    p2 += r2.x * w0 + r2.y * w1 + r2.z * w2 + r2.w * w3;
    p3 += r3.x * w0 + r3.y * w1 + r3.z * w2 + r3.w * w3;
  }
  float p[4] = {p0, p1, p2, p3};
  #pragma unroll
  for (int r = 0; r < 4; ++r) {
    float m = wave_max64(fabsf(p[r]));
    float e1 = __expf(p[r] - m);
    float e2 = __expf(-p[r] - m);
    float z = wave_sum64(e1 + e2);
    float inv = 1.0f / z;
    size_t base = ((size_t)bh * L_ + l0 + r) * F_;
    out[base + lane]      = e1 * inv;
    out[base + 64 + lane] = e2 * inv;
  }
}

// ---------------------------------------------------------------------------
// Phase A: per-chunk kv_n[f][d] outer products -> frag-tiled split bf16.
// ---------------------------------------------------------------------------
__global__ __launch_bounds__(256)
void chunk_kv_kernel(const float* __restrict__ kf, const float* __restrict__ v,
                     u16* __restrict__ kvbH, u16* __restrict__ kvbL) {
  __shared__ __align__(16) float kfs[64][128];
  int n = blockIdx.x & (NC_ - 1), bh = blockIdx.x >> 5;
  int b = bh >> 3;
  const float* kfp = kf + ((size_t)bh * L_ + (size_t)n * 64) * F_;
  int t = threadIdx.x;
  #pragma unroll
  for (int it = 0; it < 8; ++it) {
    int flat = t * 4 + it * 1024;
    *(float4*)&kfs[flat >> 7][flat & 127] = *(const float4*)(kfp + flat);
  }
  __syncthreads();
  int dg = t & 63;
  int fg = t >> 6;
  const float* vp = v + (size_t)(b * L_ + n * 64) * HD_ + dg * 4;
  size_t cb = (size_t)blockIdx.x * 32768;
  #pragma unroll
  for (int pass = 0; pass < 4; ++pass) {
    int f0 = fg * 8 + pass * 32;
    float4 acc[8];
    #pragma unroll
    for (int i = 0; i < 8; ++i) acc[i] = make_float4(0.f, 0.f, 0.f, 0.f);
    for (int j = 0; j < 64; ++j) {
      float4 vv = *(const float4*)(vp + (size_t)j * HD_);
      float4 ka = *(const float4*)&kfs[j][f0];
      float4 kb = *(const float4*)&kfs[j][f0 + 4];
      FMA4(acc[0], ka.x, vv); FMA4(acc[1], ka.y, vv);
      FMA4(acc[2], ka.z, vv); FMA4(acc[3], ka.w, vv);
      FMA4(acc[4], kb.x, vv); FMA4(acc[5], kb.y, vv);
      FMA4(acc[6], kb.z, vv); FMA4(acc[7], kb.w, vv);
    }
    #pragma unroll
    for (int c = 0; c < 4; ++c) {
      u16x8 hv, lv;
      #pragma unroll
      for (int ff = 0; ff < 8; ++ff) {
        float xs = (c == 0) ? acc[ff].x : (c == 1) ? acc[ff].y
                 : (c == 2) ? acc[ff].z : acc[ff].w;
        u16 hh, ll; bf16_split(xs, hh, ll); hv[ff] = hh; lv[ff] = ll;
      }
      int d = dg * 4 + c;
      size_t off = cb + kvb_off(d, f0);
      *(u16x8*)(kvbH + off) = hv;
      *(u16x8*)(kvbL + off) = lv;
    }
  }
}

// Phase B: in-place exclusive prefix over the 32 chunks, on split bf16.
__global__ __launch_bounds__(256)
void chunk_scan_kernel(u16* __restrict__ kvbH, u16* __restrict__ kvbL) {
  int bh = blockIdx.x >> 4, g = blockIdx.x & 15;
  int d = threadIdx.x;
  size_t off = kvb_off(d, g * 8);
  float run[8] = {0.f, 0.f, 0.f, 0.f, 0.f, 0.f, 0.f, 0.f};
  for (int n = 0; n < NC_; ++n) {
    size_t a = ((size_t)(bh * 32 + n)) * 32768 + off;
    u16x8 hv = *(u16x8*)(kvbH + a);
    u16x8 lv = *(u16x8*)(kvbL + a);
    u16x8 oh, ol;
    #pragma unroll
    for (int c = 0; c < 8; ++c) {
      float val = __uint_as_float((unsigned)hv[c] << 16)
                + __uint_as_float((unsigned)lv[c] << 16);
      u16 hh, ll; bf16_split(run[c], hh, ll); oh[c] = hh; ol[c] = ll;
      run[c] += val;
    }
    *(u16x8*)(kvbH + a) = oh;
    *(u16x8*)(kvbL + a) = ol;
  }
}

// ---------------------------------------------------------------------------
// Phase C (MFMA): v now read as pre-tiled split frags (prep_v) - removes
// 64 scalar loads + 64 splits per thread and the 8x per-head redundancy.
// ---------------------------------------------------------------------------
__global__ __launch_bounds__(256, 2)
void chunk_attn_kernel(const float* __restrict__ qf, const float* __restrict__ kf,
                       const u16* __restrict__ vbH, const u16* __restrict__ vbL,
                       const u16* __restrict__ kvbH, const u16* __restrict__ kvbL,
                       float* __restrict__ o) {
  __shared__ __align__(16) u16 lds[32768];   // qsH|qsL|kfH|kfL
  const int n = blockIdx.x & (NC_ - 1), bh = blockIdx.x >> 5;
  const int h = bh & 7, b = bh >> 3;
  const int t = threadIdx.x;
  const int w = t >> 6, i31 = t & 31, G = (t >> 5) & 1;
  const int l8 = (t & 63) * 8;

  {
    const float* qp = qf + ((size_t)bh * L_ + (size_t)n * 64) * F_;
    const float* kp = kf + ((size_t)bh * L_ + (size_t)n * 64) * F_;
    int o8 = t & 15, ib = t >> 4;
    #pragma unroll
    for (int iter = 0; iter < 4; ++iter) {
      int i = ib + iter * 16;
      int it = i >> 5, ks = o8 >> 1;
      int sub = (it * 8 + ks) * 512 + (o8 & 1) * 256 + (i & 31) * 8;
      {
        const float* src = qp + (size_t)i * 128 + o8 * 8;
        float4 a = *(const float4*)src, c = *(const float4*)(src + 4);
        float vals[8] = {a.x, a.y, a.z, a.w, c.x, c.y, c.z, c.w};
        u16x8 hv, lv;
        #pragma unroll
        for (int j = 0; j < 8; ++j) {
          u16 hh, ll; bf16_split(vals[j] * SCALE_Q, hh, ll);
          hv[j] = hh; lv[j] = ll;
        }
        *(u16x8*)(lds + sub) = hv;
        *(u16x8*)(lds + 8192 + sub) = lv;
      }
      {
        const float* src = kp + (size_t)i * 128 + o8 * 8;
        float4 a = *(const float4*)src, c = *(const float4*)(src + 4);
        float vals[8] = {a.x, a.y, a.z, a.w, c.x, c.y, c.z, c.w};
        u16x8 hv, lv;
        #pragma unroll
        for (int j = 0; j < 8; ++j) {
          u16 hh, ll; bf16_split(vals[j], hh, ll);
          hv[j] = hh; lv[j] = ll;
        }
        *(u16x8*)(lds + 16384 + sub) = hv;
        *(u16x8*)(lds + 24576 + sub) = lv;
      }
    }
  }
  __syncthreads();

  const u16* Lq  = lds;
  const u16* Lql = lds + 8192;
  const u16* Lk  = lds + 16384;
  const u16* Lkl = lds + 24576;

  // ---- phase S: sT = kf · qs^T (3-pass split) ----
  f32x16 st[2][2];
  #pragma unroll
  for (int a = 0; a < 2; ++a)
    #pragma unroll
    for (int c = 0; c < 2; ++c)
      #pragma unroll
      for (int r = 0; r < 16; ++r) st[a][c][r] = 0.f;

  #pragma unroll
  for (int ks = 0; ks < 8; ++ks) {
    bf16x8 kh0 = *(const bf16x8*)(Lk  + ks * 512 + l8);
    bf16x8 kh1 = *(const bf16x8*)(Lk  + (8 + ks) * 512 + l8);
    bf16x8 kl0 = *(const bf16x8*)(Lkl + ks * 512 + l8);
    bf16x8 kl1 = *(const bf16x8*)(Lkl + (8 + ks) * 512 + l8);
    bf16x8 qh0 = *(const bf16x8*)(Lq  + ks * 512 + l8);
    bf16x8 qh1 = *(const bf16x8*)(Lq  + (8 + ks) * 512 + l8);
    bf16x8 ql0 = *(const bf16x8*)(Lql + ks * 512 + l8);
    bf16x8 ql1 = *(const bf16x8*)(Lql + (8 + ks) * 512 + l8);
    MFB(kh0, qh0, st[0][0]); MFB(kh0, ql0, st[0][0]); MFB(kl0, qh0, st[0][0]);
    MFB(kh0, qh1, st[0][1]); MFB(kh0, ql1, st[0][1]); MFB(kl0, qh1, st[0][1]);
    MFB(kh1, qh0, st[1][0]); MFB(kh1, ql0, st[1][0]); MFB(kl1, qh0, st[1][0]);
    MFB(kh1, qh1, st[1][1]); MFB(kh1, ql1, st[1][1]); MFB(kl1, qh1, st[1][1]);
  }

  // ---- mask + split + cross-lane transpose: sT C-regs -> s A-frags ----
  bf16x8 sfH[2][4], sfL[2][4];
  #pragma unroll
  for (int mt = 0; mt < 2; ++mt) {
    int iv = mt * 32 + i31;
    #pragma unroll
    for (int ksj = 0; ksj < 4; ++ksj) {
      const int jt = ksj >> 1, kb = ksj & 1;
      unsigned ph[4], pl[4];
      #pragma unroll
      for (int half = 0; half < 2; ++half) {
        u16 hh[4], ll[4];
        #pragma unroll
        for (int c = 0; c < 4; ++c) {
          int r = 8 * kb + 4 * half + c;
          int jv = jt * 32 + (r & 3) + 8 * (r >> 2) + 4 * G;
          float mv = (jv <= iv) ? st[jt][mt][r] : 0.f;
          u16 h_, l_; bf16_split(mv, h_, l_);
          hh[c] = h_; ll[c] = l_;
        }
        ph[half * 2 + 0] = (unsigned)hh[0] | ((unsigned)hh[1] << 16);
        ph[half * 2 + 1] = (unsigned)hh[2] | ((unsigned)hh[3] << 16);
        pl[half * 2 + 0] = (unsigned)ll[0] | ((unsigned)ll[1] << 16);
        pl[half * 2 + 1] = (unsigned)ll[2] | ((unsigned)ll[3] << 16);
      }
      unsigned rH1 = (unsigned)__shfl_xor((int)(G ? ph[0] : ph[2]), 32, 64);
      unsigned rH2 = (unsigned)__shfl_xor((int)(G ? ph[1] : ph[3]), 32, 64);
      unsigned rL1 = (unsigned)__shfl_xor((int)(G ? pl[0] : pl[2]), 32, 64);
      unsigned rL2 = (unsigned)__shfl_xor((int)(G ? pl[1] : pl[3]), 32, 64);
      u32x4 wH, wL;
      wH[0] = G ? rH1 : ph[0]; wH[1] = G ? rH2 : ph[1];
      wH[2] = G ? ph[2] : rH1; wH[3] = G ? ph[3] : rH2;
      wL[0] = G ? rL1 : pl[0]; wL[1] = G ? rL2 : pl[1];
      wL[2] = G ? pl[2] : rL1; wL[3] = G ? pl[3] : rL2;
      sfH[mt][ksj] = __builtin_bit_cast(bf16x8, wH);
      sfL[mt][ksj] = __builtin_bit_cast(bf16x8, wL);
    }
  }

  f32x16 acc[2][2];
  #pragma unroll
  for (int a = 0; a < 2; ++a)
    #pragma unroll
    for (int c = 0; c < 2; ++c)
      #pragma unroll
      for (int r = 0; r < 16; ++r) acc[a][c][r] = 0.f;

  // ---- phase A (intra): acc += s · v, v frags pre-tiled (prep_v) ----
  {
    size_t vcb = ((size_t)(b * NC_ + n)) * 16384;
    #pragma unroll
    for (int nt = 0; nt < 2; ++nt) {
      #pragma unroll
      for (int ksj = 0; ksj < 4; ++ksj) {
        size_t basev = vcb + vb_off(w * 64 + nt * 32, ksj * 16) + l8;
        bf16x8 vH = *(const bf16x8*)((const short*)(vbH + basev));
        bf16x8 vL = *(const bf16x8*)((const short*)(vbL + basev));
        MFB(sfH[0][ksj], vH, acc[0][nt]); MFB(sfL[0][ksj], vH, acc[0][nt]);
        MFB(sfH[0][ksj], vL, acc[0][nt]);
        MFB(sfH[1][ksj], vH, acc[1][nt]); MFB(sfL[1][ksj], vH, acc[1][nt]);
        MFB(sfH[1][ksj], vL, acc[1][nt]);
      }
    }
  }

  // ---- phase I (inter): acc += qs · kv_cum ----
  {
    size_t cb = (size_t)blockIdx.x * 32768;
    #pragma unroll
    for (int ks = 0; ks < 8; ++ks) {
      bf16x8 qa_h0 = *(const bf16x8*)(Lq  + ks * 512 + l8);
      bf16x8 qa_h1 = *(const bf16x8*)(Lq  + (8 + ks) * 512 + l8);
      bf16x8 qa_l0 = *(const bf16x8*)(Lql + ks * 512 + l8);
      bf16x8 qa_l1 = *(const bf16x8*)(Lql + (8 + ks) * 512 + l8);
      #pragma unroll
      for (int nt = 0; nt < 2; ++nt) {
        size_t base = cb + kvb_off(w * 64 + nt * 32, ks * 16) + l8;
        bf16x8 kvH = *(const bf16x8*)((const short*)(kvbH + base));
        bf16x8 kvL = *(const bf16x8*)((const short*)(kvbL + base));
        MFB(qa_h0, kvH, acc[0][nt]); MFB(qa_l0, kvH, acc[0][nt]);
        MFB(qa_h0, kvL, acc[0][nt]);
        MFB(qa_h1, kvH, acc[1][nt]); MFB(qa_l1, kvH, acc[1][nt]);
        MFB(qa_h1, kvL, acc[1][nt]);
      }
    }
  }

  float* op = o + ((size_t)(b * L_ + n * 64)) * 2048 + h * 256 + w * 64;
  #pragma unroll
  for (int mt = 0; mt < 2; ++mt)
    #pragma unroll
    for (int nt = 0; nt < 2; ++nt)
      #pragma unroll
      for (int r = 0; r < 16; ++r) {
        int row = mt * 32 + (r & 3) + 8 * (r >> 2) + 4 * G;
        op[(size_t)row * 2048 + nt * 32 + i31] = acc[mt][nt][r];
      }
}

// ---------------------------------------------------------------------------
extern "C" void kernel_launch(void* const* d_in, const int* in_sizes, int n_in,
                              void* d_out, int out_size, void* d_ws, size_t ws_size,
                              hipStream_t stream) {
  const float* hs   = (const float*)d_in[0];
  const float* fcos = (const float*)d_in[1];
  const float* fsin = (const float*)d_in[2];
  // d_in[3] = mask (all ones, unused)
  const float* Wq  = (const float*)d_in[4];
  const float* Wk  = (const float*)d_in[5];
  const float* Wv  = (const float*)d_in[6];
  const float* Wo  = (const float*)d_in[7];
  const float* fmq = (const float*)d_in[8];
  const float* fmk = (const float*)d_in[9];
  float* out = (float*)d_out;

  float* ws = (float*)d_ws;
  float* q  = ws;                                   // 32MB (later o fp32)
  float* k  = q  + (size_t)M_ * 2048;               // 4MB (later vbH/vbL)
  float* v  = k  + (size_t)M_ * 256;                // 4MB
  float* qf = v  + (size_t)M_ * 256;                // 16MB (later oHt)
  float* kf = qf + (size_t)B_ * H_ * L_ * F_;       // 16MB (later oLt)
  float* kvr = kf + (size_t)B_ * H_ * L_ * F_;      // 64MB region

  u16* hsHt = (u16*)kvr;                      // 16 MB
  u16* hsLt = hsHt + (size_t)M_ * 2048;       // 16 MB
  u16* WTh  = hsLt + (size_t)M_ * 2048;       // 10 MB
  u16* kvbH = (u16*)kvr;                      // 32 MB
  u16* kvbL = kvbH + (size_t)512 * 32768;     // 32 MB
  u16* WoTh = (u16*)kvr;                      // 8 MB (after kvb dead)
  // v frag tiles live in the dead k region (4 MB exactly)
  u16* vbH  = (u16*)k;                        // 2 MB
  u16* vbL  = vbH + (size_t)64 * 16384;       // 2 MB
  float* o  = q;
  u16* oHt  = (u16*)qf;
  u16* oLt  = (u16*)kf;

  // 1) Fused prep: hs split + Wq/Wk/Wv tiling
  prep_kernel<<<4096 + 1280, 256, 0, stream>>>(hs, Wq, Wk, Wv, hsHt, hsLt, WTh);
  // 2a) q projection: phase-split pipelined body, 256 blocks
  mfma_q<<<dim3(16, 16), 512, 0, stream>>>(hsHt, hsLt, WTh, q);
  // 2b) k/v projections: old body, 256 blocks
  mfma_kv<<<dim3(4, 64), 128, 0, stream>>>(hsHt, hsLt, WTh, k, v);
  // 3) Fused RoPE + hedgehog (k fp32 dead afterwards)
  hedgehog_kernel<<<2048 + 2048, 256, 0, stream>>>(q, k, fmq, fmk, fcos, fsin, qf, kf);
  // 3b) v -> frag-tiled split bf16 (into dead k region)
  prep_v<<<B_ * NC_, 256, 0, stream>>>(v, vbH, vbL);
  // 4) Per-chunk k^T v outer products -> split frag-tiled bf16; in-place scan
  chunk_kv_kernel<<<B_ * H_ * NC_, 256, 0, stream>>>(kf, v, kvbH, kvbL);
  chunk_scan_kernel<<<256, 256, 0, stream>>>(kvbH, kvbL);
  // 5) MFMA inter+intra chunk attention -> fp32 o
  chunk_attn_kernel<<<B_ * H_ * NC_, 256, 0, stream>>>(qf, kf, vbH, vbL, kvbH, kvbL, o);
  // 5b) o -> A-tiled split bf16
  prep_o<<<4096, 256, 0, stream>>>(o, oHt, oLt);
  // 6) Output projection
  wtrans_wo<<<dim3(16, 64), 256, 0, stream>>>(Wo, WoTh);
  mfma_wo<<<dim3(16, 16), 512, 0, stream>>>(oHt, oLt, WoTh, out);
}

// Round 6
// 503.484 us; speedup vs baseline: 1.1091x; 1.0683x over previous
//
#include <hip/hip_runtime.h>

#define B_ 2
#define L_ 2048
#define D_ 2048
#define H_ 8
#define HD_ 256
#define FD_ 64
#define F_ 128          // 2*FD
#define NC_ 32          // L/CHUNK
#define M_ (B_*L_)      // 4096
#define SCALE_Q 0.08838834764831845f   // 128^-0.5

typedef unsigned short u16;
typedef __attribute__((ext_vector_type(8))) short bf16x8;
typedef __attribute__((ext_vector_type(8))) unsigned short u16x8;
typedef __attribute__((ext_vector_type(16))) float f32x16;
typedef __attribute__((ext_vector_type(4))) unsigned int u32x4;

#define FMA4(a_, s_, v_) { (a_).x += (s_)*(v_).x; (a_).y += (s_)*(v_).y; \
                           (a_).z += (s_)*(v_).z; (a_).w += (s_)*(v_).w; }

// ---------------------------------------------------------------------------
// Tiled operand layouts (read-major: memory order == MFMA fragment order).
// 512-u16 chunk (one 32xK16 fragment set): addr = ((k>>3)&1)*256 + (x&31)*8
// + (k&7). Lane l reads u16x8 at chunk + l*8 -> (x = l&31, k = ks*16 +
// (l>>5)*8 + elem). Symmetric between A-frags and B-frags.
// ---------------------------------------------------------------------------

__device__ __forceinline__ u16 bf16_rne(float x) {
  unsigned u = __float_as_uint(x);
  return (u16)((u + 0x7fffu + ((u >> 16) & 1u)) >> 16);
}
__device__ __forceinline__ void bf16_split(float x, u16& h, u16& l) {
  unsigned u = __float_as_uint(x);
  unsigned hb = (u + 0x7fffu + ((u >> 16) & 1u)) >> 16;
  h = (u16)hb;
  float hf = __uint_as_float(hb << 16);
  l = bf16_rne(x - hf);
}

__device__ __forceinline__ void gl_lds16(const u16* g, u16* l) {
  __builtin_amdgcn_global_load_lds(
      (const __attribute__((address_space(1))) unsigned int*)g,
      (__attribute__((address_space(3))) unsigned int*)l, 16, 0, 0);
}

// kvb frag-tiled offset: per-chunk [2 d-panel][4 f-kt][4096] (F=128,HD=256).
__device__ __forceinline__ size_t kvb_off(int d, int f) {
  return (size_t)(((d >> 7) & 1) * 16384 + ((f >> 5) & 3) * 4096 +
                  ((d >> 6) & 1) * 2048 + ((f >> 4) & 1) * 1024 +
                  ((d >> 5) & 1) * 512 + ((f >> 3) & 1) * 256 +
                  (d & 31) * 8 + (f & 7));
}
// vb frag-tiled offset: per-chunk (J=64,HD=256) -> 16384 u16.
__device__ __forceinline__ size_t vb_off(int d, int j) {
  return (size_t)(((d >> 7) & 1) * 8192 + ((j >> 5) & 1) * 4096 +
                  ((d >> 6) & 1) * 2048 + ((j >> 4) & 1) * 1024 +
                  ((d >> 5) & 1) * 512 + ((j >> 3) & 1) * 256 +
                  (d & 31) * 8 + (j & 7));
}

// ---------------------------------------------------------------------------
// W[K=2048][Nsrc] fp32 -> B-tiled bf16 (panel P, ktile kt).
// ---------------------------------------------------------------------------
__device__ __forceinline__ void wtrans_body(const float* __restrict__ W, int Nsrc,
                                            int n0, u16* __restrict__ dst,
                                            int P, int kt) {
  int t = threadIdx.x;
  int nn = t & 127, kh = t >> 7;
  const float* src = W + (size_t)(kt * 32 + kh * 16) * Nsrc + n0 + nn;
  u16x8 u0, u1;
  #pragma unroll
  for (int kk = 0; kk < 8; ++kk) u0[kk] = bf16_rne(src[(size_t)kk * Nsrc]);
  #pragma unroll
  for (int kk = 0; kk < 8; ++kk) u1[kk] = bf16_rne(src[(size_t)(kk + 8) * Nsrc]);
  size_t base = ((size_t)P * 64 + kt) * 4096 + (size_t)((nn >> 6) & 1) * 2048
              + (size_t)kh * 1024 + (size_t)((nn >> 5) & 1) * 512
              + (size_t)(nn & 31) * 8;
  *(u16x8*)(dst + base) = u0;
  *(u16x8*)(dst + base + 256) = u1;
}

// Fused prep: hs split (0..4095) + Wq|Wk|Wv tiling (4096..5375) +
// (bigws path) Wo tiling (5376..6399). One launch.
__global__ __launch_bounds__(256)
void prep_kernel(const float* __restrict__ hs,
                 const float* __restrict__ Wq, const float* __restrict__ Wk,
                 const float* __restrict__ Wv, const float* __restrict__ Wo,
                 u16* __restrict__ hsHt, u16* __restrict__ hsLt,
                 u16* __restrict__ WTh, u16* __restrict__ WoTh) {
  int bid = blockIdx.x;
  if (bid < 4096) {
    int gid = bid * 256 + threadIdx.x;
    int r = gid >> 8, u = gid & 255;
    const float* src = hs + (size_t)r * 2048 + u * 8;
    float4 v0 = *(const float4*)src, v1 = *(const float4*)(src + 4);
    float vals[8] = {v0.x, v0.y, v0.z, v0.w, v1.x, v1.y, v1.z, v1.w};
    u16x8 hv, lv;
    #pragma unroll
    for (int j = 0; j < 8; ++j) { u16 hh, ll; bf16_split(vals[j], hh, ll); hv[j] = hh; lv[j] = ll; }
    size_t off = ((size_t)(r >> 6) * 64 + (u >> 2)) * 2048
               + (size_t)((u >> 1) & 1) * 1024 + (size_t)((r >> 5) & 1) * 512
               + (size_t)(u & 1) * 256 + (size_t)(r & 31) * 8;
    *(u16x8*)(hsHt + off) = hv;
    *(u16x8*)(hsLt + off) = lv;
  } else if (bid < 5376) {
    int idx = bid - 4096;
    int P = idx >> 6, kt = idx & 63;
    const float* W; int Nsrc, n0;
    if (P < 16)      { W = Wq; Nsrc = 2048; n0 = P * 128; }
    else if (P < 18) { W = Wk; Nsrc = 256;  n0 = (P - 16) * 128; }
    else             { W = Wv; Nsrc = 256;  n0 = (P - 18) * 128; }
    wtrans_body(W, Nsrc, n0, WTh, P, kt);
  } else {
    int idx = bid - 5376;
    wtrans_body(Wo, 2048, (idx >> 6) * 128, WoTh, idx >> 6, idx & 63);
  }
}

// Fallback standalone Wo tiling (small-workspace path).
__global__ __launch_bounds__(256)
void wtrans_wo(const float* __restrict__ Wo, u16* __restrict__ WoTh) {
  wtrans_body(Wo, 2048, blockIdx.x * 128, WoTh, blockIdx.x, blockIdx.y);
}

// ---------------------------------------------------------------------------
// OLD 2-pass split-bf16 MFMA GEMM (64x128 tile, BK=32, 128 threads).
// Kept for the small k/v projection.
// ---------------------------------------------------------------------------
__device__ __forceinline__ void mfma_body(
    const u16* __restrict__ AtH, const u16* __restrict__ AtL,
    const u16* __restrict__ Bt, float* __restrict__ C, int cstride,
    int bm, int bn) {
  __shared__ __align__(16) u16 AsH[2048];
  __shared__ __align__(16) u16 AsL[2048];
  __shared__ __align__(16) u16 Bs[4096];
  const int t = threadIdx.x, lane = t & 63, wv = t >> 6;
  const u16* aSrc = (wv ? AtL : AtH) + (size_t)bm * 131072 + lane * 8;
  const u16* bSrc = Bt + (size_t)bn * 262144 + wv * 2048 + lane * 8;
  u16* aDst = wv ? AsL : AsH;
  u16* bDst = Bs + wv * 2048;

  f32x16 acc[2][2];
  #pragma unroll
  for (int a = 0; a < 2; ++a)
    #pragma unroll
    for (int b2 = 0; b2 < 2; ++b2)
      #pragma unroll
      for (int r = 0; r < 16; ++r) acc[a][b2][r] = 0.f;

  for (int kt = 0; kt < 64; ++kt) {
    const u16* ak = aSrc + (size_t)kt * 2048;
    const u16* bk = bSrc + (size_t)kt * 4096;
    __syncthreads();
    #pragma unroll
    for (int c = 0; c < 4; ++c) {
      gl_lds16(ak + c * 512, aDst + c * 512);
      gl_lds16(bk + c * 512, bDst + c * 512);
    }
    __syncthreads();

    #pragma unroll
    for (int ks = 0; ks < 2; ++ks) {
      const u16* ph = AsH + ks * 1024 + lane * 8;
      const u16* pl = AsL + ks * 1024 + lane * 8;
      const u16* pb = Bs + wv * 2048 + ks * 1024 + lane * 8;
      bf16x8 a0 = *(const bf16x8*)ph;
      bf16x8 a1 = *(const bf16x8*)(ph + 512);
      bf16x8 b0 = *(const bf16x8*)pb;
      bf16x8 b1 = *(const bf16x8*)(pb + 512);
      acc[0][0] = __builtin_amdgcn_mfma_f32_32x32x16_bf16(a0, b0, acc[0][0], 0, 0, 0);
      acc[0][1] = __builtin_amdgcn_mfma_f32_32x32x16_bf16(a0, b1, acc[0][1], 0, 0, 0);
      acc[1][0] = __builtin_amdgcn_mfma_f32_32x32x16_bf16(a1, b0, acc[1][0], 0, 0, 0);
      acc[1][1] = __builtin_amdgcn_mfma_f32_32x32x16_bf16(a1, b1, acc[1][1], 0, 0, 0);
      bf16x8 l0 = *(const bf16x8*)pl;
      bf16x8 l1 = *(const bf16x8*)(pl + 512);
      acc[0][0] = __builtin_amdgcn_mfma_f32_32x32x16_bf16(l0, b0, acc[0][0], 0, 0, 0);
      acc[0][1] = __builtin_amdgcn_mfma_f32_32x32x16_bf16(l0, b1, acc[0][1], 0, 0, 0);
      acc[1][0] = __builtin_amdgcn_mfma_f32_32x32x16_bf16(l1, b0, acc[1][0], 0, 0, 0);
      acc[1][1] = __builtin_amdgcn_mfma_f32_32x32x16_bf16(l1, b1, acc[1][1], 0, 0, 0);
    }
  }

  const int fr = lane & 31, g = lane >> 5;
  float* Cp = C + (size_t)(bm * 64) * cstride + wv * 64;
  #pragma unroll
  for (int mt = 0; mt < 2; ++mt)
    #pragma unroll
    for (int nt = 0; nt < 2; ++nt) {
      #pragma unroll
      for (int r = 0; r < 16; ++r) {
        int row = mt * 32 + (r & 3) + 8 * (r >> 2) + 4 * g;
        Cp[(size_t)row * cstride + nt * 32 + fr] = acc[mt][nt][r];
      }
    }
}

// ---------------------------------------------------------------------------
// Phase-split pipelined body: 256x128 tile, 8 waves, BK=32, triple-buffered
// ring, counted vmcnt(5), setprio around MFMA clusters.
// ---------------------------------------------------------------------------
#define SUB_ 20480
#define MFB(a_, b_, c_) (c_) = __builtin_amdgcn_mfma_f32_32x32x16_bf16((a_), (b_), (c_), 0, 0, 0)

__device__ __forceinline__ void mfma_big_body(
    const u16* __restrict__ AtH, const u16* __restrict__ AtL,
    const u16* __restrict__ Bt, float* __restrict__ C, int cstride,
    int bm, int bn) {
  __shared__ __align__(16) u16 lds[3 * SUB_];
  const int t = threadIdx.x, lane = t & 63, wv = t >> 6;
  const int wm = wv >> 1, wn = wv & 1;

  const u16* gs[5];
  unsigned lo[5], gst[5];
  #pragma unroll
  for (int j = 0; j < 5; ++j) {
    int line = wv * 5 + j;
    if (line < 16) {
      gs[j] = AtH + ((size_t)(4 * bm + (line >> 2)) * 64) * 2048
                  + (size_t)(line & 3) * 512 + lane * 8;
      lo[j] = line * 512; gst[j] = 2048;
    } else if (line < 32) {
      int l2 = line - 16;
      gs[j] = AtL + ((size_t)(4 * bm + (l2 >> 2)) * 64) * 2048
                  + (size_t)(l2 & 3) * 512 + lane * 8;
      lo[j] = 8192 + l2 * 512; gst[j] = 2048;
    } else {
      int l3 = line - 32;
      gs[j] = Bt + (size_t)bn * 262144 + (size_t)l3 * 512 + lane * 8;
      lo[j] = 16384 + l3 * 512; gst[j] = 4096;
    }
  }

  f32x16 acc[2][2];
  #pragma unroll
  for (int a = 0; a < 2; ++a)
    #pragma unroll
    for (int b2 = 0; b2 < 2; ++b2)
      #pragma unroll
      for (int r = 0; r < 16; ++r) acc[a][b2][r] = 0.f;

  #pragma unroll
  for (int j = 0; j < 5; ++j) gl_lds16(gs[j], lds + lo[j]);
  #pragma unroll
  for (int j = 0; j < 5; ++j) gl_lds16(gs[j] + gst[j], lds + SUB_ + lo[j]);
  asm volatile("s_waitcnt vmcnt(5)" ::: "memory");
  __builtin_amdgcn_s_barrier();
  __builtin_amdgcn_sched_barrier(0);

  int cb = 0;
  for (int kt = 0; kt < 64; ++kt) {
    int sb = cb + 2 * SUB_; if (sb >= 3 * SUB_) sb -= 3 * SUB_;
    const u16* base = lds + cb;
    const u16* ph0 = base + wm * 2048 + lane * 8;
    const u16* pb0 = base + 16384 + wn * 2048 + lane * 8;

    bf16x8 a0 = *(const bf16x8*)(ph0);
    bf16x8 a1 = *(const bf16x8*)(ph0 + 512);
    bf16x8 l0 = *(const bf16x8*)(ph0 + 8192);
    bf16x8 l1 = *(const bf16x8*)(ph0 + 8704);
    bf16x8 b0 = *(const bf16x8*)(pb0);
    bf16x8 b1 = *(const bf16x8*)(pb0 + 512);
    if (kt < 62) {
      gl_lds16(gs[0] + (size_t)(kt + 2) * gst[0], lds + sb + lo[0]);
      gl_lds16(gs[1] + (size_t)(kt + 2) * gst[1], lds + sb + lo[1]);
      gl_lds16(gs[2] + (size_t)(kt + 2) * gst[2], lds + sb + lo[2]);
    }
    __builtin_amdgcn_s_barrier();
    asm volatile("s_waitcnt lgkmcnt(0)" ::: "memory");
    __builtin_amdgcn_sched_barrier(0);
    __builtin_amdgcn_s_setprio(1);
    MFB(a0, b0, acc[0][0]); MFB(a0, b1, acc[0][1]);
    MFB(a1, b0, acc[1][0]); MFB(a1, b1, acc[1][1]);
    MFB(l0, b0, acc[0][0]); MFB(l0, b1, acc[0][1]);
    MFB(l1, b0, acc[1][0]); MFB(l1, b1, acc[1][1]);
    __builtin_amdgcn_s_setprio(0);
    __builtin_amdgcn_s_barrier();
    __builtin_amdgcn_sched_barrier(0);

    bf16x8 c0 = *(const bf16x8*)(ph0 + 1024);
    bf16x8 c1 = *(const bf16x8*)(ph0 + 1536);
    bf16x8 m0 = *(const bf16x8*)(ph0 + 9216);
    bf16x8 m1 = *(const bf16x8*)(ph0 + 9728);
    bf16x8 d0 = *(const bf16x8*)(pb0 + 1024);
    bf16x8 d1 = *(const bf16x8*)(pb0 + 1536);
    if (kt < 62) {
      gl_lds16(gs[3] + (size_t)(kt + 2) * gst[3], lds + sb + lo[3]);
      gl_lds16(gs[4] + (size_t)(kt + 2) * gst[4], lds + sb + lo[4]);
    }
    __builtin_amdgcn_s_barrier();
    asm volatile("s_waitcnt lgkmcnt(0)" ::: "memory");
    __builtin_amdgcn_sched_barrier(0);
    __builtin_amdgcn_s_setprio(1);
    MFB(c0, d0, acc[0][0]); MFB(c0, d1, acc[0][1]);
    MFB(c1, d0, acc[1][0]); MFB(c1, d1, acc[1][1]);
    MFB(m0, d0, acc[0][0]); MFB(m0, d1, acc[0][1]);
    MFB(m1, d0, acc[1][0]); MFB(m1, d1, acc[1][1]);
    __builtin_amdgcn_s_setprio(0);
    if (kt < 62) asm volatile("s_waitcnt vmcnt(5)" ::: "memory");
    else         asm volatile("s_waitcnt vmcnt(0)" ::: "memory");
    __builtin_amdgcn_s_barrier();
    __builtin_amdgcn_sched_barrier(0);
    cb += SUB_; if (cb == 3 * SUB_) cb = 0;
  }

  const int fr = lane & 31, g = lane >> 5;
  float* Cp = C + (size_t)(bm * 256 + wm * 64) * cstride + wn * 64;
  #pragma unroll
  for (int mt = 0; mt < 2; ++mt)
    #pragma unroll
    for (int nt = 0; nt < 2; ++nt) {
      #pragma unroll
      for (int r = 0; r < 16; ++r) {
        int row = mt * 32 + (r & 3) + 8 * (r >> 2) + 4 * g;
        Cp[(size_t)row * cstride + nt * 32 + fr] = acc[mt][nt][r];
      }
    }
}

__global__ __launch_bounds__(512, 2)
void mfma_q(const u16* __restrict__ hsHt, const u16* __restrict__ hsLt,
            const u16* __restrict__ WTh, float* __restrict__ q) {
  mfma_big_body(hsHt, hsLt, WTh, q + blockIdx.x * 128, 2048,
                blockIdx.y, blockIdx.x);
}

__global__ __launch_bounds__(128, 4)
void mfma_kv(const u16* __restrict__ hsHt, const u16* __restrict__ hsLt,
             const u16* __restrict__ WTh,
             float* __restrict__ k, float* __restrict__ v) {
  int bn = blockIdx.x;
  float* Cb; int co;
  if (bn < 2) { Cb = k; co = bn * 128; }
  else        { Cb = v; co = (bn - 2) * 128; }
  mfma_body(hsHt, hsLt, WTh, Cb + co, 256, blockIdx.y, 16 + bn);
}

__global__ __launch_bounds__(512, 2)
void mfma_wo(const u16* __restrict__ oHt, const u16* __restrict__ oLt,
             const u16* __restrict__ WoTh, float* __restrict__ out) {
  mfma_big_body(oHt, oLt, WoTh, out + blockIdx.x * 128, 2048,
                blockIdx.y, blockIdx.x);
}

__device__ __forceinline__ float wave_max64(float v) {
  #pragma unroll
  for (int off = 32; off > 0; off >>= 1) v = fmaxf(v, __shfl_xor(v, off, 64));
  return v;
}
__device__ __forceinline__ float wave_sum64(float v) {
  #pragma unroll
  for (int off = 32; off > 0; off >>= 1) v += __shfl_xor(v, off, 64);
  return v;
}

// ---------------------------------------------------------------------------
// Fused RoPE + hedgehog (blocks 0..4095) + prep_v branch (4096..4159).
// ---------------------------------------------------------------------------
__global__ __launch_bounds__(256)
void hedgehog_kernel(const float* __restrict__ q, const float* __restrict__ kx,
                     const float* __restrict__ fmq, const float* __restrict__ fmk,
                     const float* __restrict__ cosb, const float* __restrict__ sinb,
                     float* __restrict__ qf, float* __restrict__ kf,
                     const float* __restrict__ vsrc,
                     u16* __restrict__ vbH, u16* __restrict__ vbL) {
  int bid = blockIdx.x;
  if (bid >= 4096) {                    // fused prep_v: v chunk -> frag tiles
    int bn = bid - 4096;
    const float* vp = vsrc + (size_t)bn * 64 * HD_;
    size_t cbout = (size_t)bn * 16384;
    int d = threadIdx.x;
    #pragma unroll
    for (int it = 0; it < 8; ++it) {
      int j0 = it * 8;
      u16x8 hv, lv;
      #pragma unroll
      for (int c = 0; c < 8; ++c) {
        u16 hh, ll; bf16_split(vp[(size_t)(j0 + c) * HD_ + d], hh, ll);
        hv[c] = hh; lv[c] = ll;
      }
      size_t off = cbout + vb_off(d, j0);
      *(u16x8*)(vbH + off) = hv;
      *(u16x8*)(vbL + off) = lv;
    }
    return;
  }
  __shared__ __align__(16) float rows[4][4][256];
  const float* x; const float* fm; float* out; int nh_in, gb;
  if (bid < 2048) { x = q;  fm = fmq; out = qf; nh_in = 8; gb = bid * 4; }
  else            { x = kx; fm = fmk; out = kf; nh_in = 1; gb = (bid - 2048) * 4; }
  int wave = threadIdx.x >> 6, lane = threadIdx.x & 63;
  int g = gb + wave;
  int l4 = g & (L_/4 - 1);
  int bh = g / (L_/4);
  int h = bh & 7, b = bh >> 3;
  int l0 = l4 * 4;
  size_t rstride = (nh_in == 1) ? (size_t)HD_ : (size_t)H_ * HD_;
  const float* xrow = (nh_in == 1)
      ? x + (size_t)(b * L_ + l0) * HD_
      : x + ((size_t)(b * L_ + l0) * H_ + h) * HD_;
  int dd = (lane & 31) * 4;
  #pragma unroll
  for (int r = 0; r < 4; ++r) {
    float4 v = *(const float4*)(xrow + r * rstride + lane * 4);
    float4 u;
    u.x = __shfl_xor(v.x, 32, 64); u.y = __shfl_xor(v.y, 32, 64);
    u.z = __shfl_xor(v.z, 32, 64); u.w = __shfl_xor(v.w, 32, 64);
    int l = l0 + r;
    float4 c = *(const float4*)(cosb + (size_t)l * 128 + dd);
    float4 s = *(const float4*)(sinb + (size_t)l * 128 + dd);
    float4 ro;
    if (lane < 32) {
      ro.x = v.x * c.x - u.x * s.x; ro.y = v.y * c.y - u.y * s.y;
      ro.z = v.z * c.z - u.z * s.z; ro.w = v.w * c.w - u.w * s.w;
    } else {
      ro.x = u.x * s.x + v.x * c.x; ro.y = u.y * s.y + v.y * c.y;
      ro.z = u.z * s.z + v.z * c.z; ro.w = u.w * s.w + v.w * c.w;
    }
    *(float4*)&rows[wave][r][lane * 4] = ro;
  }
  __syncthreads();

  const float* fmh = fm + (size_t)h * HD_ * FD_;
  float p0 = 0.f, p1 = 0.f, p2 = 0.f, p3 = 0.f;
  for (int d2 = 0; d2 < HD_; d2 += 4) {
    float w0 = fmh[(d2 + 0) * FD_ + lane];
    float w1 = fmh[(d2 + 1) * FD_ + lane];
    float w2 = fmh[(d2 + 2) * FD_ + lane];
    float w3 = fmh[(d2 + 3) * FD_ + lane];
    float4 r0 = *(const float4*)&rows[wave][0][d2];
    float4 r1 = *(const float4*)&rows[wave][1][d2];
    float4 r2 = *(const float4*)&rows[wave][2][d2];
    float4 r3 = *(const float4*)&rows[wave][3][d2];
    p0 += r0.x * w0 + r0.y * w1 + r0.z * w2 + r0.w * w3;
    p1 += r1.x * w0 + r1.y * w1 + r1.z * w2 + r1.w * w3;
    p2 += r2.x * w0 + r2.y * w1 + r2.z * w2 + r2.w * w3;
    p3 += r3.x * w0 + r3.y * w1 + r3.z * w2 + r3.w * w3;
  }
  float p[4] = {p0, p1, p2, p3};
  #pragma unroll
  for (int r = 0; r < 4; ++r) {
    float m = wave_max64(fabsf(p[r]));
    float e1 = __expf(p[r] - m);
    float e2 = __expf(-p[r] - m);
    float z = wave_sum64(e1 + e2);
    float inv = 1.0f / z;
    size_t base = ((size_t)bh * L_ + l0 + r) * F_;
    out[base + lane]      = e1 * inv;
    out[base + 64 + lane] = e2 * inv;
  }
}

// ---------------------------------------------------------------------------
// Phase A: per-chunk kv_n[f][d] outer products -> frag-tiled split bf16.
// ---------------------------------------------------------------------------
__global__ __launch_bounds__(256)
void chunk_kv_kernel(const float* __restrict__ kf, const float* __restrict__ v,
                     u16* __restrict__ kvbH, u16* __restrict__ kvbL) {
  __shared__ __align__(16) float kfs[64][128];
  int n = blockIdx.x & (NC_ - 1), bh = blockIdx.x >> 5;
  int b = bh >> 3;
  const float* kfp = kf + ((size_t)bh * L_ + (size_t)n * 64) * F_;
  int t = threadIdx.x;
  #pragma unroll
  for (int it = 0; it < 8; ++it) {
    int flat = t * 4 + it * 1024;
    *(float4*)&kfs[flat >> 7][flat & 127] = *(const float4*)(kfp + flat);
  }
  __syncthreads();
  int dg = t & 63;
  int fg = t >> 6;
  const float* vp = v + (size_t)(b * L_ + n * 64) * HD_ + dg * 4;
  size_t cb = (size_t)blockIdx.x * 32768;
  #pragma unroll
  for (int pass = 0; pass < 4; ++pass) {
    int f0 = fg * 8 + pass * 32;
    float4 acc[8];
    #pragma unroll
    for (int i = 0; i < 8; ++i) acc[i] = make_float4(0.f, 0.f, 0.f, 0.f);
    for (int j = 0; j < 64; ++j) {
      float4 vv = *(const float4*)(vp + (size_t)j * HD_);
      float4 ka = *(const float4*)&kfs[j][f0];
      float4 kb = *(const float4*)&kfs[j][f0 + 4];
      FMA4(acc[0], ka.x, vv); FMA4(acc[1], ka.y, vv);
      FMA4(acc[2], ka.z, vv); FMA4(acc[3], ka.w, vv);
      FMA4(acc[4], kb.x, vv); FMA4(acc[5], kb.y, vv);
      FMA4(acc[6], kb.z, vv); FMA4(acc[7], kb.w, vv);
    }
    #pragma unroll
    for (int c = 0; c < 4; ++c) {
      u16x8 hv, lv;
      #pragma unroll
      for (int ff = 0; ff < 8; ++ff) {
        float xs = (c == 0) ? acc[ff].x : (c == 1) ? acc[ff].y
                 : (c == 2) ? acc[ff].z : acc[ff].w;
        u16 hh, ll; bf16_split(xs, hh, ll); hv[ff] = hh; lv[ff] = ll;
      }
      int d = dg * 4 + c;
      size_t off = cb + kvb_off(d, f0);
      *(u16x8*)(kvbH + off) = hv;
      *(u16x8*)(kvbL + off) = lv;
    }
  }
}

// Phase B: in-place exclusive prefix over the 32 chunks, on split bf16.
__global__ __launch_bounds__(256)
void chunk_scan_kernel(u16* __restrict__ kvbH, u16* __restrict__ kvbL) {
  int bh = blockIdx.x >> 4, g = blockIdx.x & 15;
  int d = threadIdx.x;
  size_t off = kvb_off(d, g * 8);
  float run[8] = {0.f, 0.f, 0.f, 0.f, 0.f, 0.f, 0.f, 0.f};
  for (int n = 0; n < NC_; ++n) {
    size_t a = ((size_t)(bh * 32 + n)) * 32768 + off;
    u16x8 hv = *(u16x8*)(kvbH + a);
    u16x8 lv = *(u16x8*)(kvbL + a);
    u16x8 oh, ol;
    #pragma unroll
    for (int c = 0; c < 8; ++c) {
      float val = __uint_as_float((unsigned)hv[c] << 16)
                + __uint_as_float((unsigned)lv[c] << 16);
      u16 hh, ll; bf16_split(run[c], hh, ll); oh[c] = hh; ol[c] = ll;
      run[c] += val;
    }
    *(u16x8*)(kvbH + a) = oh;
    *(u16x8*)(kvbL + a) = ol;
  }
}

// ---------------------------------------------------------------------------
// Phase C (MFMA): epilogue now writes A-tiled split bf16 oHt/oLt DIRECTLY
// (prep_o fused away; index algebra replicates prep_o's formula exactly).
// ---------------------------------------------------------------------------
__global__ __launch_bounds__(256, 2)
void chunk_attn_kernel(const float* __restrict__ qf, const float* __restrict__ kf,
                       const u16* __restrict__ vbH, const u16* __restrict__ vbL,
                       const u16* __restrict__ kvbH, const u16* __restrict__ kvbL,
                       u16* __restrict__ oHt, u16* __restrict__ oLt) {
  __shared__ __align__(16) u16 lds[32768];   // qsH|qsL|kfH|kfL
  const int n = blockIdx.x & (NC_ - 1), bh = blockIdx.x >> 5;
  const int h = bh & 7, b = bh >> 3;
  const int t = threadIdx.x;
  const int w = t >> 6, i31 = t & 31, G = (t >> 5) & 1;
  const int l8 = (t & 63) * 8;

  {
    const float* qp = qf + ((size_t)bh * L_ + (size_t)n * 64) * F_;
    const float* kp = kf + ((size_t)bh * L_ + (size_t)n * 64) * F_;
    int o8 = t & 15, ib = t >> 4;
    #pragma unroll
    for (int iter = 0; iter < 4; ++iter) {
      int i = ib + iter * 16;
      int it = i >> 5, ks = o8 >> 1;
      int sub = (it * 8 + ks) * 512 + (o8 & 1) * 256 + (i & 31) * 8;
      {
        const float* src = qp + (size_t)i * 128 + o8 * 8;
        float4 a = *(const float4*)src, c = *(const float4*)(src + 4);
        float vals[8] = {a.x, a.y, a.z, a.w, c.x, c.y, c.z, c.w};
        u16x8 hv, lv;
        #pragma unroll
        for (int j = 0; j < 8; ++j) {
          u16 hh, ll; bf16_split(vals[j] * SCALE_Q, hh, ll);
          hv[j] = hh; lv[j] = ll;
        }
        *(u16x8*)(lds + sub) = hv;
        *(u16x8*)(lds + 8192 + sub) = lv;
      }
      {
        const float* src = kp + (size_t)i * 128 + o8 * 8;
        float4 a = *(const float4*)src, c = *(const float4*)(src + 4);
        float vals[8] = {a.x, a.y, a.z, a.w, c.x, c.y, c.z, c.w};
        u16x8 hv, lv;
        #pragma unroll
        for (int j = 0; j < 8; ++j) {
          u16 hh, ll; bf16_split(vals[j], hh, ll);
          hv[j] = hh; lv[j] = ll;
        }
        *(u16x8*)(lds + 16384 + sub) = hv;
        *(u16x8*)(lds + 24576 + sub) = lv;
      }
    }
  }
  __syncthreads();

  const u16* Lq  = lds;
  const u16* Lql = lds + 8192;
  const u16* Lk  = lds + 16384;
  const u16* Lkl = lds + 24576;

  // ---- phase S: sT = kf · qs^T (3-pass split) ----
  f32x16 st[2][2];
  #pragma unroll
  for (int a = 0; a < 2; ++a)
    #pragma unroll
    for (int c = 0; c < 2; ++c)
      #pragma unroll
      for (int r = 0; r < 16; ++r) st[a][c][r] = 0.f;

  #pragma unroll
  for (int ks = 0; ks < 8; ++ks) {
    bf16x8 kh0 = *(const bf16x8*)(Lk  + ks * 512 + l8);
    bf16x8 kh1 = *(const bf16x8*)(Lk  + (8 + ks) * 512 + l8);
    bf16x8 kl0 = *(const bf16x8*)(Lkl + ks * 512 + l8);
    bf16x8 kl1 = *(const bf16x8*)(Lkl + (8 + ks) * 512 + l8);
    bf16x8 qh0 = *(const bf16x8*)(Lq  + ks * 512 + l8);
    bf16x8 qh1 = *(const bf16x8*)(Lq  + (8 + ks) * 512 + l8);
    bf16x8 ql0 = *(const bf16x8*)(Lql + ks * 512 + l8);
    bf16x8 ql1 = *(const bf16x8*)(Lql + (8 + ks) * 512 + l8);
    MFB(kh0, qh0, st[0][0]); MFB(kh0, ql0, st[0][0]); MFB(kl0, qh0, st[0][0]);
    MFB(kh0, qh1, st[0][1]); MFB(kh0, ql1, st[0][1]); MFB(kl0, qh1, st[0][1]);
    MFB(kh1, qh0, st[1][0]); MFB(kh1, ql0, st[1][0]); MFB(kl1, qh0, st[1][0]);
    MFB(kh1, qh1, st[1][1]); MFB(kh1, ql1, st[1][1]); MFB(kl1, qh1, st[1][1]);
  }

  // ---- mask + split + cross-lane transpose: sT C-regs -> s A-frags ----
  bf16x8 sfH[2][4], sfL[2][4];
  #pragma unroll
  for (int mt = 0; mt < 2; ++mt) {
    int iv = mt * 32 + i31;
    #pragma unroll
    for (int ksj = 0; ksj < 4; ++ksj) {
      const int jt = ksj >> 1, kb = ksj & 1;
      unsigned ph[4], pl[4];
      #pragma unroll
      for (int half = 0; half < 2; ++half) {
        u16 hh[4], ll[4];
        #pragma unroll
        for (int c = 0; c < 4; ++c) {
          int r = 8 * kb + 4 * half + c;
          int jv = jt * 32 + (r & 3) + 8 * (r >> 2) + 4 * G;
          float mv = (jv <= iv) ? st[jt][mt][r] : 0.f;
          u16 h_, l_; bf16_split(mv, h_, l_);
          hh[c] = h_; ll[c] = l_;
        }
        ph[half * 2 + 0] = (unsigned)hh[0] | ((unsigned)hh[1] << 16);
        ph[half * 2 + 1] = (unsigned)hh[2] | ((unsigned)hh[3] << 16);
        pl[half * 2 + 0] = (unsigned)ll[0] | ((unsigned)ll[1] << 16);
        pl[half * 2 + 1] = (unsigned)ll[2] | ((unsigned)ll[3] << 16);
      }
      unsigned rH1 = (unsigned)__shfl_xor((int)(G ? ph[0] : ph[2]), 32, 64);
      unsigned rH2 = (unsigned)__shfl_xor((int)(G ? ph[1] : ph[3]), 32, 64);
      unsigned rL1 = (unsigned)__shfl_xor((int)(G ? pl[0] : pl[2]), 32, 64);
      unsigned rL2 = (unsigned)__shfl_xor((int)(G ? pl[1] : pl[3]), 32, 64);
      u32x4 wH, wL;
      wH[0] = G ? rH1 : ph[0]; wH[1] = G ? rH2 : ph[1];
      wH[2] = G ? ph[2] : rH1; wH[3] = G ? ph[3] : rH2;
      wL[0] = G ? rL1 : pl[0]; wL[1] = G ? rL2 : pl[1];
      wL[2] = G ? pl[2] : rL1; wL[3] = G ? pl[3] : rL2;
      sfH[mt][ksj] = __builtin_bit_cast(bf16x8, wH);
      sfL[mt][ksj] = __builtin_bit_cast(bf16x8, wL);
    }
  }

  f32x16 acc[2][2];
  #pragma unroll
  for (int a = 0; a < 2; ++a)
    #pragma unroll
    for (int c = 0; c < 2; ++c)
      #pragma unroll
      for (int r = 0; r < 16; ++r) acc[a][c][r] = 0.f;

  // ---- phase A (intra): acc += s · v, v frags pre-tiled ----
  {
    size_t vcb = ((size_t)(b * NC_ + n)) * 16384;
    #pragma unroll
    for (int nt = 0; nt < 2; ++nt) {
      #pragma unroll
      for (int ksj = 0; ksj < 4; ++ksj) {
        size_t basev = vcb + vb_off(w * 64 + nt * 32, ksj * 16) + l8;
        bf16x8 vH = *(const bf16x8*)((const short*)(vbH + basev));
        bf16x8 vL = *(const bf16x8*)((const short*)(vbL + basev));
        MFB(sfH[0][ksj], vH, acc[0][nt]); MFB(sfL[0][ksj], vH, acc[0][nt]);
        MFB(sfH[0][ksj], vL, acc[0][nt]);
        MFB(sfH[1][ksj], vH, acc[1][nt]); MFB(sfL[1][ksj], vH, acc[1][nt]);
        MFB(sfH[1][ksj], vL, acc[1][nt]);
      }
    }
  }

  // ---- phase I (inter): acc += qs · kv_cum ----
  {
    size_t cb = (size_t)blockIdx.x * 32768;
    #pragma unroll
    for (int ks = 0; ks < 8; ++ks) {
      bf16x8 qa_h0 = *(const bf16x8*)(Lq  + ks * 512 + l8);
      bf16x8 qa_h1 = *(const bf16x8*)(Lq  + (8 + ks) * 512 + l8);
      bf16x8 qa_l0 = *(const bf16x8*)(Lql + ks * 512 + l8);
      bf16x8 qa_l1 = *(const bf16x8*)(Lql + (8 + ks) * 512 + l8);
      #pragma unroll
      for (int nt = 0; nt < 2; ++nt) {
        size_t base = cb + kvb_off(w * 64 + nt * 32, ks * 16) + l8;
        bf16x8 kvH = *(const bf16x8*)((const short*)(kvbH + base));
        bf16x8 kvL = *(const bf16x8*)((const short*)(kvbL + base));
        MFB(qa_h0, kvH, acc[0][nt]); MFB(qa_l0, kvH, acc[0][nt]);
        MFB(qa_h0, kvL, acc[0][nt]);
        MFB(qa_h1, kvH, acc[1][nt]); MFB(qa_l1, kvH, acc[1][nt]);
        MFB(qa_h1, kvL, acc[1][nt]);
      }
    }
  }

  // ---- fused epilogue: A-tiled split bf16 write (replaces fp32 o + prep_o)
  // row = p*64 + mt*32 + rr (p = b*NC + n), d = h*256 + w*64 + nt*32 + i31
  {
    int p = b * NC_ + n;
    #pragma unroll
    for (int mt = 0; mt < 2; ++mt)
      #pragma unroll
      for (int nt = 0; nt < 2; ++nt) {
        int u_ = h * 32 + w * 8 + nt * 4 + (i31 >> 3);
        size_t ob = ((size_t)p * 64 + (u_ >> 2)) * 2048
                  + (size_t)((u_ >> 1) & 1) * 1024 + (size_t)mt * 512
                  + (size_t)(u_ & 1) * 256 + (size_t)(i31 & 7);
        #pragma unroll
        for (int r = 0; r < 16; ++r) {
          int rr = (r & 3) + 8 * (r >> 2) + 4 * G;
          u16 hh, ll; bf16_split(acc[mt][nt][r], hh, ll);
          oHt[ob + (size_t)rr * 8] = hh;
          oLt[ob + (size_t)rr * 8] = ll;
        }
      }
  }
}

// ---------------------------------------------------------------------------
extern "C" void kernel_launch(void* const* d_in, const int* in_sizes, int n_in,
                              void* d_out, int out_size, void* d_ws, size_t ws_size,
                              hipStream_t stream) {
  const float* hs   = (const float*)d_in[0];
  const float* fcos = (const float*)d_in[1];
  const float* fsin = (const float*)d_in[2];
  // d_in[3] = mask (all ones, unused)
  const float* Wq  = (const float*)d_in[4];
  const float* Wk  = (const float*)d_in[5];
  const float* Wv  = (const float*)d_in[6];
  const float* Wo  = (const float*)d_in[7];
  const float* fmq = (const float*)d_in[8];
  const float* fmk = (const float*)d_in[9];
  float* out = (float*)d_out;

  float* ws = (float*)d_ws;
  float* q  = ws;                                   // 32MB; later oHt/oLt
  float* k  = q  + (size_t)M_ * 2048;               // 4MB; later vb tiles
  float* v  = k  + (size_t)M_ * 256;                // 4MB
  float* qf = v  + (size_t)M_ * 256;                // 16MB
  float* kf = qf + (size_t)B_ * H_ * L_ * F_;       // 16MB
  float* kvr = kf + (size_t)B_ * H_ * L_ * F_;      // 64MB region

  u16* hsHt = (u16*)kvr;                      // 16 MB
  u16* hsLt = hsHt + (size_t)M_ * 2048;       // 16 MB
  u16* WTh  = hsLt + (size_t)M_ * 2048;       // 10 MB
  u16* kvbH = (u16*)kvr;                      // 32 MB
  u16* kvbL = kvbH + (size_t)512 * 32768;     // 32 MB
  u16* vbH  = (u16*)k;                        // 2 MB
  u16* vbL  = vbH + (size_t)64 * 16384;       // 2 MB
  u16* oHt  = (u16*)q;                        // 16 MB (q dead after hedgehog)
  u16* oLt  = oHt + (size_t)M_ * 2048;        // 16 MB

  // WoTh: own 8 MB past the 136 MB base if workspace allows (-> prep fusion);
  // else fall back to late separate launch aliasing kvr (kvb dead by then).
  const size_t WS_BASE = (size_t)142606336;   // 136 MB layout above
  bool bigws = ws_size >= WS_BASE + (size_t)8388608;
  u16* WoTh = bigws ? (u16*)((char*)d_ws + WS_BASE) : (u16*)kvr;

  // 1) Fused prep: hs split + Wq/Wk/Wv tiling (+ Wo tiling when bigws)
  prep_kernel<<<bigws ? 6400 : 5376, 256, 0, stream>>>(
      hs, Wq, Wk, Wv, Wo, hsHt, hsLt, WTh, WoTh);
  // 2a) q projection: phase-split pipelined body, 256 blocks
  mfma_q<<<dim3(16, 16), 512, 0, stream>>>(hsHt, hsLt, WTh, q);
  // 2b) k/v projections: old body, 256 blocks
  mfma_kv<<<dim3(4, 64), 128, 0, stream>>>(hsHt, hsLt, WTh, k, v);
  // 3) Fused RoPE + hedgehog + prep_v branch (64 extra blocks)
  hedgehog_kernel<<<4096 + 64, 256, 0, stream>>>(q, k, fmq, fmk, fcos, fsin,
                                                 qf, kf, v, vbH, vbL);
  // 4) Per-chunk k^T v outer products -> split frag-tiled bf16; in-place scan
  chunk_kv_kernel<<<B_ * H_ * NC_, 256, 0, stream>>>(kf, v, kvbH, kvbL);
  chunk_scan_kernel<<<256, 256, 0, stream>>>(kvbH, kvbL);
  // 5) MFMA inter+intra chunk attention -> A-tiled split bf16 (fused epilogue)
  chunk_attn_kernel<<<B_ * H_ * NC_, 256, 0, stream>>>(qf, kf, vbH, vbL,
                                                       kvbH, kvbL, oHt, oLt);
  // 6) Output projection (fallback path tiles Wo late)
  if (!bigws)
    wtrans_wo<<<dim3(16, 64), 256, 0, stream>>>(Wo, WoTh);
  mfma_wo<<<dim3(16, 16), 512, 0, stream>>>(oHt, oLt, WoTh, out);
}

// Round 8
// 490.237 us; speedup vs baseline: 1.1391x; 1.0270x over previous
//
#include <hip/hip_runtime.h>

#define B_ 2
#define L_ 2048
#define D_ 2048
#define H_ 8
#define HD_ 256
#define FD_ 64
#define F_ 128          // 2*FD
#define NC_ 32          // L/CHUNK
#define M_ (B_*L_)      // 4096
#define SCALE_Q 0.08838834764831845f   // 128^-0.5

typedef unsigned short u16;
typedef __attribute__((ext_vector_type(8))) short bf16x8;
typedef __attribute__((ext_vector_type(8))) unsigned short u16x8;
typedef __attribute__((ext_vector_type(16))) float f32x16;
typedef __attribute__((ext_vector_type(4))) unsigned int u32x4;

#define FMA4(a_, s_, v_) { (a_).x += (s_)*(v_).x; (a_).y += (s_)*(v_).y; \
                           (a_).z += (s_)*(v_).z; (a_).w += (s_)*(v_).w; }

// ---------------------------------------------------------------------------
// Tiled operand layouts (read-major: memory order == MFMA fragment order).
// 512-u16 chunk (one 32xK16 fragment set): addr = ((k>>3)&1)*256 + (x&31)*8
// + (k&7). Lane l reads u16x8 at chunk + l*8 -> (x = l&31, k = ks*16 +
// (l>>5)*8 + elem). Symmetric between A-frags and B-frags.
// ---------------------------------------------------------------------------

__device__ __forceinline__ u16 bf16_rne(float x) {
  unsigned u = __float_as_uint(x);
  return (u16)((u + 0x7fffu + ((u >> 16) & 1u)) >> 16);
}
__device__ __forceinline__ void bf16_split(float x, u16& h, u16& l) {
  unsigned u = __float_as_uint(x);
  unsigned hb = (u + 0x7fffu + ((u >> 16) & 1u)) >> 16;
  h = (u16)hb;
  float hf = __uint_as_float(hb << 16);
  l = bf16_rne(x - hf);
}

__device__ __forceinline__ void gl_lds16(const u16* g, u16* l) {
  __builtin_amdgcn_global_load_lds(
      (const __attribute__((address_space(1))) unsigned int*)g,
      (__attribute__((address_space(3))) unsigned int*)l, 16, 0, 0);
}

// kvb frag-tiled offset: per-chunk [2 d-panel][4 f-kt][4096] (F=128,HD=256).
__device__ __forceinline__ size_t kvb_off(int d, int f) {
  return (size_t)(((d >> 7) & 1) * 16384 + ((f >> 5) & 3) * 4096 +
                  ((d >> 6) & 1) * 2048 + ((f >> 4) & 1) * 1024 +
                  ((d >> 5) & 1) * 512 + ((f >> 3) & 1) * 256 +
                  (d & 31) * 8 + (f & 7));
}
// vb frag-tiled offset: per-chunk (J=64,HD=256) -> 16384 u16.
__device__ __forceinline__ size_t vb_off(int d, int j) {
  return (size_t)(((d >> 7) & 1) * 8192 + ((j >> 5) & 1) * 4096 +
                  ((d >> 6) & 1) * 2048 + ((j >> 4) & 1) * 1024 +
                  ((d >> 5) & 1) * 512 + ((j >> 3) & 1) * 256 +
                  (d & 31) * 8 + (j & 7));
}

// ---------------------------------------------------------------------------
// W[K=2048][Nsrc] fp32 -> B-tiled bf16 (panel P, ktile kt).
// ---------------------------------------------------------------------------
__device__ __forceinline__ void wtrans_body(const float* __restrict__ W, int Nsrc,
                                            int n0, u16* __restrict__ dst,
                                            int P, int kt) {
  int t = threadIdx.x;
  int nn = t & 127, kh = t >> 7;
  const float* src = W + (size_t)(kt * 32 + kh * 16) * Nsrc + n0 + nn;
  u16x8 u0, u1;
  #pragma unroll
  for (int kk = 0; kk < 8; ++kk) u0[kk] = bf16_rne(src[(size_t)kk * Nsrc]);
  #pragma unroll
  for (int kk = 0; kk < 8; ++kk) u1[kk] = bf16_rne(src[(size_t)(kk + 8) * Nsrc]);
  size_t base = ((size_t)P * 64 + kt) * 4096 + (size_t)((nn >> 6) & 1) * 2048
              + (size_t)kh * 1024 + (size_t)((nn >> 5) & 1) * 512
              + (size_t)(nn & 31) * 8;
  *(u16x8*)(dst + base) = u0;
  *(u16x8*)(dst + base + 256) = u1;
}

// Fused prep: hs split (0..4095) + Wq|Wk|Wv tiling (4096..5375) +
// (bigws path) Wo tiling (5376..6399). One launch.
__global__ __launch_bounds__(256)
void prep_kernel(const float* __restrict__ hs,
                 const float* __restrict__ Wq, const float* __restrict__ Wk,
                 const float* __restrict__ Wv, const float* __restrict__ Wo,
                 u16* __restrict__ hsHt, u16* __restrict__ hsLt,
                 u16* __restrict__ WTh, u16* __restrict__ WoTh) {
  int bid = blockIdx.x;
  if (bid < 4096) {
    int gid = bid * 256 + threadIdx.x;
    int r = gid >> 8, u = gid & 255;
    const float* src = hs + (size_t)r * 2048 + u * 8;
    float4 v0 = *(const float4*)src, v1 = *(const float4*)(src + 4);
    float vals[8] = {v0.x, v0.y, v0.z, v0.w, v1.x, v1.y, v1.z, v1.w};
    u16x8 hv, lv;
    #pragma unroll
    for (int j = 0; j < 8; ++j) { u16 hh, ll; bf16_split(vals[j], hh, ll); hv[j] = hh; lv[j] = ll; }
    size_t off = ((size_t)(r >> 6) * 64 + (u >> 2)) * 2048
               + (size_t)((u >> 1) & 1) * 1024 + (size_t)((r >> 5) & 1) * 512
               + (size_t)(u & 1) * 256 + (size_t)(r & 31) * 8;
    *(u16x8*)(hsHt + off) = hv;
    *(u16x8*)(hsLt + off) = lv;
  } else if (bid < 5376) {
    int idx = bid - 4096;
    int P = idx >> 6, kt = idx & 63;
    const float* W; int Nsrc, n0;
    if (P < 16)      { W = Wq; Nsrc = 2048; n0 = P * 128; }
    else if (P < 18) { W = Wk; Nsrc = 256;  n0 = (P - 16) * 128; }
    else             { W = Wv; Nsrc = 256;  n0 = (P - 18) * 128; }
    wtrans_body(W, Nsrc, n0, WTh, P, kt);
  } else {
    int idx = bid - 5376;
    wtrans_body(Wo, 2048, (idx >> 6) * 128, WoTh, idx >> 6, idx & 63);
  }
}

// Fallback standalone Wo tiling (small-workspace path).
__global__ __launch_bounds__(256)
void wtrans_wo(const float* __restrict__ Wo, u16* __restrict__ WoTh) {
  wtrans_body(Wo, 2048, blockIdx.x * 128, WoTh, blockIdx.x, blockIdx.y);
}

// ---------------------------------------------------------------------------
// OLD 2-pass split-bf16 MFMA GEMM (64x128 tile, BK=32, 128 threads).
// Kept for the small k/v projection.
// ---------------------------------------------------------------------------
__device__ __forceinline__ void mfma_body(
    const u16* __restrict__ AtH, const u16* __restrict__ AtL,
    const u16* __restrict__ Bt, float* __restrict__ C, int cstride,
    int bm, int bn) {
  __shared__ __align__(16) u16 AsH[2048];
  __shared__ __align__(16) u16 AsL[2048];
  __shared__ __align__(16) u16 Bs[4096];
  const int t = threadIdx.x, lane = t & 63, wv = t >> 6;
  const u16* aSrc = (wv ? AtL : AtH) + (size_t)bm * 131072 + lane * 8;
  const u16* bSrc = Bt + (size_t)bn * 262144 + wv * 2048 + lane * 8;
  u16* aDst = wv ? AsL : AsH;
  u16* bDst = Bs + wv * 2048;

  f32x16 acc[2][2];
  #pragma unroll
  for (int a = 0; a < 2; ++a)
    #pragma unroll
    for (int b2 = 0; b2 < 2; ++b2)
      #pragma unroll
      for (int r = 0; r < 16; ++r) acc[a][b2][r] = 0.f;

  for (int kt = 0; kt < 64; ++kt) {
    const u16* ak = aSrc + (size_t)kt * 2048;
    const u16* bk = bSrc + (size_t)kt * 4096;
    __syncthreads();
    #pragma unroll
    for (int c = 0; c < 4; ++c) {
      gl_lds16(ak + c * 512, aDst + c * 512);
      gl_lds16(bk + c * 512, bDst + c * 512);
    }
    __syncthreads();

    #pragma unroll
    for (int ks = 0; ks < 2; ++ks) {
      const u16* ph = AsH + ks * 1024 + lane * 8;
      const u16* pl = AsL + ks * 1024 + lane * 8;
      const u16* pb = Bs + wv * 2048 + ks * 1024 + lane * 8;
      bf16x8 a0 = *(const bf16x8*)ph;
      bf16x8 a1 = *(const bf16x8*)(ph + 512);
      bf16x8 b0 = *(const bf16x8*)pb;
      bf16x8 b1 = *(const bf16x8*)(pb + 512);
      acc[0][0] = __builtin_amdgcn_mfma_f32_32x32x16_bf16(a0, b0, acc[0][0], 0, 0, 0);
      acc[0][1] = __builtin_amdgcn_mfma_f32_32x32x16_bf16(a0, b1, acc[0][1], 0, 0, 0);
      acc[1][0] = __builtin_amdgcn_mfma_f32_32x32x16_bf16(a1, b0, acc[1][0], 0, 0, 0);
      acc[1][1] = __builtin_amdgcn_mfma_f32_32x32x16_bf16(a1, b1, acc[1][1], 0, 0, 0);
      bf16x8 l0 = *(const bf16x8*)pl;
      bf16x8 l1 = *(const bf16x8*)(pl + 512);
      acc[0][0] = __builtin_amdgcn_mfma_f32_32x32x16_bf16(l0, b0, acc[0][0], 0, 0, 0);
      acc[0][1] = __builtin_amdgcn_mfma_f32_32x32x16_bf16(l0, b1, acc[0][1], 0, 0, 0);
      acc[1][0] = __builtin_amdgcn_mfma_f32_32x32x16_bf16(l1, b0, acc[1][0], 0, 0, 0);
      acc[1][1] = __builtin_amdgcn_mfma_f32_32x32x16_bf16(l1, b1, acc[1][1], 0, 0, 0);
    }
  }

  const int fr = lane & 31, g = lane >> 5;
  float* Cp = C + (size_t)(bm * 64) * cstride + wv * 64;
  #pragma unroll
  for (int mt = 0; mt < 2; ++mt)
    #pragma unroll
    for (int nt = 0; nt < 2; ++nt) {
      #pragma unroll
      for (int r = 0; r < 16; ++r) {
        int row = mt * 32 + (r & 3) + 8 * (r >> 2) + 4 * g;
        Cp[(size_t)row * cstride + nt * 32 + fr] = acc[mt][nt][r];
      }
    }
}

// ---------------------------------------------------------------------------
// Pipelined body v3: 128x128 tile, 4 waves (256 thr), BK=32, triple-buffered
// ring of 24 KB slots (72 KB LDS -> 2 blocks/CU: block-level TLP covers the
// barrier drains that capped the 1-block/CU variants at ~37% MfmaUtil).
// Phase-split + counted vmcnt(6) + setprio. Grid 512 blocks = 2/CU.
// Slot layout (u16): A_H [0,4096) | A_L [4096,8192) | B [8192,12288).
// ---------------------------------------------------------------------------
#define SUB_ 12288
#define MFB(a_, b_, c_) (c_) = __builtin_amdgcn_mfma_f32_32x32x16_bf16((a_), (b_), (c_), 0, 0, 0)

__device__ __forceinline__ void mfma_big_body(
    const u16* __restrict__ AtH, const u16* __restrict__ AtL,
    const u16* __restrict__ Bt, float* __restrict__ C, int cstride,
    int bm, int bn) {
  __shared__ __align__(16) u16 lds[3 * SUB_];
  const int t = threadIdx.x, lane = t & 63, wv = t >> 6;   // 4 waves
  const int wm = wv >> 1, wn = wv & 1;

  // 24 staging lines of 1 KB per K-step; 6 per wave.
  // lines 0-7 A_H (2 panels x 4 quarters), 8-15 A_L, 16-23 B (8 quarters).
  const u16* gs[6];
  unsigned lo[6], gst[6];
  #pragma unroll
  for (int j = 0; j < 6; ++j) {
    int line = wv * 6 + j;
    if (line < 8) {
      gs[j] = AtH + ((size_t)(2 * bm + (line >> 2)) * 64) * 2048
                  + (size_t)(line & 3) * 512 + lane * 8;
      gst[j] = 2048;
    } else if (line < 16) {
      int l2 = line - 8;
      gs[j] = AtL + ((size_t)(2 * bm + (l2 >> 2)) * 64) * 2048
                  + (size_t)(l2 & 3) * 512 + lane * 8;
      gst[j] = 2048;
    } else {
      int l3 = line - 16;
      gs[j] = Bt + (size_t)bn * 262144 + (size_t)l3 * 512 + lane * 8;
      gst[j] = 4096;
    }
    lo[j] = line * 512;
  }

  f32x16 acc[2][2];
  #pragma unroll
  for (int a = 0; a < 2; ++a)
    #pragma unroll
    for (int b2 = 0; b2 < 2; ++b2)
      #pragma unroll
      for (int r = 0; r < 16; ++r) acc[a][b2][r] = 0.f;

  // prologue: fill slots 0,1 (12 lines in flight); wait slot 0 (6 newest fly)
  #pragma unroll
  for (int j = 0; j < 6; ++j) gl_lds16(gs[j], lds + lo[j]);
  #pragma unroll
  for (int j = 0; j < 6; ++j) gl_lds16(gs[j] + gst[j], lds + SUB_ + lo[j]);
  asm volatile("s_waitcnt vmcnt(6)" ::: "memory");
  __builtin_amdgcn_s_barrier();
  __builtin_amdgcn_sched_barrier(0);

  int cb = 0;
  for (int kt = 0; kt < 64; ++kt) {
    int sb = cb + 2 * SUB_; if (sb >= 3 * SUB_) sb -= 3 * SUB_;
    const u16* base = lds + cb;
    const u16* ph0 = base + wm * 2048 + lane * 8;            // A_H
    const u16* pb0 = base + 8192 + wn * 2048 + lane * 8;     // B

    // -------- phase A (ks=0): 6 ds_read, stage lines 0-2, 8 MFMA --------
    bf16x8 a0 = *(const bf16x8*)(ph0);
    bf16x8 a1 = *(const bf16x8*)(ph0 + 512);
    bf16x8 l0 = *(const bf16x8*)(ph0 + 4096);
    bf16x8 l1 = *(const bf16x8*)(ph0 + 4608);
    bf16x8 b0 = *(const bf16x8*)(pb0);
    bf16x8 b1 = *(const bf16x8*)(pb0 + 512);
    if (kt < 62) {
      gl_lds16(gs[0] + (size_t)(kt + 2) * gst[0], lds + sb + lo[0]);
      gl_lds16(gs[1] + (size_t)(kt + 2) * gst[1], lds + sb + lo[1]);
      gl_lds16(gs[2] + (size_t)(kt + 2) * gst[2], lds + sb + lo[2]);
    }
    __builtin_amdgcn_s_barrier();
    asm volatile("s_waitcnt lgkmcnt(0)" ::: "memory");
    __builtin_amdgcn_sched_barrier(0);
    __builtin_amdgcn_s_setprio(1);
    MFB(a0, b0, acc[0][0]); MFB(a0, b1, acc[0][1]);
    MFB(a1, b0, acc[1][0]); MFB(a1, b1, acc[1][1]);
    MFB(l0, b0, acc[0][0]); MFB(l0, b1, acc[0][1]);
    MFB(l1, b0, acc[1][0]); MFB(l1, b1, acc[1][1]);
    __builtin_amdgcn_s_setprio(0);
    __builtin_amdgcn_s_barrier();
    __builtin_amdgcn_sched_barrier(0);

    // -------- phase B (ks=1): 6 ds_read, stage lines 3-5, 8 MFMA --------
    bf16x8 c0 = *(const bf16x8*)(ph0 + 1024);
    bf16x8 c1 = *(const bf16x8*)(ph0 + 1536);
    bf16x8 m0 = *(const bf16x8*)(ph0 + 5120);
    bf16x8 m1 = *(const bf16x8*)(ph0 + 5632);
    bf16x8 d0 = *(const bf16x8*)(pb0 + 1024);
    bf16x8 d1 = *(const bf16x8*)(pb0 + 1536);
    if (kt < 62) {
      gl_lds16(gs[3] + (size_t)(kt + 2) * gst[3], lds + sb + lo[3]);
      gl_lds16(gs[4] + (size_t)(kt + 2) * gst[4], lds + sb + lo[4]);
      gl_lds16(gs[5] + (size_t)(kt + 2) * gst[5], lds + sb + lo[5]);
    }
    __builtin_amdgcn_s_barrier();
    asm volatile("s_waitcnt lgkmcnt(0)" ::: "memory");
    __builtin_amdgcn_sched_barrier(0);
    __builtin_amdgcn_s_setprio(1);
    MFB(c0, d0, acc[0][0]); MFB(c0, d1, acc[0][1]);
    MFB(c1, d0, acc[1][0]); MFB(c1, d1, acc[1][1]);
    MFB(m0, d0, acc[0][0]); MFB(m0, d1, acc[0][1]);
    MFB(m1, d0, acc[1][0]); MFB(m1, d1, acc[1][1]);
    __builtin_amdgcn_s_setprio(0);
    if (kt < 62) asm volatile("s_waitcnt vmcnt(6)" ::: "memory");
    else         asm volatile("s_waitcnt vmcnt(0)" ::: "memory");
    __builtin_amdgcn_s_barrier();
    __builtin_amdgcn_sched_barrier(0);
    cb += SUB_; if (cb == 3 * SUB_) cb = 0;
  }

  const int fr = lane & 31, g = lane >> 5;
  float* Cp = C + (size_t)(bm * 128 + wm * 64) * cstride + wn * 64;
  #pragma unroll
  for (int mt = 0; mt < 2; ++mt)
    #pragma unroll
    for (int nt = 0; nt < 2; ++nt) {
      #pragma unroll
      for (int r = 0; r < 16; ++r) {
        int row = mt * 32 + (r & 3) + 8 * (r >> 2) + 4 * g;
        Cp[(size_t)row * cstride + nt * 32 + fr] = acc[mt][nt][r];
      }
    }
}

__global__ __launch_bounds__(256, 2)
void mfma_q(const u16* __restrict__ hsHt, const u16* __restrict__ hsLt,
            const u16* __restrict__ WTh, float* __restrict__ q) {
  mfma_big_body(hsHt, hsLt, WTh, q + blockIdx.x * 128, 2048,
                blockIdx.y, blockIdx.x);
}

__global__ __launch_bounds__(128, 4)
void mfma_kv(const u16* __restrict__ hsHt, const u16* __restrict__ hsLt,
             const u16* __restrict__ WTh,
             float* __restrict__ k, float* __restrict__ v) {
  int bn = blockIdx.x;
  float* Cb; int co;
  if (bn < 2) { Cb = k; co = bn * 128; }
  else        { Cb = v; co = (bn - 2) * 128; }
  mfma_body(hsHt, hsLt, WTh, Cb + co, 256, blockIdx.y, 16 + bn);
}

__global__ __launch_bounds__(256, 2)
void mfma_wo(const u16* __restrict__ oHt, const u16* __restrict__ oLt,
             const u16* __restrict__ WoTh, float* __restrict__ out) {
  mfma_big_body(oHt, oLt, WoTh, out + blockIdx.x * 128, 2048,
                blockIdx.y, blockIdx.x);
}

__device__ __forceinline__ float wave_max64(float v) {
  #pragma unroll
  for (int off = 32; off > 0; off >>= 1) v = fmaxf(v, __shfl_xor(v, off, 64));
  return v;
}
__device__ __forceinline__ float wave_sum64(float v) {
  #pragma unroll
  for (int off = 32; off > 0; off >>= 1) v += __shfl_xor(v, off, 64);
  return v;
}

// ---------------------------------------------------------------------------
// Fused RoPE + hedgehog (blocks 0..4095) + prep_v branch (4096..4159).
// ---------------------------------------------------------------------------
__global__ __launch_bounds__(256)
void hedgehog_kernel(const float* __restrict__ q, const float* __restrict__ kx,
                     const float* __restrict__ fmq, const float* __restrict__ fmk,
                     const float* __restrict__ cosb, const float* __restrict__ sinb,
                     float* __restrict__ qf, float* __restrict__ kf,
                     const float* __restrict__ vsrc,
                     u16* __restrict__ vbH, u16* __restrict__ vbL) {
  int bid = blockIdx.x;
  if (bid >= 4096) {                    // fused prep_v: v chunk -> frag tiles
    int bn = bid - 4096;
    const float* vp = vsrc + (size_t)bn * 64 * HD_;
    size_t cbout = (size_t)bn * 16384;
    int d = threadIdx.x;
    #pragma unroll
    for (int it = 0; it < 8; ++it) {
      int j0 = it * 8;
      u16x8 hv, lv;
      #pragma unroll
      for (int c = 0; c < 8; ++c) {
        u16 hh, ll; bf16_split(vp[(size_t)(j0 + c) * HD_ + d], hh, ll);
        hv[c] = hh; lv[c] = ll;
      }
      size_t off = cbout + vb_off(d, j0);
      *(u16x8*)(vbH + off) = hv;
      *(u16x8*)(vbL + off) = lv;
    }
    return;
  }
  __shared__ __align__(16) float rows[4][4][256];
  const float* x; const float* fm; float* out; int nh_in, gb;
  if (bid < 2048) { x = q;  fm = fmq; out = qf; nh_in = 8; gb = bid * 4; }
  else            { x = kx; fm = fmk; out = kf; nh_in = 1; gb = (bid - 2048) * 4; }
  int wave = threadIdx.x >> 6, lane = threadIdx.x & 63;
  int g = gb + wave;
  int l4 = g & (L_/4 - 1);
  int bh = g / (L_/4);
  int h = bh & 7, b = bh >> 3;
  int l0 = l4 * 4;
  size_t rstride = (nh_in == 1) ? (size_t)HD_ : (size_t)H_ * HD_;
  const float* xrow = (nh_in == 1)
      ? x + (size_t)(b * L_ + l0) * HD_
      : x + ((size_t)(b * L_ + l0) * H_ + h) * HD_;
  int dd = (lane & 31) * 4;
  #pragma unroll
  for (int r = 0; r < 4; ++r) {
    float4 v = *(const float4*)(xrow + r * rstride + lane * 4);
    float4 u;
    u.x = __shfl_xor(v.x, 32, 64); u.y = __shfl_xor(v.y, 32, 64);
    u.z = __shfl_xor(v.z, 32, 64); u.w = __shfl_xor(v.w, 32, 64);
    int l = l0 + r;
    float4 c = *(const float4*)(cosb + (size_t)l * 128 + dd);
    float4 s = *(const float4*)(sinb + (size_t)l * 128 + dd);
    float4 ro;
    if (lane < 32) {
      ro.x = v.x * c.x - u.x * s.x; ro.y = v.y * c.y - u.y * s.y;
      ro.z = v.z * c.z - u.z * s.z; ro.w = v.w * c.w - u.w * s.w;
    } else {
      ro.x = u.x * s.x + v.x * c.x; ro.y = u.y * s.y + v.y * c.y;
      ro.z = u.z * s.z + v.z * c.z; ro.w = u.w * s.w + v.w * c.w;
    }
    *(float4*)&rows[wave][r][lane * 4] = ro;
  }
  __syncthreads();

  const float* fmh = fm + (size_t)h * HD_ * FD_;
  float p0 = 0.f, p1 = 0.f, p2 = 0.f, p3 = 0.f;
  for (int d2 = 0; d2 < HD_; d2 += 4) {
    float w0 = fmh[(d2 + 0) * FD_ + lane];
    float w1 = fmh[(d2 + 1) * FD_ + lane];
    float w2 = fmh[(d2 + 2) * FD_ + lane];
    float w3 = fmh[(d2 + 3) * FD_ + lane];
    float4 r0 = *(const float4*)&rows[wave][0][d2];
    float4 r1 = *(const float4*)&rows[wave][1][d2];
    float4 r2 = *(const float4*)&rows[wave][2][d2];
    float4 r3 = *(const float4*)&rows[wave][3][d2];
    p0 += r0.x * w0 + r0.y * w1 + r0.z * w2 + r0.w * w3;
    p1 += r1.x * w0 + r1.y * w1 + r1.z * w2 + r1.w * w3;
    p2 += r2.x * w0 + r2.y * w1 + r2.z * w2 + r2.w * w3;
    p3 += r3.x * w0 + r3.y * w1 + r3.z * w2 + r3.w * w3;
  }
  float p[4] = {p0, p1, p2, p3};
  #pragma unroll
  for (int r = 0; r < 4; ++r) {
    float m = wave_max64(fabsf(p[r]));
    float e1 = __expf(p[r] - m);
    float e2 = __expf(-p[r] - m);
    float z = wave_sum64(e1 + e2);
    float inv = 1.0f / z;
    size_t base = ((size_t)bh * L_ + l0 + r) * F_;
    out[base + lane]      = e1 * inv;
    out[base + 64 + lane] = e2 * inv;
  }
}

// ---------------------------------------------------------------------------
// Phase A: per-chunk kv_n[f][d] outer products -> frag-tiled split bf16.
// ---------------------------------------------------------------------------
__global__ __launch_bounds__(256)
void chunk_kv_kernel(const float* __restrict__ kf, const float* __restrict__ v,
                     u16* __restrict__ kvbH, u16* __restrict__ kvbL) {
  __shared__ __align__(16) float kfs[64][128];
  int n = blockIdx.x & (NC_ - 1), bh = blockIdx.x >> 5;
  int b = bh >> 3;
  const float* kfp = kf + ((size_t)bh * L_ + (size_t)n * 64) * F_;
  int t = threadIdx.x;
  #pragma unroll
  for (int it = 0; it < 8; ++it) {
    int flat = t * 4 + it * 1024;
    *(float4*)&kfs[flat >> 7][flat & 127] = *(const float4*)(kfp + flat);
  }
  __syncthreads();
  int dg = t & 63;
  int fg = t >> 6;
  const float* vp = v + (size_t)(b * L_ + n * 64) * HD_ + dg * 4;
  size_t cb = (size_t)blockIdx.x * 32768;
  #pragma unroll
  for (int pass = 0; pass < 4; ++pass) {
    int f0 = fg * 8 + pass * 32;
    float4 acc[8];
    #pragma unroll
    for (int i = 0; i < 8; ++i) acc[i] = make_float4(0.f, 0.f, 0.f, 0.f);
    for (int j = 0; j < 64; ++j) {
      float4 vv = *(const float4*)(vp + (size_t)j * HD_);
      float4 ka = *(const float4*)&kfs[j][f0];
      float4 kb = *(const float4*)&kfs[j][f0 + 4];
      FMA4(acc[0], ka.x, vv); FMA4(acc[1], ka.y, vv);
      FMA4(acc[2], ka.z, vv); FMA4(acc[3], ka.w, vv);
      FMA4(acc[4], kb.x, vv); FMA4(acc[5], kb.y, vv);
      FMA4(acc[6], kb.z, vv); FMA4(acc[7], kb.w, vv);
    }
    #pragma unroll
    for (int c = 0; c < 4; ++c) {
      u16x8 hv, lv;
      #pragma unroll
      for (int ff = 0; ff < 8; ++ff) {
        float xs = (c == 0) ? acc[ff].x : (c == 1) ? acc[ff].y
                 : (c == 2) ? acc[ff].z : acc[ff].w;
        u16 hh, ll; bf16_split(xs, hh, ll); hv[ff] = hh; lv[ff] = ll;
      }
      int d = dg * 4 + c;
      size_t off = cb + kvb_off(d, f0);
      *(u16x8*)(kvbH + off) = hv;
      *(u16x8*)(kvbL + off) = lv;
    }
  }
}

// Phase B: in-place exclusive prefix over the 32 chunks, on split bf16.
__global__ __launch_bounds__(256)
void chunk_scan_kernel(u16* __restrict__ kvbH, u16* __restrict__ kvbL) {
  int bh = blockIdx.x >> 4, g = blockIdx.x & 15;
  int d = threadIdx.x;
  size_t off = kvb_off(d, g * 8);
  float run[8] = {0.f, 0.f, 0.f, 0.f, 0.f, 0.f, 0.f, 0.f};
  for (int n = 0; n < NC_; ++n) {
    size_t a = ((size_t)(bh * 32 + n)) * 32768 + off;
    u16x8 hv = *(u16x8*)(kvbH + a);
    u16x8 lv = *(u16x8*)(kvbL + a);
    u16x8 oh, ol;
    #pragma unroll
    for (int c = 0; c < 8; ++c) {
      float val = __uint_as_float((unsigned)hv[c] << 16)
                + __uint_as_float((unsigned)lv[c] << 16);
      u16 hh, ll; bf16_split(run[c], hh, ll); oh[c] = hh; ol[c] = ll;
      run[c] += val;
    }
    *(u16x8*)(kvbH + a) = oh;
    *(u16x8*)(kvbL + a) = ol;
  }
}

// ---------------------------------------------------------------------------
// Phase C (MFMA): epilogue writes A-tiled split bf16 oHt/oLt directly.
// ---------------------------------------------------------------------------
__global__ __launch_bounds__(256, 2)
void chunk_attn_kernel(const float* __restrict__ qf, const float* __restrict__ kf,
                       const u16* __restrict__ vbH, const u16* __restrict__ vbL,
                       const u16* __restrict__ kvbH, const u16* __restrict__ kvbL,
                       u16* __restrict__ oHt, u16* __restrict__ oLt) {
  __shared__ __align__(16) u16 lds[32768];   // qsH|qsL|kfH|kfL
  const int n = blockIdx.x & (NC_ - 1), bh = blockIdx.x >> 5;
  const int h = bh & 7, b = bh >> 3;
  const int t = threadIdx.x;
  const int w = t >> 6, i31 = t & 31, G = (t >> 5) & 1;
  const int l8 = (t & 63) * 8;

  {
    const float* qp = qf + ((size_t)bh * L_ + (size_t)n * 64) * F_;
    const float* kp = kf + ((size_t)bh * L_ + (size_t)n * 64) * F_;
    int o8 = t & 15, ib = t >> 4;
    #pragma unroll
    for (int iter = 0; iter < 4; ++iter) {
      int i = ib + iter * 16;
      int it = i >> 5, ks = o8 >> 1;
      int sub = (it * 8 + ks) * 512 + (o8 & 1) * 256 + (i & 31) * 8;
      {
        const float* src = qp + (size_t)i * 128 + o8 * 8;
        float4 a = *(const float4*)src, c = *(const float4*)(src + 4);
        float vals[8] = {a.x, a.y, a.z, a.w, c.x, c.y, c.z, c.w};
        u16x8 hv, lv;
        #pragma unroll
        for (int j = 0; j < 8; ++j) {
          u16 hh, ll; bf16_split(vals[j] * SCALE_Q, hh, ll);
          hv[j] = hh; lv[j] = ll;
        }
        *(u16x8*)(lds + sub) = hv;
        *(u16x8*)(lds + 8192 + sub) = lv;
      }
      {
        const float* src = kp + (size_t)i * 128 + o8 * 8;
        float4 a = *(const float4*)src, c = *(const float4*)(src + 4);
        float vals[8] = {a.x, a.y, a.z, a.w, c.x, c.y, c.z, c.w};
        u16x8 hv, lv;
        #pragma unroll
        for (int j = 0; j < 8; ++j) {
          u16 hh, ll; bf16_split(vals[j], hh, ll);
          hv[j] = hh; lv[j] = ll;
        }
        *(u16x8*)(lds + 16384 + sub) = hv;
        *(u16x8*)(lds + 24576 + sub) = lv;
      }
    }
  }
  __syncthreads();

  const u16* Lq  = lds;
  const u16* Lql = lds + 8192;
  const u16* Lk  = lds + 16384;
  const u16* Lkl = lds + 24576;

  // ---- phase S: sT = kf · qs^T (3-pass split) ----
  f32x16 st[2][2];
  #pragma unroll
  for (int a = 0; a < 2; ++a)
    #pragma unroll
    for (int c = 0; c < 2; ++c)
      #pragma unroll
      for (int r = 0; r < 16; ++r) st[a][c][r] = 0.f;

  #pragma unroll
  for (int ks = 0; ks < 8; ++ks) {
    bf16x8 kh0 = *(const bf16x8*)(Lk  + ks * 512 + l8);
    bf16x8 kh1 = *(const bf16x8*)(Lk  + (8 + ks) * 512 + l8);
    bf16x8 kl0 = *(const bf16x8*)(Lkl + ks * 512 + l8);
    bf16x8 kl1 = *(const bf16x8*)(Lkl + (8 + ks) * 512 + l8);
    bf16x8 qh0 = *(const bf16x8*)(Lq  + ks * 512 + l8);
    bf16x8 qh1 = *(const bf16x8*)(Lq  + (8 + ks) * 512 + l8);
    bf16x8 ql0 = *(const bf16x8*)(Lql + ks * 512 + l8);
    bf16x8 ql1 = *(const bf16x8*)(Lql + (8 + ks) * 512 + l8);
    MFB(kh0, qh0, st[0][0]); MFB(kh0, ql0, st[0][0]); MFB(kl0, qh0, st[0][0]);
    MFB(kh0, qh1, st[0][1]); MFB(kh0, ql1, st[0][1]); MFB(kl0, qh1, st[0][1]);
    MFB(kh1, qh0, st[1][0]); MFB(kh1, ql0, st[1][0]); MFB(kl1, qh0, st[1][0]);
    MFB(kh1, qh1, st[1][1]); MFB(kh1, ql1, st[1][1]); MFB(kl1, qh1, st[1][1]);
  }

  // ---- mask + split + cross-lane transpose: sT C-regs -> s A-frags ----
  bf16x8 sfH[2][4], sfL[2][4];
  #pragma unroll
  for (int mt = 0; mt < 2; ++mt) {
    int iv = mt * 32 + i31;
    #pragma unroll
    for (int ksj = 0; ksj < 4; ++ksj) {
      const int jt = ksj >> 1, kb = ksj & 1;
      unsigned ph[4], pl[4];
      #pragma unroll
      for (int half = 0; half < 2; ++half) {
        u16 hh[4], ll[4];
        #pragma unroll
        for (int c = 0; c < 4; ++c) {
          int r = 8 * kb + 4 * half + c;
          int jv = jt * 32 + (r & 3) + 8 * (r >> 2) + 4 * G;
          float mv = (jv <= iv) ? st[jt][mt][r] : 0.f;
          u16 h_, l_; bf16_split(mv, h_, l_);
          hh[c] = h_; ll[c] = l_;
        }
        ph[half * 2 + 0] = (unsigned)hh[0] | ((unsigned)hh[1] << 16);
        ph[half * 2 + 1] = (unsigned)hh[2] | ((unsigned)hh[3] << 16);
        pl[half * 2 + 0] = (unsigned)ll[0] | ((unsigned)ll[1] << 16);
        pl[half * 2 + 1] = (unsigned)ll[2] | ((unsigned)ll[3] << 16);
      }
      unsigned rH1 = (unsigned)__shfl_xor((int)(G ? ph[0] : ph[2]), 32, 64);
      unsigned rH2 = (unsigned)__shfl_xor((int)(G ? ph[1] : ph[3]), 32, 64);
      unsigned rL1 = (unsigned)__shfl_xor((int)(G ? pl[0] : pl[2]), 32, 64);
      unsigned rL2 = (unsigned)__shfl_xor((int)(G ? pl[1] : pl[3]), 32, 64);
      u32x4 wH, wL;
      wH[0] = G ? rH1 : ph[0]; wH[1] = G ? rH2 : ph[1];
      wH[2] = G ? ph[2] : rH1; wH[3] = G ? ph[3] : rH2;
      wL[0] = G ? rL1 : pl[0]; wL[1] = G ? rL2 : pl[1];
      wL[2] = G ? pl[2] : rL1; wL[3] = G ? pl[3] : rL2;
      sfH[mt][ksj] = __builtin_bit_cast(bf16x8, wH);
      sfL[mt][ksj] = __builtin_bit_cast(bf16x8, wL);
    }
  }

  f32x16 acc[2][2];
  #pragma unroll
  for (int a = 0; a < 2; ++a)
    #pragma unroll
    for (int c = 0; c < 2; ++c)
      #pragma unroll
      for (int r = 0; r < 16; ++r) acc[a][c][r] = 0.f;

  // ---- phase A (intra): acc += s · v, v frags pre-tiled ----
  {
    size_t vcb = ((size_t)(b * NC_ + n)) * 16384;
    #pragma unroll
    for (int nt = 0; nt < 2; ++nt) {
      #pragma unroll
      for (int ksj = 0; ksj < 4; ++ksj) {
        size_t basev = vcb + vb_off(w * 64 + nt * 32, ksj * 16) + l8;
        bf16x8 vH = *(const bf16x8*)((const short*)(vbH + basev));
        bf16x8 vL = *(const bf16x8*)((const short*)(vbL + basev));
        MFB(sfH[0][ksj], vH, acc[0][nt]); MFB(sfL[0][ksj], vH, acc[0][nt]);
        MFB(sfH[0][ksj], vL, acc[0][nt]);
        MFB(sfH[1][ksj], vH, acc[1][nt]); MFB(sfL[1][ksj], vH, acc[1][nt]);
        MFB(sfH[1][ksj], vL, acc[1][nt]);
      }
    }
  }

  // ---- phase I (inter): acc += qs · kv_cum ----
  {
    size_t cb = (size_t)blockIdx.x * 32768;
    #pragma unroll
    for (int ks = 0; ks < 8; ++ks) {
      bf16x8 qa_h0 = *(const bf16x8*)(Lq  + ks * 512 + l8);
      bf16x8 qa_h1 = *(const bf16x8*)(Lq  + (8 + ks) * 512 + l8);
      bf16x8 qa_l0 = *(const bf16x8*)(Lql + ks * 512 + l8);
      bf16x8 qa_l1 = *(const bf16x8*)(Lql + (8 + ks) * 512 + l8);
      #pragma unroll
      for (int nt = 0; nt < 2; ++nt) {
        size_t base = cb + kvb_off(w * 64 + nt * 32, ks * 16) + l8;
        bf16x8 kvH = *(const bf16x8*)((const short*)(kvbH + base));
        bf16x8 kvL = *(const bf16x8*)((const short*)(kvbL + base));
        MFB(qa_h0, kvH, acc[0][nt]); MFB(qa_l0, kvH, acc[0][nt]);
        MFB(qa_h0, kvL, acc[0][nt]);
        MFB(qa_h1, kvH, acc[1][nt]); MFB(qa_l1, kvH, acc[1][nt]);
        MFB(qa_h1, kvL, acc[1][nt]);
      }
    }
  }

  // ---- fused epilogue: A-tiled split bf16 write ----
  {
    int p = b * NC_ + n;
    #pragma unroll
    for (int mt = 0; mt < 2; ++mt)
      #pragma unroll
      for (int nt = 0; nt < 2; ++nt) {
        int u_ = h * 32 + w * 8 + nt * 4 + (i31 >> 3);
        size_t ob = ((size_t)p * 64 + (u_ >> 2)) * 2048
                  + (size_t)((u_ >> 1) & 1) * 1024 + (size_t)mt * 512
                  + (size_t)(u_ & 1) * 256 + (size_t)(i31 & 7);
        #pragma unroll
        for (int r = 0; r < 16; ++r) {
          int rr = (r & 3) + 8 * (r >> 2) + 4 * G;
          u16 hh, ll; bf16_split(acc[mt][nt][r], hh, ll);
          oHt[ob + (size_t)rr * 8] = hh;
          oLt[ob + (size_t)rr * 8] = ll;
        }
      }
  }
}

// ---------------------------------------------------------------------------
extern "C" void kernel_launch(void* const* d_in, const int* in_sizes, int n_in,
                              void* d_out, int out_size, void* d_ws, size_t ws_size,
                              hipStream_t stream) {
  const float* hs   = (const float*)d_in[0];
  const float* fcos = (const float*)d_in[1];
  const float* fsin = (const float*)d_in[2];
  // d_in[3] = mask (all ones, unused)
  const float* Wq  = (const float*)d_in[4];
  const float* Wk  = (const float*)d_in[5];
  const float* Wv  = (const float*)d_in[6];
  const float* Wo  = (const float*)d_in[7];
  const float* fmq = (const float*)d_in[8];
  const float* fmk = (const float*)d_in[9];
  float* out = (float*)d_out;

  float* ws = (float*)d_ws;
  float* q  = ws;                                   // 32MB; later oHt/oLt
  float* k  = q  + (size_t)M_ * 2048;               // 4MB; later vb tiles
  float* v  = k  + (size_t)M_ * 256;                // 4MB
  float* qf = v  + (size_t)M_ * 256;                // 16MB
  float* kf = qf + (size_t)B_ * H_ * L_ * F_;       // 16MB
  float* kvr = kf + (size_t)B_ * H_ * L_ * F_;      // 64MB region

  u16* hsHt = (u16*)kvr;                      // 16 MB
  u16* hsLt = hsHt + (size_t)M_ * 2048;       // 16 MB
  u16* WTh  = hsLt + (size_t)M_ * 2048;       // 10 MB
  u16* kvbH = (u16*)kvr;                      // 32 MB
  u16* kvbL = kvbH + (size_t)512 * 32768;     // 32 MB
  u16* vbH  = (u16*)k;                        // 2 MB
  u16* vbL  = vbH + (size_t)64 * 16384;       // 2 MB
  u16* oHt  = (u16*)q;                        // 16 MB (q dead after hedgehog)
  u16* oLt  = oHt + (size_t)M_ * 2048;        // 16 MB

  // WoTh: own 8 MB past the 136 MB base if workspace allows (-> prep fusion);
  // else fall back to late separate launch aliasing kvr (kvb dead by then).
  const size_t WS_BASE = (size_t)142606336;   // 136 MB layout above
  bool bigws = ws_size >= WS_BASE + (size_t)8388608;
  u16* WoTh = bigws ? (u16*)((char*)d_ws + WS_BASE) : (u16*)kvr;

  // 1) Fused prep: hs split + Wq/Wk/Wv tiling (+ Wo tiling when bigws)
  prep_kernel<<<bigws ? 6400 : 5376, 256, 0, stream>>>(
      hs, Wq, Wk, Wv, Wo, hsHt, hsLt, WTh, WoTh);
  // 2a) q projection: 128x128 pipelined body, 512 blocks = 2/CU
  mfma_q<<<dim3(16, 32), 256, 0, stream>>>(hsHt, hsLt, WTh, q);
  // 2b) k/v projections: old body, 256 blocks
  mfma_kv<<<dim3(4, 64), 128, 0, stream>>>(hsHt, hsLt, WTh, k, v);
  // 3) Fused RoPE + hedgehog + prep_v branch (64 extra blocks)
  hedgehog_kernel<<<4096 + 64, 256, 0, stream>>>(q, k, fmq, fmk, fcos, fsin,
                                                 qf, kf, v, vbH, vbL);
  // 4) Per-chunk k^T v outer products -> split frag-tiled bf16; in-place scan
  chunk_kv_kernel<<<B_ * H_ * NC_, 256, 0, stream>>>(kf, v, kvbH, kvbL);
  chunk_scan_kernel<<<256, 256, 0, stream>>>(kvbH, kvbL);
  // 5) MFMA inter+intra chunk attention -> A-tiled split bf16 (fused epilogue)
  chunk_attn_kernel<<<B_ * H_ * NC_, 256, 0, stream>>>(qf, kf, vbH, vbL,
                                                       kvbH, kvbL, oHt, oLt);
  // 6) Output projection (fallback path tiles Wo late)
  if (!bigws)
    wtrans_wo<<<dim3(16, 64), 256, 0, stream>>>(Wo, WoTh);
  mfma_wo<<<dim3(16, 32), 256, 0, stream>>>(oHt, oLt, WoTh, out);
}

// Round 9
// 481.800 us; speedup vs baseline: 1.1590x; 1.0175x over previous
//
#include <hip/hip_runtime.h>

#define B_ 2
#define L_ 2048
#define D_ 2048
#define H_ 8
#define HD_ 256
#define FD_ 64
#define F_ 128          // 2*FD
#define NC_ 32          // L/CHUNK
#define M_ (B_*L_)      // 4096
#define SCALE_Q 0.08838834764831845f   // 128^-0.5

typedef unsigned short u16;
typedef __attribute__((ext_vector_type(8))) short bf16x8;
typedef __attribute__((ext_vector_type(8))) unsigned short u16x8;
typedef __attribute__((ext_vector_type(4))) unsigned short u16x4;
typedef __attribute__((ext_vector_type(16))) float f32x16;
typedef __attribute__((ext_vector_type(4))) unsigned int u32x4;

#define FMA4(a_, s_, v_) { (a_).x += (s_)*(v_).x; (a_).y += (s_)*(v_).y; \
                           (a_).z += (s_)*(v_).z; (a_).w += (s_)*(v_).w; }

// ---------------------------------------------------------------------------
// Tiled operand layouts (read-major: memory order == MFMA fragment order).
// 512-u16 chunk (one 32xK16 fragment set): addr = ((k>>3)&1)*256 + (x&31)*8
// + (k&7). Lane l reads u16x8 at chunk + l*8 -> (x = l&31, k = ks*16 +
// (l>>5)*8 + elem). Symmetric between A-frags and B-frags.
// ---------------------------------------------------------------------------

__device__ __forceinline__ u16 bf16_rne(float x) {
  unsigned u = __float_as_uint(x);
  return (u16)((u + 0x7fffu + ((u >> 16) & 1u)) >> 16);
}
__device__ __forceinline__ void bf16_split(float x, u16& h, u16& l) {
  unsigned u = __float_as_uint(x);
  unsigned hb = (u + 0x7fffu + ((u >> 16) & 1u)) >> 16;
  h = (u16)hb;
  float hf = __uint_as_float(hb << 16);
  l = bf16_rne(x - hf);
}

__device__ __forceinline__ void gl_lds16(const u16* g, u16* l) {
  __builtin_amdgcn_global_load_lds(
      (const __attribute__((address_space(1))) unsigned int*)g,
      (__attribute__((address_space(3))) unsigned int*)l, 16, 0, 0);
}

// kvb frag-tiled offset: per-chunk [2 d-panel][4 f-kt][4096] (F=128,HD=256).
__device__ __forceinline__ size_t kvb_off(int d, int f) {
  return (size_t)(((d >> 7) & 1) * 16384 + ((f >> 5) & 3) * 4096 +
                  ((d >> 6) & 1) * 2048 + ((f >> 4) & 1) * 1024 +
                  ((d >> 5) & 1) * 512 + ((f >> 3) & 1) * 256 +
                  (d & 31) * 8 + (f & 7));
}
// vb frag-tiled offset: per-chunk (J=64,HD=256) -> 16384 u16.
__device__ __forceinline__ size_t vb_off(int d, int j) {
  return (size_t)(((d >> 7) & 1) * 8192 + ((j >> 5) & 1) * 4096 +
                  ((d >> 6) & 1) * 2048 + ((j >> 4) & 1) * 1024 +
                  ((d >> 5) & 1) * 512 + ((j >> 3) & 1) * 256 +
                  (d & 31) * 8 + (j & 7));
}

// ---------------------------------------------------------------------------
// W[K=2048][Nsrc] fp32 -> B-tiled bf16 (panel P, ktile kt).
// ---------------------------------------------------------------------------
__device__ __forceinline__ void wtrans_body(const float* __restrict__ W, int Nsrc,
                                            int n0, u16* __restrict__ dst,
                                            int P, int kt) {
  int t = threadIdx.x;
  int nn = t & 127, kh = t >> 7;
  const float* src = W + (size_t)(kt * 32 + kh * 16) * Nsrc + n0 + nn;
  u16x8 u0, u1;
  #pragma unroll
  for (int kk = 0; kk < 8; ++kk) u0[kk] = bf16_rne(src[(size_t)kk * Nsrc]);
  #pragma unroll
  for (int kk = 0; kk < 8; ++kk) u1[kk] = bf16_rne(src[(size_t)(kk + 8) * Nsrc]);
  size_t base = ((size_t)P * 64 + kt) * 4096 + (size_t)((nn >> 6) & 1) * 2048
              + (size_t)kh * 1024 + (size_t)((nn >> 5) & 1) * 512
              + (size_t)(nn & 31) * 8;
  *(u16x8*)(dst + base) = u0;
  *(u16x8*)(dst + base + 256) = u1;
}

// Fused prep: hs split (0..4095) + Wq|Wk|Wv tiling (4096..5375) +
// fmq/fmk B-frag tiling (5376..5503) + (bigws) Wo tiling (5504..6527).
__global__ __launch_bounds__(256)
void prep_kernel(const float* __restrict__ hs,
                 const float* __restrict__ Wq, const float* __restrict__ Wk,
                 const float* __restrict__ Wv, const float* __restrict__ Wo,
                 const float* __restrict__ fmq, const float* __restrict__ fmk,
                 u16* __restrict__ hsHt, u16* __restrict__ hsLt,
                 u16* __restrict__ WTh, u16* __restrict__ WoTh,
                 u16* __restrict__ fmbtH, u16* __restrict__ fmbtL) {
  int bid = blockIdx.x;
  if (bid < 4096) {
    int gid = bid * 256 + threadIdx.x;
    int r = gid >> 8, u = gid & 255;
    const float* src = hs + (size_t)r * 2048 + u * 8;
    float4 v0 = *(const float4*)src, v1 = *(const float4*)(src + 4);
    float vals[8] = {v0.x, v0.y, v0.z, v0.w, v1.x, v1.y, v1.z, v1.w};
    u16x8 hv, lv;
    #pragma unroll
    for (int j = 0; j < 8; ++j) { u16 hh, ll; bf16_split(vals[j], hh, ll); hv[j] = hh; lv[j] = ll; }
    size_t off = ((size_t)(r >> 6) * 64 + (u >> 2)) * 2048
               + (size_t)((u >> 1) & 1) * 1024 + (size_t)((r >> 5) & 1) * 512
               + (size_t)(u & 1) * 256 + (size_t)(r & 31) * 8;
    *(u16x8*)(hsHt + off) = hv;
    *(u16x8*)(hsLt + off) = lv;
  } else if (bid < 5376) {
    int idx = bid - 4096;
    int P = idx >> 6, kt = idx & 63;
    const float* W; int Nsrc, n0;
    if (P < 16)      { W = Wq; Nsrc = 2048; n0 = P * 128; }
    else if (P < 18) { W = Wk; Nsrc = 256;  n0 = (P - 16) * 128; }
    else             { W = Wv; Nsrc = 256;  n0 = (P - 18) * 128; }
    wtrans_body(W, Nsrc, n0, WTh, P, kt);
  } else if (bid < 5504) {
    // fm B-frag tiling: per (h16, kt): 64 cols x 32 k -> 2048-u16 chunk.
    int idx = bid - 5376;                  // 0..127
    int h16 = idx >> 3, kt = idx & 7;
    const float* src = (h16 < 8) ? (fmq + (size_t)h16 * 16384)
                                 : (fmk + (size_t)(h16 - 8) * 16384);
    int t = threadIdx.x;
    int f = t & 63, kq = t >> 6;           // k = kq*8 + i
    u16x8 hv, lv;
    #pragma unroll
    for (int i = 0; i < 8; ++i) {
      float val = src[(size_t)(kt * 32 + kq * 8 + i) * 64 + f];
      u16 hh, ll; bf16_split(val, hh, ll); hv[i] = hh; lv[i] = ll;
    }
    size_t base = (size_t)(h16 * 8 + kt) * 2048 + (size_t)(kq >> 1) * 1024
                + (size_t)(f >> 5) * 512 + (size_t)(kq & 1) * 256
                + (size_t)(f & 31) * 8;
    *(u16x8*)(fmbtH + base) = hv;
    *(u16x8*)(fmbtL + base) = lv;
  } else {
    int idx = bid - 5504;
    wtrans_body(Wo, 2048, (idx >> 6) * 128, WoTh, idx >> 6, idx & 63);
  }
}

// Fallback standalone Wo tiling (small-workspace path).
__global__ __launch_bounds__(256)
void wtrans_wo(const float* __restrict__ Wo, u16* __restrict__ WoTh) {
  wtrans_body(Wo, 2048, blockIdx.x * 128, WoTh, blockIdx.x, blockIdx.y);
}

// Standalone prep_v (fallback path; bigws fuses into mfma_hh).
__global__ __launch_bounds__(256)
void prep_v(const float* __restrict__ v, u16* __restrict__ vbH,
            u16* __restrict__ vbL) {
  int bn = blockIdx.x;
  const float* vp = v + (size_t)bn * 64 * HD_;
  size_t cbout = (size_t)bn * 16384;
  int d = threadIdx.x;
  #pragma unroll
  for (int it = 0; it < 8; ++it) {
    int j0 = it * 8;
    u16x8 hv, lv;
    #pragma unroll
    for (int c = 0; c < 8; ++c) {
      u16 hh, ll; bf16_split(vp[(size_t)(j0 + c) * HD_ + d], hh, ll);
      hv[c] = hh; lv[c] = ll;
    }
    size_t off = cbout + vb_off(d, j0);
    *(u16x8*)(vbH + off) = hv;
    *(u16x8*)(vbL + off) = lv;
  }
}

// ---------------------------------------------------------------------------
// OLD 2-pass split-bf16 MFMA GEMM (64x128 tile, BK=32, 128 threads).
// ---------------------------------------------------------------------------
__device__ __forceinline__ void mfma_body(
    const u16* __restrict__ AtH, const u16* __restrict__ AtL,
    const u16* __restrict__ Bt, float* __restrict__ C, int cstride,
    int bm, int bn) {
  __shared__ __align__(16) u16 AsH[2048];
  __shared__ __align__(16) u16 AsL[2048];
  __shared__ __align__(16) u16 Bs[4096];
  const int t = threadIdx.x, lane = t & 63, wv = t >> 6;
  const u16* aSrc = (wv ? AtL : AtH) + (size_t)bm * 131072 + lane * 8;
  const u16* bSrc = Bt + (size_t)bn * 262144 + wv * 2048 + lane * 8;
  u16* aDst = wv ? AsL : AsH;
  u16* bDst = Bs + wv * 2048;

  f32x16 acc[2][2];
  #pragma unroll
  for (int a = 0; a < 2; ++a)
    #pragma unroll
    for (int b2 = 0; b2 < 2; ++b2)
      #pragma unroll
      for (int r = 0; r < 16; ++r) acc[a][b2][r] = 0.f;

  for (int kt = 0; kt < 64; ++kt) {
    const u16* ak = aSrc + (size_t)kt * 2048;
    const u16* bk = bSrc + (size_t)kt * 4096;
    __syncthreads();
    #pragma unroll
    for (int c = 0; c < 4; ++c) {
      gl_lds16(ak + c * 512, aDst + c * 512);
      gl_lds16(bk + c * 512, bDst + c * 512);
    }
    __syncthreads();

    #pragma unroll
    for (int ks = 0; ks < 2; ++ks) {
      const u16* ph = AsH + ks * 1024 + lane * 8;
      const u16* pl = AsL + ks * 1024 + lane * 8;
      const u16* pb = Bs + wv * 2048 + ks * 1024 + lane * 8;
      bf16x8 a0 = *(const bf16x8*)ph;
      bf16x8 a1 = *(const bf16x8*)(ph + 512);
      bf16x8 b0 = *(const bf16x8*)pb;
      bf16x8 b1 = *(const bf16x8*)(pb + 512);
      acc[0][0] = __builtin_amdgcn_mfma_f32_32x32x16_bf16(a0, b0, acc[0][0], 0, 0, 0);
      acc[0][1] = __builtin_amdgcn_mfma_f32_32x32x16_bf16(a0, b1, acc[0][1], 0, 0, 0);
      acc[1][0] = __builtin_amdgcn_mfma_f32_32x32x16_bf16(a1, b0, acc[1][0], 0, 0, 0);
      acc[1][1] = __builtin_amdgcn_mfma_f32_32x32x16_bf16(a1, b1, acc[1][1], 0, 0, 0);
      bf16x8 l0 = *(const bf16x8*)pl;
      bf16x8 l1 = *(const bf16x8*)(pl + 512);
      acc[0][0] = __builtin_amdgcn_mfma_f32_32x32x16_bf16(l0, b0, acc[0][0], 0, 0, 0);
      acc[0][1] = __builtin_amdgcn_mfma_f32_32x32x16_bf16(l0, b1, acc[0][1], 0, 0, 0);
      acc[1][0] = __builtin_amdgcn_mfma_f32_32x32x16_bf16(l1, b0, acc[1][0], 0, 0, 0);
      acc[1][1] = __builtin_amdgcn_mfma_f32_32x32x16_bf16(l1, b1, acc[1][1], 0, 0, 0);
    }
  }

  const int fr = lane & 31, g = lane >> 5;
  float* Cp = C + (size_t)(bm * 64) * cstride + wv * 64;
  #pragma unroll
  for (int mt = 0; mt < 2; ++mt)
    #pragma unroll
    for (int nt = 0; nt < 2; ++nt) {
      #pragma unroll
      for (int r = 0; r < 16; ++r) {
        int row = mt * 32 + (r & 3) + 8 * (r >> 2) + 4 * g;
        Cp[(size_t)row * cstride + nt * 32 + fr] = acc[mt][nt][r];
      }
    }
}

// ---------------------------------------------------------------------------
// Pipelined body v3: 128x128 tile, 4 waves, BK=32, triple ring (72 KB ->
// 2 blocks/CU), phase-split + counted vmcnt(6) + setprio. (R8-verified.)
// ---------------------------------------------------------------------------
#define SUB_ 12288
#define MFB(a_, b_, c_) (c_) = __builtin_amdgcn_mfma_f32_32x32x16_bf16((a_), (b_), (c_), 0, 0, 0)

__device__ __forceinline__ void mfma_big_body(
    const u16* __restrict__ AtH, const u16* __restrict__ AtL,
    const u16* __restrict__ Bt, float* __restrict__ C, int cstride,
    int bm, int bn) {
  __shared__ __align__(16) u16 lds[3 * SUB_];
  const int t = threadIdx.x, lane = t & 63, wv = t >> 6;
  const int wm = wv >> 1, wn = wv & 1;

  const u16* gs[6];
  unsigned lo[6], gst[6];
  #pragma unroll
  for (int j = 0; j < 6; ++j) {
    int line = wv * 6 + j;
    if (line < 8) {
      gs[j] = AtH + ((size_t)(2 * bm + (line >> 2)) * 64) * 2048
                  + (size_t)(line & 3) * 512 + lane * 8;
      gst[j] = 2048;
    } else if (line < 16) {
      int l2 = line - 8;
      gs[j] = AtL + ((size_t)(2 * bm + (l2 >> 2)) * 64) * 2048
                  + (size_t)(l2 & 3) * 512 + lane * 8;
      gst[j] = 2048;
    } else {
      int l3 = line - 16;
      gs[j] = Bt + (size_t)bn * 262144 + (size_t)l3 * 512 + lane * 8;
      gst[j] = 4096;
    }
    lo[j] = line * 512;
  }

  f32x16 acc[2][2];
  #pragma unroll
  for (int a = 0; a < 2; ++a)
    #pragma unroll
    for (int b2 = 0; b2 < 2; ++b2)
      #pragma unroll
      for (int r = 0; r < 16; ++r) acc[a][b2][r] = 0.f;

  #pragma unroll
  for (int j = 0; j < 6; ++j) gl_lds16(gs[j], lds + lo[j]);
  #pragma unroll
  for (int j = 0; j < 6; ++j) gl_lds16(gs[j] + gst[j], lds + SUB_ + lo[j]);
  asm volatile("s_waitcnt vmcnt(6)" ::: "memory");
  __builtin_amdgcn_s_barrier();
  __builtin_amdgcn_sched_barrier(0);

  int cb = 0;
  for (int kt = 0; kt < 64; ++kt) {
    int sb = cb + 2 * SUB_; if (sb >= 3 * SUB_) sb -= 3 * SUB_;
    const u16* base = lds + cb;
    const u16* ph0 = base + wm * 2048 + lane * 8;
    const u16* pb0 = base + 8192 + wn * 2048 + lane * 8;

    bf16x8 a0 = *(const bf16x8*)(ph0);
    bf16x8 a1 = *(const bf16x8*)(ph0 + 512);
    bf16x8 l0 = *(const bf16x8*)(ph0 + 4096);
    bf16x8 l1 = *(const bf16x8*)(ph0 + 4608);
    bf16x8 b0 = *(const bf16x8*)(pb0);
    bf16x8 b1 = *(const bf16x8*)(pb0 + 512);
    if (kt < 62) {
      gl_lds16(gs[0] + (size_t)(kt + 2) * gst[0], lds + sb + lo[0]);
      gl_lds16(gs[1] + (size_t)(kt + 2) * gst[1], lds + sb + lo[1]);
      gl_lds16(gs[2] + (size_t)(kt + 2) * gst[2], lds + sb + lo[2]);
    }
    __builtin_amdgcn_s_barrier();
    asm volatile("s_waitcnt lgkmcnt(0)" ::: "memory");
    __builtin_amdgcn_sched_barrier(0);
    __builtin_amdgcn_s_setprio(1);
    MFB(a0, b0, acc[0][0]); MFB(a0, b1, acc[0][1]);
    MFB(a1, b0, acc[1][0]); MFB(a1, b1, acc[1][1]);
    MFB(l0, b0, acc[0][0]); MFB(l0, b1, acc[0][1]);
    MFB(l1, b0, acc[1][0]); MFB(l1, b1, acc[1][1]);
    __builtin_amdgcn_s_setprio(0);
    __builtin_amdgcn_s_barrier();
    __builtin_amdgcn_sched_barrier(0);

    bf16x8 c0 = *(const bf16x8*)(ph0 + 1024);
    bf16x8 c1 = *(const bf16x8*)(ph0 + 1536);
    bf16x8 m0 = *(const bf16x8*)(ph0 + 5120);
    bf16x8 m1 = *(const bf16x8*)(ph0 + 5632);
    bf16x8 d0 = *(const bf16x8*)(pb0 + 1024);
    bf16x8 d1 = *(const bf16x8*)(pb0 + 1536);
    if (kt < 62) {
      gl_lds16(gs[3] + (size_t)(kt + 2) * gst[3], lds + sb + lo[3]);
      gl_lds16(gs[4] + (size_t)(kt + 2) * gst[4], lds + sb + lo[4]);
      gl_lds16(gs[5] + (size_t)(kt + 2) * gst[5], lds + sb + lo[5]);
    }
    __builtin_amdgcn_s_barrier();
    asm volatile("s_waitcnt lgkmcnt(0)" ::: "memory");
    __builtin_amdgcn_sched_barrier(0);
    __builtin_amdgcn_s_setprio(1);
    MFB(c0, d0, acc[0][0]); MFB(c0, d1, acc[0][1]);
    MFB(c1, d0, acc[1][0]); MFB(c1, d1, acc[1][1]);
    MFB(m0, d0, acc[0][0]); MFB(m0, d1, acc[0][1]);
    MFB(m1, d0, acc[1][0]); MFB(m1, d1, acc[1][1]);
    __builtin_amdgcn_s_setprio(0);
    if (kt < 62) asm volatile("s_waitcnt vmcnt(6)" ::: "memory");
    else         asm volatile("s_waitcnt vmcnt(0)" ::: "memory");
    __builtin_amdgcn_s_barrier();
    __builtin_amdgcn_sched_barrier(0);
    cb += SUB_; if (cb == 3 * SUB_) cb = 0;
  }

  const int fr = lane & 31, g = lane >> 5;
  float* Cp = C + (size_t)(bm * 128 + wm * 64) * cstride + wn * 64;
  #pragma unroll
  for (int mt = 0; mt < 2; ++mt)
    #pragma unroll
    for (int nt = 0; nt < 2; ++nt) {
      #pragma unroll
      for (int r = 0; r < 16; ++r) {
        int row = mt * 32 + (r & 3) + 8 * (r >> 2) + 4 * g;
        Cp[(size_t)row * cstride + nt * 32 + fr] = acc[mt][nt][r];
      }
    }
}

__global__ __launch_bounds__(256, 2)
void mfma_q(const u16* __restrict__ hsHt, const u16* __restrict__ hsLt,
            const u16* __restrict__ WTh, float* __restrict__ q) {
  mfma_big_body(hsHt, hsLt, WTh, q + blockIdx.x * 128, 2048,
                blockIdx.y, blockIdx.x);
}

__global__ __launch_bounds__(128, 4)
void mfma_kv(const u16* __restrict__ hsHt, const u16* __restrict__ hsLt,
             const u16* __restrict__ WTh,
             float* __restrict__ k, float* __restrict__ v) {
  int bn = blockIdx.x;
  float* Cb; int co;
  if (bn < 2) { Cb = k; co = bn * 128; }
  else        { Cb = v; co = (bn - 2) * 128; }
  mfma_body(hsHt, hsLt, WTh, Cb + co, 256, blockIdx.y, 16 + bn);
}

__global__ __launch_bounds__(256, 2)
void mfma_wo(const u16* __restrict__ oHt, const u16* __restrict__ oLt,
             const u16* __restrict__ WoTh, float* __restrict__ out) {
  mfma_big_body(oHt, oLt, WoTh, out + blockIdx.x * 128, 2048,
                blockIdx.y, blockIdx.x);
}

// ---------------------------------------------------------------------------
// mfma_hh: RoPE + hedgehog projection via MFMA (replaces hedgehog_kernel).
// Block = 128 rows x 1 head (h16: 0-7 q, 8-15 k). 256 thr / 4 waves.
// Stage: coalesced read of x rows, RoPE in-register, split-bf16 A-frags to
// LDS ([8kt][4 rowtile][2 HL][1024 u16] = 128 KB). fm read as pre-tiled
// B-frag chunks (prep). 96 MFMA/wave (3-pass split). Softmax in-register:
// m = max|p| / Z via 5 shfl_xor over the 32-lane feature group.
// Blocks >= 512 (bigws): fused prep_v.
// ---------------------------------------------------------------------------
__global__ __launch_bounds__(256, 1)
void mfma_hh(const float* __restrict__ q, const float* __restrict__ kx,
             const float* __restrict__ cosb, const float* __restrict__ sinb,
             const u16* __restrict__ fmbtH, const u16* __restrict__ fmbtL,
             float* __restrict__ qf, float* __restrict__ kf,
             const float* __restrict__ vsrc,
             u16* __restrict__ vbH, u16* __restrict__ vbL) {
  int bid = blockIdx.x;
  if (bid >= 512) {                     // fused prep_v (bigws path)
    int bn = bid - 512;
    const float* vp = vsrc + (size_t)bn * 64 * HD_;
    size_t cbout = (size_t)bn * 16384;
    int d = threadIdx.x;
    #pragma unroll
    for (int it = 0; it < 8; ++it) {
      int j0 = it * 8;
      u16x8 hv, lv;
      #pragma unroll
      for (int c = 0; c < 8; ++c) {
        u16 hh, ll; bf16_split(vp[(size_t)(j0 + c) * HD_ + d], hh, ll);
        hv[c] = hh; lv[c] = ll;
      }
      size_t off = cbout + vb_off(d, j0);
      *(u16x8*)(vbH + off) = hv;
      *(u16x8*)(vbL + off) = lv;
    }
    return;
  }
  __shared__ __align__(16) u16 xlds[65536];   // [kt][rt32][hl][1024]
  const int t = threadIdx.x;
  const int rt = bid & 31, h16 = bid >> 5;
  const int rowbase = rt * 128;
  const float* xsrc; size_t xstr;
  if (h16 < 8) { xsrc = q + (size_t)h16 * 256; xstr = 2048; }
  else         { xsrc = kx;                    xstr = 256; }

  // ---- stage: RoPE + split -> A-frag LDS ----
  for (int iter = 0; iter < 16; ++iter) {
    int flat = iter * 1024 + t * 4;          // 128 rows x 128 dd
    int r = flat >> 7, dd = flat & 127;
    int grow = rowbase + r;
    int l = grow & 2047;
    const float* xr = xsrc + (size_t)grow * xstr + dd;
    float4 x1 = *(const float4*)xr;
    float4 x2 = *(const float4*)(xr + 128);
    float4 c  = *(const float4*)(cosb + (size_t)l * 128 + dd);
    float4 s  = *(const float4*)(sinb + (size_t)l * 128 + dd);
    float lo4[4] = {x1.x*c.x - x2.x*s.x, x1.y*c.y - x2.y*s.y,
                    x1.z*c.z - x2.z*s.z, x1.w*c.w - x2.w*s.w};
    float hi4[4] = {x1.x*s.x + x2.x*c.x, x1.y*s.y + x2.y*c.y,
                    x1.z*s.z + x2.z*c.z, x1.w*s.w + x2.w*c.w};
    int rt32 = r >> 5, r5 = r & 31;
    #pragma unroll
    for (int half = 0; half < 2; ++half) {
      int d = dd + half * 128;
      int kt = d >> 5, k = d & 31;
      unsigned base = (unsigned)((kt * 4 + rt32) * 2) * 1024
                    + (unsigned)(k >> 4) * 512 + (unsigned)((k >> 3) & 1) * 256
                    + (unsigned)r5 * 8 + (unsigned)(k & 7);
      const float* vv = half ? hi4 : lo4;
      u16x4 hv, lv;
      #pragma unroll
      for (int j = 0; j < 4; ++j) {
        u16 hh, ll; bf16_split(vv[j], hh, ll); hv[j] = hh; lv[j] = ll;
      }
      *(u16x4*)(xlds + base) = hv;
      *(u16x4*)(xlds + 1024 + base) = lv;
    }
  }
  __syncthreads();

  // ---- MFMA: wave w = rowtile, both nt; 3-pass split ----
  const int w = t >> 6, lane = t & 63;
  f32x16 acc[2];
  #pragma unroll
  for (int nt = 0; nt < 2; ++nt)
    #pragma unroll
    for (int r = 0; r < 16; ++r) acc[nt][r] = 0.f;

  const u16* fmbH = fmbtH + (size_t)h16 * 8 * 2048;
  const u16* fmbL = fmbtL + (size_t)h16 * 8 * 2048;
  #pragma unroll
  for (int kt = 0; kt < 8; ++kt) {
    unsigned xb = (unsigned)((kt * 4 + w) * 2) * 1024;
    #pragma unroll
    for (int ks = 0; ks < 2; ++ks) {
      bf16x8 xh = *(const bf16x8*)(xlds + xb + ks * 512 + lane * 8);
      bf16x8 xl = *(const bf16x8*)(xlds + xb + 1024 + ks * 512 + lane * 8);
      #pragma unroll
      for (int nt = 0; nt < 2; ++nt) {
        size_t fb = (size_t)kt * 2048 + ks * 1024 + nt * 512 + lane * 8;
        bf16x8 bh_ = *(const bf16x8*)((const short*)(fmbH + fb));
        bf16x8 bl_ = *(const bf16x8*)((const short*)(fmbL + fb));
        MFB(xh, bh_, acc[nt]); MFB(xl, bh_, acc[nt]); MFB(xh, bl_, acc[nt]);
      }
    }
  }

  // ---- softmax over concat(p,-p) + store qf/kf ----
  const int g = lane >> 5, f31 = lane & 31;
  float* outp = (h16 < 8) ? qf : kf;
  const int hh = h16 & 7;
  #pragma unroll
  for (int r = 0; r < 16; ++r) {
    int rowl = (r & 3) + 8 * (r >> 2) + 4 * g;
    int grow = rowbase + w * 32 + rowl;
    float p0 = acc[0][r], p1 = acc[1][r];
    float m = fmaxf(fabsf(p0), fabsf(p1));
    #pragma unroll
    for (int off = 16; off > 0; off >>= 1) m = fmaxf(m, __shfl_xor(m, off, 64));
    float e0 = __expf(p0 - m),  e0n = __expf(-p0 - m);
    float e1 = __expf(p1 - m),  e1n = __expf(-p1 - m);
    float zl = e0 + e0n + e1 + e1n;
    #pragma unroll
    for (int off = 16; off > 0; off >>= 1) zl += __shfl_xor(zl, off, 64);
    float inv = 1.0f / zl;
    int b = grow >> 11, l = grow & 2047;
    size_t ob = ((size_t)((b * 8 + hh) * 2048 + l)) * 128;
    outp[ob + f31]       = e0 * inv;
    outp[ob + 32 + f31]  = e1 * inv;
    outp[ob + 64 + f31]  = e0n * inv;
    outp[ob + 96 + f31]  = e1n * inv;
  }
}

// ---------------------------------------------------------------------------
// Phase A: per-chunk kv_n[f][d] outer products -> frag-tiled split bf16.
// ---------------------------------------------------------------------------
__global__ __launch_bounds__(256)
void chunk_kv_kernel(const float* __restrict__ kf, const float* __restrict__ v,
                     u16* __restrict__ kvbH, u16* __restrict__ kvbL) {
  __shared__ __align__(16) float kfs[64][128];
  int n = blockIdx.x & (NC_ - 1), bh = blockIdx.x >> 5;
  int b = bh >> 3;
  const float* kfp = kf + ((size_t)bh * L_ + (size_t)n * 64) * F_;
  int t = threadIdx.x;
  #pragma unroll
  for (int it = 0; it < 8; ++it) {
    int flat = t * 4 + it * 1024;
    *(float4*)&kfs[flat >> 7][flat & 127] = *(const float4*)(kfp + flat);
  }
  __syncthreads();
  int dg = t & 63;
  int fg = t >> 6;
  const float* vp = v + (size_t)(b * L_ + n * 64) * HD_ + dg * 4;
  size_t cb = (size_t)blockIdx.x * 32768;
  #pragma unroll
  for (int pass = 0; pass < 4; ++pass) {
    int f0 = fg * 8 + pass * 32;
    float4 acc[8];
    #pragma unroll
    for (int i = 0; i < 8; ++i) acc[i] = make_float4(0.f, 0.f, 0.f, 0.f);
    for (int j = 0; j < 64; ++j) {
      float4 vv = *(const float4*)(vp + (size_t)j * HD_);
      float4 ka = *(const float4*)&kfs[j][f0];
      float4 kb = *(const float4*)&kfs[j][f0 + 4];
      FMA4(acc[0], ka.x, vv); FMA4(acc[1], ka.y, vv);
      FMA4(acc[2], ka.z, vv); FMA4(acc[3], ka.w, vv);
      FMA4(acc[4], kb.x, vv); FMA4(acc[5], kb.y, vv);
      FMA4(acc[6], kb.z, vv); FMA4(acc[7], kb.w, vv);
    }
    #pragma unroll
    for (int c = 0; c < 4; ++c) {
      u16x8 hv, lv;
      #pragma unroll
      for (int ff = 0; ff < 8; ++ff) {
        float xs = (c == 0) ? acc[ff].x : (c == 1) ? acc[ff].y
                 : (c == 2) ? acc[ff].z : acc[ff].w;
        u16 hh, ll; bf16_split(xs, hh, ll); hv[ff] = hh; lv[ff] = ll;
      }
      int d = dg * 4 + c;
      size_t off = cb + kvb_off(d, f0);
      *(u16x8*)(kvbH + off) = hv;
      *(u16x8*)(kvbL + off) = lv;
    }
  }
}

// Phase B: in-place exclusive prefix over the 32 chunks, on split bf16.
__global__ __launch_bounds__(256)
void chunk_scan_kernel(u16* __restrict__ kvbH, u16* __restrict__ kvbL) {
  int bh = blockIdx.x >> 4, g = blockIdx.x & 15;
  int d = threadIdx.x;
  size_t off = kvb_off(d, g * 8);
  float run[8] = {0.f, 0.f, 0.f, 0.f, 0.f, 0.f, 0.f, 0.f};
  for (int n = 0; n < NC_; ++n) {
    size_t a = ((size_t)(bh * 32 + n)) * 32768 + off;
    u16x8 hv = *(u16x8*)(kvbH + a);
    u16x8 lv = *(u16x8*)(kvbL + a);
    u16x8 oh, ol;
    #pragma unroll
    for (int c = 0; c < 8; ++c) {
      float val = __uint_as_float((unsigned)hv[c] << 16)
                + __uint_as_float((unsigned)lv[c] << 16);
      u16 hh, ll; bf16_split(run[c], hh, ll); oh[c] = hh; ol[c] = ll;
      run[c] += val;
    }
    *(u16x8*)(kvbH + a) = oh;
    *(u16x8*)(kvbL + a) = ol;
  }
}

// ---------------------------------------------------------------------------
// Phase C (MFMA): epilogue writes A-tiled split bf16 oHt/oLt directly.
// ---------------------------------------------------------------------------
__global__ __launch_bounds__(256, 2)
void chunk_attn_kernel(const float* __restrict__ qf, const float* __restrict__ kf,
                       const u16* __restrict__ vbH, const u16* __restrict__ vbL,
                       const u16* __restrict__ kvbH, const u16* __restrict__ kvbL,
                       u16* __restrict__ oHt, u16* __restrict__ oLt) {
  __shared__ __align__(16) u16 lds[32768];   // qsH|qsL|kfH|kfL
  const int n = blockIdx.x & (NC_ - 1), bh = blockIdx.x >> 5;
  const int h = bh & 7, b = bh >> 3;
  const int t = threadIdx.x;
  const int w = t >> 6, i31 = t & 31, G = (t >> 5) & 1;
  const int l8 = (t & 63) * 8;

  {
    const float* qp = qf + ((size_t)bh * L_ + (size_t)n * 64) * F_;
    const float* kp = kf + ((size_t)bh * L_ + (size_t)n * 64) * F_;
    int o8 = t & 15, ib = t >> 4;
    #pragma unroll
    for (int iter = 0; iter < 4; ++iter) {
      int i = ib + iter * 16;
      int it = i >> 5, ks = o8 >> 1;
      int sub = (it * 8 + ks) * 512 + (o8 & 1) * 256 + (i & 31) * 8;
      {
        const float* src = qp + (size_t)i * 128 + o8 * 8;
        float4 a = *(const float4*)src, c = *(const float4*)(src + 4);
        float vals[8] = {a.x, a.y, a.z, a.w, c.x, c.y, c.z, c.w};
        u16x8 hv, lv;
        #pragma unroll
        for (int j = 0; j < 8; ++j) {
          u16 hh, ll; bf16_split(vals[j] * SCALE_Q, hh, ll);
          hv[j] = hh; lv[j] = ll;
        }
        *(u16x8*)(lds + sub) = hv;
        *(u16x8*)(lds + 8192 + sub) = lv;
      }
      {
        const float* src = kp + (size_t)i * 128 + o8 * 8;
        float4 a = *(const float4*)src, c = *(const float4*)(src + 4);
        float vals[8] = {a.x, a.y, a.z, a.w, c.x, c.y, c.z, c.w};
        u16x8 hv, lv;
        #pragma unroll
        for (int j = 0; j < 8; ++j) {
          u16 hh, ll; bf16_split(vals[j], hh, ll);
          hv[j] = hh; lv[j] = ll;
        }
        *(u16x8*)(lds + 16384 + sub) = hv;
        *(u16x8*)(lds + 24576 + sub) = lv;
      }
    }
  }
  __syncthreads();

  const u16* Lq  = lds;
  const u16* Lql = lds + 8192;
  const u16* Lk  = lds + 16384;
  const u16* Lkl = lds + 24576;

  // ---- phase S: sT = kf · qs^T (3-pass split) ----
  f32x16 st[2][2];
  #pragma unroll
  for (int a = 0; a < 2; ++a)
    #pragma unroll
    for (int c = 0; c < 2; ++c)
      #pragma unroll
      for (int r = 0; r < 16; ++r) st[a][c][r] = 0.f;

  #pragma unroll
  for (int ks = 0; ks < 8; ++ks) {
    bf16x8 kh0 = *(const bf16x8*)(Lk  + ks * 512 + l8);
    bf16x8 kh1 = *(const bf16x8*)(Lk  + (8 + ks) * 512 + l8);
    bf16x8 kl0 = *(const bf16x8*)(Lkl + ks * 512 + l8);
    bf16x8 kl1 = *(const bf16x8*)(Lkl + (8 + ks) * 512 + l8);
    bf16x8 qh0 = *(const bf16x8*)(Lq  + ks * 512 + l8);
    bf16x8 qh1 = *(const bf16x8*)(Lq  + (8 + ks) * 512 + l8);
    bf16x8 ql0 = *(const bf16x8*)(Lql + ks * 512 + l8);
    bf16x8 ql1 = *(const bf16x8*)(Lql + (8 + ks) * 512 + l8);
    MFB(kh0, qh0, st[0][0]); MFB(kh0, ql0, st[0][0]); MFB(kl0, qh0, st[0][0]);
    MFB(kh0, qh1, st[0][1]); MFB(kh0, ql1, st[0][1]); MFB(kl0, qh1, st[0][1]);
    MFB(kh1, qh0, st[1][0]); MFB(kh1, ql0, st[1][0]); MFB(kl1, qh0, st[1][0]);
    MFB(kh1, qh1, st[1][1]); MFB(kh1, ql1, st[1][1]); MFB(kl1, qh1, st[1][1]);
  }

  // ---- mask + split + cross-lane transpose: sT C-regs -> s A-frags ----
  bf16x8 sfH[2][4], sfL[2][4];
  #pragma unroll
  for (int mt = 0; mt < 2; ++mt) {
    int iv = mt * 32 + i31;
    #pragma unroll
    for (int ksj = 0; ksj < 4; ++ksj) {
      const int jt = ksj >> 1, kb = ksj & 1;
      unsigned ph[4], pl[4];
      #pragma unroll
      for (int half = 0; half < 2; ++half) {
        u16 hh[4], ll[4];
        #pragma unroll
        for (int c = 0; c < 4; ++c) {
          int r = 8 * kb + 4 * half + c;
          int jv = jt * 32 + (r & 3) + 8 * (r >> 2) + 4 * G;
          float mv = (jv <= iv) ? st[jt][mt][r] : 0.f;
          u16 h_, l_; bf16_split(mv, h_, l_);
          hh[c] = h_; ll[c] = l_;
        }
        ph[half * 2 + 0] = (unsigned)hh[0] | ((unsigned)hh[1] << 16);
        ph[half * 2 + 1] = (unsigned)hh[2] | ((unsigned)hh[3] << 16);
        pl[half * 2 + 0] = (unsigned)ll[0] | ((unsigned)ll[1] << 16);
        pl[half * 2 + 1] = (unsigned)ll[2] | ((unsigned)ll[3] << 16);
      }
      unsigned rH1 = (unsigned)__shfl_xor((int)(G ? ph[0] : ph[2]), 32, 64);
      unsigned rH2 = (unsigned)__shfl_xor((int)(G ? ph[1] : ph[3]), 32, 64);
      unsigned rL1 = (unsigned)__shfl_xor((int)(G ? pl[0] : pl[2]), 32, 64);
      unsigned rL2 = (unsigned)__shfl_xor((int)(G ? pl[1] : pl[3]), 32, 64);
      u32x4 wH, wL;
      wH[0] = G ? rH1 : ph[0]; wH[1] = G ? rH2 : ph[1];
      wH[2] = G ? ph[2] : rH1; wH[3] = G ? ph[3] : rH2;
      wL[0] = G ? rL1 : pl[0]; wL[1] = G ? rL2 : pl[1];
      wL[2] = G ? pl[2] : rL1; wL[3] = G ? pl[3] : rL2;
      sfH[mt][ksj] = __builtin_bit_cast(bf16x8, wH);
      sfL[mt][ksj] = __builtin_bit_cast(bf16x8, wL);
    }
  }

  f32x16 acc[2][2];
  #pragma unroll
  for (int a = 0; a < 2; ++a)
    #pragma unroll
    for (int c = 0; c < 2; ++c)
      #pragma unroll
      for (int r = 0; r < 16; ++r) acc[a][c][r] = 0.f;

  // ---- phase A (intra): acc += s · v, v frags pre-tiled ----
  {
    size_t vcb = ((size_t)(b * NC_ + n)) * 16384;
    #pragma unroll
    for (int nt = 0; nt < 2; ++nt) {
      #pragma unroll
      for (int ksj = 0; ksj < 4; ++ksj) {
        size_t basev = vcb + vb_off(w * 64 + nt * 32, ksj * 16) + l8;
        bf16x8 vH = *(const bf16x8*)((const short*)(vbH + basev));
        bf16x8 vL = *(const bf16x8*)((const short*)(vbL + basev));
        MFB(sfH[0][ksj], vH, acc[0][nt]); MFB(sfL[0][ksj], vH, acc[0][nt]);
        MFB(sfH[0][ksj], vL, acc[0][nt]);
        MFB(sfH[1][ksj], vH, acc[1][nt]); MFB(sfL[1][ksj], vH, acc[1][nt]);
        MFB(sfH[1][ksj], vL, acc[1][nt]);
      }
    }
  }

  // ---- phase I (inter): acc += qs · kv_cum ----
  {
    size_t cb = (size_t)blockIdx.x * 32768;
    #pragma unroll
    for (int ks = 0; ks < 8; ++ks) {
      bf16x8 qa_h0 = *(const bf16x8*)(Lq  + ks * 512 + l8);
      bf16x8 qa_h1 = *(const bf16x8*)(Lq  + (8 + ks) * 512 + l8);
      bf16x8 qa_l0 = *(const bf16x8*)(Lql + ks * 512 + l8);
      bf16x8 qa_l1 = *(const bf16x8*)(Lql + (8 + ks) * 512 + l8);
      #pragma unroll
      for (int nt = 0; nt < 2; ++nt) {
        size_t base = cb + kvb_off(w * 64 + nt * 32, ks * 16) + l8;
        bf16x8 kvH = *(const bf16x8*)((const short*)(kvbH + base));
        bf16x8 kvL = *(const bf16x8*)((const short*)(kvbL + base));
        MFB(qa_h0, kvH, acc[0][nt]); MFB(qa_l0, kvH, acc[0][nt]);
        MFB(qa_h0, kvL, acc[0][nt]);
        MFB(qa_h1, kvH, acc[1][nt]); MFB(qa_l1, kvH, acc[1][nt]);
        MFB(qa_h1, kvL, acc[1][nt]);
      }
    }
  }

  // ---- fused epilogue: A-tiled split bf16 write ----
  {
    int p = b * NC_ + n;
    #pragma unroll
    for (int mt = 0; mt < 2; ++mt)
      #pragma unroll
      for (int nt = 0; nt < 2; ++nt) {
        int u_ = h * 32 + w * 8 + nt * 4 + (i31 >> 3);
        size_t ob = ((size_t)p * 64 + (u_ >> 2)) * 2048
                  + (size_t)((u_ >> 1) & 1) * 1024 + (size_t)mt * 512
                  + (size_t)(u_ & 1) * 256 + (size_t)(i31 & 7);
        #pragma unroll
        for (int r = 0; r < 16; ++r) {
          int rr = (r & 3) + 8 * (r >> 2) + 4 * G;
          u16 hh, ll; bf16_split(acc[mt][nt][r], hh, ll);
          oHt[ob + (size_t)rr * 8] = hh;
          oLt[ob + (size_t)rr * 8] = ll;
        }
      }
  }
}

// ---------------------------------------------------------------------------
extern "C" void kernel_launch(void* const* d_in, const int* in_sizes, int n_in,
                              void* d_out, int out_size, void* d_ws, size_t ws_size,
                              hipStream_t stream) {
  const float* hs   = (const float*)d_in[0];
  const float* fcos = (const float*)d_in[1];
  const float* fsin = (const float*)d_in[2];
  // d_in[3] = mask (all ones, unused)
  const float* Wq  = (const float*)d_in[4];
  const float* Wk  = (const float*)d_in[5];
  const float* Wv  = (const float*)d_in[6];
  const float* Wo  = (const float*)d_in[7];
  const float* fmq = (const float*)d_in[8];
  const float* fmk = (const float*)d_in[9];
  float* out = (float*)d_out;

  float* ws = (float*)d_ws;
  float* q  = ws;                                   // 32MB; later oHt/oLt
  float* k  = q  + (size_t)M_ * 2048;               // 4MB; (!bigws: vb tiles)
  float* v  = k  + (size_t)M_ * 256;                // 4MB
  float* qf = v  + (size_t)M_ * 256;                // 16MB
  float* kf = qf + (size_t)B_ * H_ * L_ * F_;       // 16MB
  float* kvr = kf + (size_t)B_ * H_ * L_ * F_;      // 64MB region

  u16* hsHt = (u16*)kvr;                      // 16 MB
  u16* hsLt = hsHt + (size_t)M_ * 2048;       // 16 MB
  u16* WTh  = hsLt + (size_t)M_ * 2048;       // 10 MB
  // fm B-frag tiles in the dead tail of kvr (live until mfma_hh; kvb
  // overwrites kvr only later, in chunk_kv).
  u16* fmbtH = WTh + (size_t)1280 * 4096;     // 0.5 MB
  u16* fmbtL = fmbtH + (size_t)131072 * 2;    // 0.5 MB
  u16* kvbH = (u16*)kvr;                      // 32 MB
  u16* kvbL = kvbH + (size_t)512 * 32768;     // 32 MB
  u16* oHt  = (u16*)q;                        // 16 MB (q dead after mfma_hh)
  u16* oLt  = oHt + (size_t)M_ * 2048;        // 16 MB

  // bigws extras past the 136 MB base: WoTh (8 MB) + vb tiles (4 MB).
  const size_t WS_BASE = (size_t)142606336;   // 136 MB
  bool bigws = ws_size >= WS_BASE + (size_t)12582912;
  u16* WoTh = bigws ? (u16*)((char*)d_ws + WS_BASE) : (u16*)kvr;
  u16* vbH  = bigws ? (u16*)((char*)d_ws + WS_BASE + 8388608) : (u16*)k;
  u16* vbL  = vbH + (size_t)64 * 16384;

  // 1) Fused prep: hs split + Wq/Wk/Wv tiling + fm tiling (+ Wo when bigws)
  prep_kernel<<<bigws ? 6528 : 5504, 256, 0, stream>>>(
      hs, Wq, Wk, Wv, Wo, fmq, fmk, hsHt, hsLt, WTh, WoTh, fmbtH, fmbtL);
  // 2a) q projection: 128x128 pipelined body, 512 blocks = 2/CU
  mfma_q<<<dim3(16, 32), 256, 0, stream>>>(hsHt, hsLt, WTh, q);
  // 2b) k/v projections: old body, 256 blocks
  mfma_kv<<<dim3(4, 64), 128, 0, stream>>>(hsHt, hsLt, WTh, k, v);
  // 3) MFMA RoPE+hedgehog (replaces VALU hedgehog); bigws fuses prep_v
  mfma_hh<<<bigws ? 576 : 512, 256, 0, stream>>>(
      q, k, fcos, fsin, fmbtH, fmbtL, qf, kf, v, vbH, vbL);
  // 3b) fallback prep_v AFTER mfma_hh (k fp32 dead -> no race)
  if (!bigws)
    prep_v<<<B_ * NC_, 256, 0, stream>>>(v, vbH, vbL);
  // 4) Per-chunk k^T v outer products -> split frag-tiled bf16; in-place scan
  chunk_kv_kernel<<<B_ * H_ * NC_, 256, 0, stream>>>(kf, v, kvbH, kvbL);
  chunk_scan_kernel<<<256, 256, 0, stream>>>(kvbH, kvbL);
  // 5) MFMA inter+intra chunk attention -> A-tiled split bf16 (fused epilogue)
  chunk_attn_kernel<<<B_ * H_ * NC_, 256, 0, stream>>>(qf, kf, vbH, vbL,
                                                       kvbH, kvbL, oHt, oLt);
  // 6) Output projection (fallback path tiles Wo late)
  if (!bigws)
    wtrans_wo<<<dim3(16, 64), 256, 0, stream>>>(Wo, WoTh);
  mfma_wo<<<dim3(16, 32), 256, 0, stream>>>(oHt, oLt, WoTh, out);
}